// Round 1
// baseline (4750.002 us; speedup 1.0000x reference)
//
#include <hip/hip_runtime.h>

// Transformer block, fp32 correctness-first baseline.
// Layouts: q/k/v/att all stored head-interleaved [B,T,C] (C = H*HS) so the
// "concat heads" transpose never materializes and out-proj is a plain GEMM.
// Workspace (fp32): [q | k | v | att | h(/h2) | x2] = 6 * 8192*1024 floats
//                 = 192 MiB. ffh [8192,4096] overlays q..att (dead by then).

constexpr int Bb = 4, Tt = 2048, Cc = 1024, Hh = 16, HSz = 64, Ff = 4096;
constexpr int Mrows = Bb * Tt;            // 8192
constexpr size_t MC = (size_t)Mrows * Cc; // 8388608

// ---------------- LayerNorm: one block per row ----------------
__global__ __launch_bounds__(256) void ln_kernel(const float* __restrict__ x,
                                                 const float* __restrict__ g,
                                                 const float* __restrict__ b,
                                                 float* __restrict__ out) {
  int row = blockIdx.x;
  const float* xr = x + (size_t)row * Cc;
  int c4 = threadIdx.x * 4;
  float4 v = *(const float4*)(xr + c4);
  float s1 = v.x + v.y + v.z + v.w;
  float s2 = v.x * v.x + v.y * v.y + v.z * v.z + v.w * v.w;
#pragma unroll
  for (int off = 32; off >= 1; off >>= 1) {
    s1 += __shfl_xor(s1, off);
    s2 += __shfl_xor(s2, off);
  }
  __shared__ float red[8];
  int wid = threadIdx.x >> 6, lane = threadIdx.x & 63;
  if (lane == 0) { red[wid] = s1; red[4 + wid] = s2; }
  __syncthreads();
  float t1 = red[0] + red[1] + red[2] + red[3];
  float t2 = red[4] + red[5] + red[6] + red[7];
  float mu = t1 * (1.0f / Cc);
  float var = t2 * (1.0f / Cc) - mu * mu;
  float rs = rsqrtf(var + 1e-5f);
  float4 gv = *(const float4*)(g + c4);
  float4 bv = *(const float4*)(b + c4);
  float4 o;
  o.x = (v.x - mu) * rs * gv.x + bv.x;
  o.y = (v.y - mu) * rs * gv.y + bv.y;
  o.z = (v.z - mu) * rs * gv.z + bv.z;
  o.w = (v.w - mu) * rs * gv.w + bv.w;
  *(float4*)(out + (size_t)row * Cc + c4) = o;
}

// ---------------- Generic 64x64 fp32 GEMM tile ----------------
// Bm/bias/res/Cout are pre-offset to the 64-col block. Row-major everywhere.
template <bool RELU, bool HASRES>
__device__ __forceinline__ void gemm_tile(const float* __restrict__ A, int lda,
                                          const float* __restrict__ Bm, int ldb,
                                          const float* __restrict__ bias,
                                          const float* __restrict__ res,
                                          float* __restrict__ Cout, int ldc,
                                          int K, int m0) {
  __shared__ float As[16][68];
  __shared__ float Bs[16][68];
  int tid = threadIdx.x;
  int tx = tid & 15, ty = tid >> 4;
  float acc[4][4] = {};
  int arow = tid >> 2, ak = (tid & 3) * 4;   // A: 4 threads x float4 per row
  int bk = tid >> 4, bcol = (tid & 15) * 4;  // B: 16 threads x float4 per k-row
  const float* Aptr = A + (size_t)(m0 + arow) * lda + ak;
  const float* Bptr = Bm + (size_t)bk * ldb + bcol;
  for (int k0 = 0; k0 < K; k0 += 16) {
    float4 av = *(const float4*)Aptr;
    Aptr += 16;
    float4 bv = *(const float4*)Bptr;
    Bptr += (size_t)16 * ldb;
    As[ak + 0][arow] = av.x;
    As[ak + 1][arow] = av.y;
    As[ak + 2][arow] = av.z;
    As[ak + 3][arow] = av.w;
    *(float4*)&Bs[bk][bcol] = bv;
    __syncthreads();
#pragma unroll
    for (int kk = 0; kk < 16; ++kk) {
      float4 a4 = *(const float4*)&As[kk][ty * 4];
      float4 b4 = *(const float4*)&Bs[kk][tx * 4];
      float aa[4] = {a4.x, a4.y, a4.z, a4.w};
      float bb[4] = {b4.x, b4.y, b4.z, b4.w};
#pragma unroll
      for (int i = 0; i < 4; ++i)
#pragma unroll
        for (int j = 0; j < 4; ++j) acc[i][j] += aa[i] * bb[j];
    }
    __syncthreads();
  }
  float4 bv4 = *(const float4*)(bias + tx * 4);
#pragma unroll
  for (int i = 0; i < 4; ++i) {
    int row = m0 + ty * 4 + i;
    float vx[4] = {acc[i][0] + bv4.x, acc[i][1] + bv4.y, acc[i][2] + bv4.z,
                   acc[i][3] + bv4.w};
    if constexpr (HASRES) {
      float4 r4 = *(const float4*)(res + (size_t)row * ldc + tx * 4);
      vx[0] += r4.x; vx[1] += r4.y; vx[2] += r4.z; vx[3] += r4.w;
    }
    if constexpr (RELU) {
#pragma unroll
      for (int j = 0; j < 4; ++j) vx[j] = fmaxf(vx[j], 0.f);
    }
    float4 o4 = {vx[0], vx[1], vx[2], vx[3]};
    *(float4*)(Cout + (size_t)row * ldc + tx * 4) = o4;
  }
}

template <bool RELU, bool HASRES>
__global__ __launch_bounds__(256) void gemm64_kernel(
    const float* __restrict__ A, int lda, const float* __restrict__ Bm, int ldb,
    const float* __restrict__ bias, const float* __restrict__ res,
    float* __restrict__ Cout, int ldc, int K) {
  int n0 = blockIdx.x * 64, m0 = blockIdx.y * 64;
  gemm_tile<RELU, HASRES>(A, lda, Bm + n0, ldb, bias + n0,
                          HASRES ? res + n0 : nullptr, Cout + n0, ldc, K, m0);
}

// QKV: per-head [8192,1024]x[1024,64]; W for head h is contiguous [C][HS].
__global__ __launch_bounds__(256) void qkv_kernel(
    const float* __restrict__ h, const float* __restrict__ wq,
    const float* __restrict__ wk, const float* __restrict__ wv,
    const float* __restrict__ bq, const float* __restrict__ bk,
    const float* __restrict__ bv, float* __restrict__ q, float* __restrict__ k,
    float* __restrict__ v) {
  int head = blockIdx.y, z = blockIdx.z, m0 = blockIdx.x * 64;
  const float* W = (z == 0 ? wq : (z == 1 ? wk : wv)) + (size_t)head * Cc * HSz;
  const float* bias = (z == 0 ? bq : (z == 1 ? bk : bv)) + head * HSz;
  float* out = (z == 0 ? q : (z == 1 ? k : v)) + head * HSz;
  gemm_tile<false, false>(h, Cc, W, HSz, bias, nullptr, out, Cc, Cc, m0);
}

// ---------------- Causal flash attention, 1 thread = 1 query row ----------
// q/k/v/att in [B,T,C] head-interleaved layout. Scores in exp2 domain
// (log2e/sqrt(C) folded into q).
constexpr int QT = 128, KT = 64;
__global__ __launch_bounds__(128) void attn_kernel(const float* __restrict__ Qm,
                                                   const float* __restrict__ Km,
                                                   const float* __restrict__ Vm,
                                                   float* __restrict__ Om) {
  __shared__ float Ks[KT][HSz];
  __shared__ float Vs[KT][HSz];
  int bh = blockIdx.y;
  int bb = bh >> 4, hh = bh & 15;
  int qrow = blockIdx.x * QT + threadIdx.x;  // t index
  size_t rowbase = ((size_t)bb * Tt + qrow) * Cc + hh * HSz;
  const float qscale = 1.4426950408889634f / 32.0f;  // log2e * C^-0.5
  float q[HSz];
#pragma unroll
  for (int d4 = 0; d4 < HSz; d4 += 4) {
    float4 t = *(const float4*)(Qm + rowbase + d4);
    q[d4] = t.x * qscale; q[d4 + 1] = t.y * qscale;
    q[d4 + 2] = t.z * qscale; q[d4 + 3] = t.w * qscale;
  }
  float o[HSz] = {};
  float m = -1e30f, l = 0.f;
  size_t kvbase = ((size_t)bb * Tt) * Cc + hh * HSz;
  int nkt = (blockIdx.x * QT + QT + KT - 1) / KT;
  for (int kt = 0; kt < nkt; ++kt) {
    int t0 = kt * KT;
#pragma unroll
    for (int i = 0; i < 8; ++i) {
      int idx4 = threadIdx.x + i * 128;
      int r = idx4 >> 4, c4 = (idx4 & 15) * 4;
      *(float4*)&Ks[r][c4] = *(const float4*)(Km + kvbase + (size_t)(t0 + r) * Cc + c4);
      *(float4*)&Vs[r][c4] = *(const float4*)(Vm + kvbase + (size_t)(t0 + r) * Cc + c4);
    }
    __syncthreads();
    int jlimit = qrow - t0;  // valid j <= jlimit
    if (jlimit >= 0) {
      int jmax = jlimit < KT - 1 ? jlimit : KT - 1;
      for (int jc = 0; jc <= jmax; jc += 16) {
        float s[16];
        float cmax = -1e30f;
#pragma unroll
        for (int jj = 0; jj < 16; ++jj) {
          int j = jc + jj;
          float acc = 0.f;
#pragma unroll
          for (int d4 = 0; d4 < HSz; d4 += 4) {
            float4 kv = *(const float4*)&Ks[j][d4];
            acc += q[d4] * kv.x + q[d4 + 1] * kv.y + q[d4 + 2] * kv.z +
                   q[d4 + 3] * kv.w;
          }
          s[jj] = (j <= jmax) ? acc : -1e30f;
          cmax = fmaxf(cmax, s[jj]);
        }
        float mnew = fmaxf(m, cmax);
        float scale = exp2f(m - mnew);
        l *= scale;
#pragma unroll
        for (int d = 0; d < HSz; ++d) o[d] *= scale;
#pragma unroll
        for (int jj = 0; jj < 16; ++jj) {
          float p = exp2f(s[jj] - mnew);
          l += p;
          int j = jc + jj;
#pragma unroll
          for (int d4 = 0; d4 < HSz; d4 += 4) {
            float4 vv = *(const float4*)&Vs[j][d4];
            o[d4] += p * vv.x; o[d4 + 1] += p * vv.y;
            o[d4 + 2] += p * vv.z; o[d4 + 3] += p * vv.w;
          }
        }
        m = mnew;
      }
    }
    __syncthreads();
  }
  float inv = 1.f / l;
#pragma unroll
  for (int d4 = 0; d4 < HSz; d4 += 4) {
    float4 ov = {o[d4] * inv, o[d4 + 1] * inv, o[d4 + 2] * inv, o[d4 + 3] * inv};
    *(float4*)(Om + rowbase + d4) = ov;
  }
}

extern "C" void kernel_launch(void* const* d_in, const int* in_sizes, int n_in,
                              void* d_out, int out_size, void* d_ws,
                              size_t ws_size, hipStream_t stream) {
  const float* x = (const float*)d_in[0];
  const float* wq = (const float*)d_in[1];
  const float* bq = (const float*)d_in[2];
  const float* wk = (const float*)d_in[3];
  const float* bk = (const float*)d_in[4];
  const float* wv = (const float*)d_in[5];
  const float* bv = (const float*)d_in[6];
  const float* wp = (const float*)d_in[7];
  const float* bp = (const float*)d_in[8];
  const float* w1 = (const float*)d_in[9];
  const float* b1 = (const float*)d_in[10];
  const float* w2 = (const float*)d_in[11];
  const float* b2 = (const float*)d_in[12];
  const float* g1 = (const float*)d_in[13];
  const float* be1 = (const float*)d_in[14];
  const float* g2 = (const float*)d_in[15];
  const float* be2 = (const float*)d_in[16];
  float* out = (float*)d_out;

  float* ws = (float*)d_ws;
  float* q = ws;
  float* k = ws + MC;
  float* v = ws + 2 * MC;
  float* att = ws + 3 * MC;
  float* h = ws + 4 * MC;   // LN1 out, reused as LN2 out
  float* x2 = ws + 5 * MC;  // post-attention residual stream
  float* ffh = ws;          // [8192,4096] overlays q..att (exactly 4*MC)

  // 1) h = LN(x; g1,be1)
  ln_kernel<<<dim3(Mrows), dim3(256), 0, stream>>>(x, g1, be1, h);
  // 2) q,k,v = h @ W{q,k,v} + b   (per-head GEMMs)
  qkv_kernel<<<dim3(Mrows / 64, Hh, 3), dim3(256), 0, stream>>>(
      h, wq, wk, wv, bq, bk, bv, q, k, v);
  // 3) att = causal_softmax(q k^T / sqrt(C)) v
  attn_kernel<<<dim3(Tt / QT, Bb * Hh), dim3(128), 0, stream>>>(q, k, v, att);
  // 4) x2 = x + att @ wp + bp
  gemm64_kernel<false, true><<<dim3(Cc / 64, Mrows / 64), dim3(256), 0, stream>>>(
      att, Cc, wp, Cc, bp, x, x2, Cc, Cc);
  // 5) h2 = LN(x2; g2,be2)
  ln_kernel<<<dim3(Mrows), dim3(256), 0, stream>>>(x2, g2, be2, h);
  // 6) ffh = relu(h2 @ w1 + b1)
  gemm64_kernel<true, false><<<dim3(Ff / 64, Mrows / 64), dim3(256), 0, stream>>>(
      h, Cc, w1, Ff, b1, nullptr, ffh, Ff, Cc);
  // 7) out = x2 + ffh @ w2 + b2
  gemm64_kernel<false, true><<<dim3(Cc / 64, Mrows / 64), dim3(256), 0, stream>>>(
      ffh, Ff, w2, Cc, b2, x2, out, Cc, Ff);
}

// Round 2
// 2247.022 us; speedup vs baseline: 2.1139x; 2.1139x over previous
//
#include <hip/hip_runtime.h>

// Transformer block. Round 1: all four GEMMs -> bf16 MFMA (m97 structure:
// 128x128 tile, BK=32, 4 waves, mfma_f32_16x16x32_bf16, global_load_lds w=16,
// A and B^T both K-contiguous in LDS so fragments are single ds_read_b128).
// Attention unchanged (fp32 flash, per-thread row) — next round's target.
//
// Workspace layout (136 MiB):
//   [qkv bf16 48M | att bf16 16M]   <- ffh bf16 64M overlays exactly
//   [h1b/h2b bf16 16M][x2 f32 32M][wqkvT 6M][wpT 2M][w1T 8M][w2T 8M][bqkv]

constexpr int Bb = 4, Tt = 2048, Cc = 1024, Hh = 16, HSz = 64, Ff = 4096;
constexpr int Mrows = Bb * Tt;  // 8192

typedef __attribute__((ext_vector_type(8))) short bf16x8;
typedef __attribute__((ext_vector_type(4))) float f32x4;

__device__ __forceinline__ ushort f2bf(float f) {
  uint u = __builtin_bit_cast(uint, f);
  uint r = (u + 0x7fffu + ((u >> 16) & 1u)) >> 16;
  return (ushort)r;
}
__device__ __forceinline__ float bf2f(ushort s) {
  return __builtin_bit_cast(float, ((uint)s) << 16);
}
__device__ __forceinline__ void gload16(const void* g, void* l) {
  __builtin_amdgcn_global_load_lds(
      (const __attribute__((address_space(1))) void*)g,
      (__attribute__((address_space(3))) void*)l, 16, 0, 0);
}

// ---------------- LayerNorm: fp32 in, bf16 out ----------------
__global__ __launch_bounds__(256) void ln_kernel(const float* __restrict__ x,
                                                 const float* __restrict__ g,
                                                 const float* __restrict__ b,
                                                 ushort* __restrict__ out) {
  int row = blockIdx.x;
  const float* xr = x + (size_t)row * Cc;
  int c4 = threadIdx.x * 4;
  float4 v = *(const float4*)(xr + c4);
  float s1 = v.x + v.y + v.z + v.w;
  float s2 = v.x * v.x + v.y * v.y + v.z * v.z + v.w * v.w;
#pragma unroll
  for (int off = 32; off >= 1; off >>= 1) {
    s1 += __shfl_xor(s1, off);
    s2 += __shfl_xor(s2, off);
  }
  __shared__ float red[8];
  int wid = threadIdx.x >> 6, lane = threadIdx.x & 63;
  if (lane == 0) { red[wid] = s1; red[4 + wid] = s2; }
  __syncthreads();
  float t1 = red[0] + red[1] + red[2] + red[3];
  float t2 = red[4] + red[5] + red[6] + red[7];
  float mu = t1 * (1.0f / Cc);
  float var = t2 * (1.0f / Cc) - mu * mu;
  float rs = rsqrtf(var + 1e-5f);
  float4 gv = *(const float4*)(g + c4);
  float4 bv = *(const float4*)(b + c4);
  ushort4 o;
  o.x = f2bf((v.x - mu) * rs * gv.x + bv.x);
  o.y = f2bf((v.y - mu) * rs * gv.y + bv.y);
  o.z = f2bf((v.z - mu) * rs * gv.z + bv.z);
  o.w = f2bf((v.w - mu) * rs * gv.w + bv.w);
  *(ushort4*)(out + (size_t)row * Cc + c4) = o;
}

// ---------------- Transpose-cast fp32 [R][C] -> bf16 [C][R] ----------------
__device__ __forceinline__ void tcast_body(const float* __restrict__ src,
                                           ushort* __restrict__ dst, int ldS,
                                           int ldD, int r0, int c0) {
  __shared__ float t[32][33];
  int c = threadIdx.x & 31, r8 = threadIdx.x >> 5;
#pragma unroll
  for (int i = 0; i < 4; ++i) {
    int r = r8 + i * 8;
    t[r][c] = src[(size_t)(r0 + r) * ldS + c0 + c];
  }
  __syncthreads();
#pragma unroll
  for (int i = 0; i < 4; ++i) {
    int rr = r8 + i * 8;
    dst[(size_t)(c0 + rr) * ldD + r0 + c] = f2bf(t[c][rr]);
  }
}

__global__ __launch_bounds__(256) void tcast_kernel(const float* __restrict__ src,
                                                    ushort* __restrict__ dst,
                                                    int ldS, int ldD) {
  tcast_body(src, dst, ldS, ldD, blockIdx.x * 32, blockIdx.y * 32);
}

// wq/wk/wv [16][1024][64] -> wqkvT [3072][1024], row n = z*1024 + h*64 + d
__global__ __launch_bounds__(256) void tcast_qkv(const float* __restrict__ wq,
                                                 const float* __restrict__ wk,
                                                 const float* __restrict__ wv,
                                                 ushort* __restrict__ dst) {
  int z = blockIdx.z, zz = z >> 4, h = z & 15;
  const float* src = (zz == 0 ? wq : (zz == 1 ? wk : wv)) + (size_t)h * Cc * HSz;
  ushort* d = dst + (size_t)(zz * 1024 + h * 64) * 1024;
  tcast_body(src, d, HSz, Cc, blockIdx.x * 32, blockIdx.y * 32);
}

__global__ __launch_bounds__(256) void bias_concat(const float* __restrict__ bq,
                                                   const float* __restrict__ bk,
                                                   const float* __restrict__ bv,
                                                   float* __restrict__ dst) {
  int i = blockIdx.x * 256 + threadIdx.x;
  dst[i] = i < 1024 ? bq[i] : (i < 2048 ? bk[i - 1024] : bv[i - 2048]);
}

// ---------------- bf16 MFMA GEMM: C = A[M][K] * (Bt[N][K])^T ----------------
// 128x128 tile, BK=32, 256 threads = 4 waves in 2x2, each wave 64x64 (4x4
// fragments of 16x16x32). A and Bt staged K-contiguous via global_load_lds.
constexpr int BK = 32;
template <bool RELU, bool HASRES, bool OUTBF16>
__global__ __launch_bounds__(256) void gemm_bf16(
    const ushort* __restrict__ A, int lda,   // bf16 [M][K]
    const ushort* __restrict__ Bt, int ldb,  // bf16 [N][K]
    const float* __restrict__ bias,          // [N]
    const float* __restrict__ res,           // [M][ldc] or null
    void* __restrict__ Cout, int ldc, int K) {
  __shared__ __align__(16) ushort As[128 * BK];
  __shared__ __align__(16) ushort Bs[128 * BK];
  int tid = threadIdx.x;
  int wid = tid >> 6, lane = tid & 63;
  int wr = wid >> 1, wc = wid & 1;
  int m0 = blockIdx.y * 128, n0 = blockIdx.x * 128;
  int fr = lane & 15, fq = lane >> 4;

  f32x4 acc[4][4] = {};
  const ushort* Ag = A + (size_t)m0 * lda;
  const ushort* Bg = Bt + (size_t)n0 * ldb;

  for (int k0 = 0; k0 < K; k0 += BK) {
    // stage 128x32 bf16 tiles (8 KiB each): 2 wave-chunks of 1024 B per matrix
#pragma unroll
    for (int c = 0; c < 2; ++c) {
      int off = wid * 1024 + c * 512 + lane * 8;  // ushort units
      int row = off >> 5, kk = off & 31;
      gload16(Ag + (size_t)row * lda + k0 + kk, &As[wid * 1024 + c * 512]);
      gload16(Bg + (size_t)row * ldb + k0 + kk, &Bs[wid * 1024 + c * 512]);
    }
    __syncthreads();
    bf16x8 av[4], bv[4];
#pragma unroll
    for (int m = 0; m < 4; ++m)
      av[m] = *(const bf16x8*)&As[(wr * 64 + m * 16 + fr) * BK + fq * 8];
#pragma unroll
    for (int n = 0; n < 4; ++n)
      bv[n] = *(const bf16x8*)&Bs[(wc * 64 + n * 16 + fr) * BK + fq * 8];
#pragma unroll
    for (int m = 0; m < 4; ++m)
#pragma unroll
      for (int n = 0; n < 4; ++n)
        acc[m][n] =
            __builtin_amdgcn_mfma_f32_16x16x32_bf16(av[m], bv[n], acc[m][n], 0, 0, 0);
    __syncthreads();
  }

  // epilogue: C/D layout col=lane&15, row=(lane>>4)*4+reg (m89-verified)
#pragma unroll
  for (int m = 0; m < 4; ++m) {
    int gm = m0 + wr * 64 + m * 16 + fq * 4;
#pragma unroll
    for (int n = 0; n < 4; ++n) {
      int gn = n0 + wc * 64 + n * 16 + fr;
      float bsv = bias[gn];
#pragma unroll
      for (int j = 0; j < 4; ++j) {
        int row = gm + j;
        float v = acc[m][n][j] + bsv;
        if constexpr (HASRES) v += res[(size_t)row * ldc + gn];
        if constexpr (RELU) v = fmaxf(v, 0.f);
        if constexpr (OUTBF16)
          ((ushort*)Cout)[(size_t)row * ldc + gn] = f2bf(v);
        else
          ((float*)Cout)[(size_t)row * ldc + gn] = v;
      }
    }
  }
}

// ---------------- Causal flash attention (fp32 math, bf16 I/O) ------------
// qkv [8192][3072] bf16 (cols: q|k|v, head-interleaved). att out bf16 [8192][1024].
constexpr int QT = 128, KT = 64;
__global__ __launch_bounds__(128) void attn_kernel(const ushort* __restrict__ QKV,
                                                   ushort* __restrict__ Om) {
  __shared__ float Ks[KT][HSz];
  __shared__ float Vs[KT][HSz];
  const int ldq = 3072;
  int bh = blockIdx.y, bb = bh >> 4, hh = bh & 15;
  int qrow = blockIdx.x * QT + threadIdx.x;
  size_t qbase = ((size_t)bb * Tt + qrow) * ldq + hh * HSz;
  const float qscale = 1.4426950408889634f / 32.0f;  // log2e * C^-0.5
  float q[HSz];
#pragma unroll
  for (int d8 = 0; d8 < HSz; d8 += 8) {
    uint4 t = *(const uint4*)(QKV + qbase + d8);
    const ushort* ts = (const ushort*)&t;
#pragma unroll
    for (int i = 0; i < 8; ++i) q[d8 + i] = bf2f(ts[i]) * qscale;
  }
  float o[HSz] = {};
  float m = -1e30f, l = 0.f;
  size_t kbase = ((size_t)bb * Tt) * ldq + 1024 + hh * HSz;
  size_t vbase = kbase + 1024;
  int nkt = (blockIdx.x * QT + QT + KT - 1) / KT;
  for (int kt = 0; kt < nkt; ++kt) {
    int t0 = kt * KT;
#pragma unroll
    for (int i = 0; i < 4; ++i) {
      int idx = threadIdx.x + i * 128;
      int r = idx >> 3, c8 = (idx & 7) * 8;
      uint4 tk = *(const uint4*)(QKV + kbase + (size_t)(t0 + r) * ldq + c8);
      uint4 tv = *(const uint4*)(QKV + vbase + (size_t)(t0 + r) * ldq + c8);
      const ushort* pk = (const ushort*)&tk;
      const ushort* pv = (const ushort*)&tv;
#pragma unroll
      for (int j2 = 0; j2 < 8; ++j2) {
        Ks[r][c8 + j2] = bf2f(pk[j2]);
        Vs[r][c8 + j2] = bf2f(pv[j2]);
      }
    }
    __syncthreads();
    int jlimit = qrow - t0;
    if (jlimit >= 0) {
      int jmax = jlimit < KT - 1 ? jlimit : KT - 1;
      for (int jc = 0; jc <= jmax; jc += 16) {
        float s[16];
        float cmax = -1e30f;
#pragma unroll
        for (int jj = 0; jj < 16; ++jj) {
          int j = jc + jj;
          float acc = 0.f;
#pragma unroll
          for (int d4 = 0; d4 < HSz; d4 += 4) {
            float4 kv = *(const float4*)&Ks[j][d4];
            acc += q[d4] * kv.x + q[d4 + 1] * kv.y + q[d4 + 2] * kv.z +
                   q[d4 + 3] * kv.w;
          }
          s[jj] = (j <= jmax) ? acc : -1e30f;
          cmax = fmaxf(cmax, s[jj]);
        }
        float mnew = fmaxf(m, cmax);
        float scale = exp2f(m - mnew);
        l *= scale;
#pragma unroll
        for (int d = 0; d < HSz; ++d) o[d] *= scale;
#pragma unroll
        for (int jj = 0; jj < 16; ++jj) {
          float p = exp2f(s[jj] - mnew);
          l += p;
          int j = jc + jj;
#pragma unroll
          for (int d4 = 0; d4 < HSz; d4 += 4) {
            float4 vv = *(const float4*)&Vs[j][d4];
            o[d4] += p * vv.x; o[d4 + 1] += p * vv.y;
            o[d4 + 2] += p * vv.z; o[d4 + 3] += p * vv.w;
          }
        }
        m = mnew;
      }
    }
    __syncthreads();
  }
  float inv = 1.f / l;
  size_t obase = ((size_t)bb * Tt + qrow) * Cc + hh * HSz;
#pragma unroll
  for (int d4 = 0; d4 < HSz; d4 += 4) {
    ushort4 o4 = {f2bf(o[d4] * inv), f2bf(o[d4 + 1] * inv),
                  f2bf(o[d4 + 2] * inv), f2bf(o[d4 + 3] * inv)};
    *(ushort4*)(Om + obase + d4) = o4;
  }
}

extern "C" void kernel_launch(void* const* d_in, const int* in_sizes, int n_in,
                              void* d_out, int out_size, void* d_ws,
                              size_t ws_size, hipStream_t stream) {
  const float* x = (const float*)d_in[0];
  const float* wq = (const float*)d_in[1];
  const float* bq = (const float*)d_in[2];
  const float* wk = (const float*)d_in[3];
  const float* bk = (const float*)d_in[4];
  const float* wv = (const float*)d_in[5];
  const float* bv = (const float*)d_in[6];
  const float* wp = (const float*)d_in[7];
  const float* bp = (const float*)d_in[8];
  const float* w1 = (const float*)d_in[9];
  const float* b1 = (const float*)d_in[10];
  const float* w2 = (const float*)d_in[11];
  const float* b2 = (const float*)d_in[12];
  const float* g1 = (const float*)d_in[13];
  const float* be1 = (const float*)d_in[14];
  const float* g2 = (const float*)d_in[15];
  const float* be2 = (const float*)d_in[16];
  float* out = (float*)d_out;

  ushort* qkv = (ushort*)d_ws;                 // [8192][3072] bf16
  ushort* att = qkv + (size_t)25165824;        // [8192][1024] bf16
  ushort* ffh = qkv;                           // [8192][4096] bf16 (overlay)
  ushort* h1b = att + (size_t)8388608;         // [8192][1024] bf16 (LN1/LN2 out)
  float* x2 = (float*)(h1b + (size_t)8388608); // [8192][1024] f32
  ushort* wqkvT = (ushort*)(x2 + (size_t)8388608);  // [3072][1024]
  ushort* wpT = wqkvT + (size_t)3145728;            // [1024][1024]
  ushort* w1T = wpT + (size_t)1048576;              // [4096][1024]
  ushort* w2T = w1T + (size_t)4194304;              // [1024][4096]
  float* bqkv = (float*)(w2T + (size_t)4194304);    // [3072]

  // weight prep (bf16, transposed to [N][K])
  tcast_qkv<<<dim3(32, 2, 48), 256, 0, stream>>>(wq, wk, wv, wqkvT);
  tcast_kernel<<<dim3(32, 32), 256, 0, stream>>>(wp, wpT, 1024, 1024);
  tcast_kernel<<<dim3(32, 128), 256, 0, stream>>>(w1, w1T, 4096, 1024);
  tcast_kernel<<<dim3(128, 32), 256, 0, stream>>>(w2, w2T, 1024, 4096);
  bias_concat<<<dim3(12), 256, 0, stream>>>(bq, bk, bv, bqkv);

  // 1) h1b = LN(x)
  ln_kernel<<<dim3(Mrows), 256, 0, stream>>>(x, g1, be1, h1b);
  // 2) qkv = h1b @ WqkvT^T + bqkv
  gemm_bf16<false, false, true><<<dim3(24, 64), 256, 0, stream>>>(
      h1b, 1024, wqkvT, 1024, bqkv, nullptr, qkv, 3072, 1024);
  // 3) att = causal_softmax(q k^T / 32) v
  attn_kernel<<<dim3(Tt / QT, Bb * Hh), 128, 0, stream>>>(qkv, att);
  // 4) x2 = x + att @ wp + bp
  gemm_bf16<false, true, false><<<dim3(8, 64), 256, 0, stream>>>(
      att, 1024, wpT, 1024, bp, x, x2, 1024, 1024);
  // 5) h2b = LN(x2)
  ln_kernel<<<dim3(Mrows), 256, 0, stream>>>(x2, g2, be2, h1b);
  // 6) ffh = relu(h2b @ w1 + b1)
  gemm_bf16<true, false, true><<<dim3(32, 64), 256, 0, stream>>>(
      h1b, 1024, w1T, 1024, b1, nullptr, ffh, 4096, 1024);
  // 7) out = x2 + ffh @ w2 + b2
  gemm_bf16<false, true, false><<<dim3(8, 64), 256, 0, stream>>>(
      ffh, 4096, w2T, 4096, b2, x2, out, 1024, 4096);
}

// Round 3
// 557.110 us; speedup vs baseline: 8.5261x; 4.0334x over previous
//
#include <hip/hip_runtime.h>

// Transformer block. Round 2: MFMA flash attention (swapped QK^T, P via
// swizzled per-wave LDS, V pre-transposed by the QKV GEMM epilogue).
// GEMMs unchanged from round 1 (m97 structure, 128x128, BK=32).
//
// Workspace (~136 MiB):
//   [Q 16M | K 16M | Vt 16M | att 16M]  <- ffh bf16 64M overlays exactly
//   [h1b 16M][x2 f32 32M][wqkvT 6M][wpT 2M][w1T 8M][w2T 8M][bqkv]

constexpr int Bb = 4, Tt = 2048, Cc = 1024, Hh = 16, HSz = 64, Ff = 4096;
constexpr int Mrows = Bb * Tt;  // 8192

typedef __attribute__((ext_vector_type(8))) short bf16x8;
typedef __attribute__((ext_vector_type(4))) float f32x4;

__device__ __forceinline__ ushort f2bf(float f) {
  uint u = __builtin_bit_cast(uint, f);
  uint r = (u + 0x7fffu + ((u >> 16) & 1u)) >> 16;
  return (ushort)r;
}
__device__ __forceinline__ float bf2f(ushort s) {
  return __builtin_bit_cast(float, ((uint)s) << 16);
}
__device__ __forceinline__ void gload16(const void* g, void* l) {
  __builtin_amdgcn_global_load_lds(
      (const __attribute__((address_space(1))) void*)g,
      (__attribute__((address_space(3))) void*)l, 16, 0, 0);
}

// ---------------- LayerNorm: fp32 in, bf16 out ----------------
__global__ __launch_bounds__(256) void ln_kernel(const float* __restrict__ x,
                                                 const float* __restrict__ g,
                                                 const float* __restrict__ b,
                                                 ushort* __restrict__ out) {
  int row = blockIdx.x;
  const float* xr = x + (size_t)row * Cc;
  int c4 = threadIdx.x * 4;
  float4 v = *(const float4*)(xr + c4);
  float s1 = v.x + v.y + v.z + v.w;
  float s2 = v.x * v.x + v.y * v.y + v.z * v.z + v.w * v.w;
#pragma unroll
  for (int off = 32; off >= 1; off >>= 1) {
    s1 += __shfl_xor(s1, off);
    s2 += __shfl_xor(s2, off);
  }
  __shared__ float red[8];
  int wid = threadIdx.x >> 6, lane = threadIdx.x & 63;
  if (lane == 0) { red[wid] = s1; red[4 + wid] = s2; }
  __syncthreads();
  float t1 = red[0] + red[1] + red[2] + red[3];
  float t2 = red[4] + red[5] + red[6] + red[7];
  float mu = t1 * (1.0f / Cc);
  float var = t2 * (1.0f / Cc) - mu * mu;
  float rs = rsqrtf(var + 1e-5f);
  float4 gv = *(const float4*)(g + c4);
  float4 bv = *(const float4*)(b + c4);
  ushort4 o;
  o.x = f2bf((v.x - mu) * rs * gv.x + bv.x);
  o.y = f2bf((v.y - mu) * rs * gv.y + bv.y);
  o.z = f2bf((v.z - mu) * rs * gv.z + bv.z);
  o.w = f2bf((v.w - mu) * rs * gv.w + bv.w);
  *(ushort4*)(out + (size_t)row * Cc + c4) = o;
}

// ---------------- Transpose-cast fp32 [R][C] -> bf16 [C][R] ----------------
__device__ __forceinline__ void tcast_body(const float* __restrict__ src,
                                           ushort* __restrict__ dst, int ldS,
                                           int ldD, int r0, int c0) {
  __shared__ float t[32][33];
  int c = threadIdx.x & 31, r8 = threadIdx.x >> 5;
#pragma unroll
  for (int i = 0; i < 4; ++i) {
    int r = r8 + i * 8;
    t[r][c] = src[(size_t)(r0 + r) * ldS + c0 + c];
  }
  __syncthreads();
#pragma unroll
  for (int i = 0; i < 4; ++i) {
    int rr = r8 + i * 8;
    dst[(size_t)(c0 + rr) * ldD + r0 + c] = f2bf(t[c][rr]);
  }
}

__global__ __launch_bounds__(256) void tcast_kernel(const float* __restrict__ src,
                                                    ushort* __restrict__ dst,
                                                    int ldS, int ldD) {
  tcast_body(src, dst, ldS, ldD, blockIdx.x * 32, blockIdx.y * 32);
}

__global__ __launch_bounds__(256) void tcast_qkv(const float* __restrict__ wq,
                                                 const float* __restrict__ wk,
                                                 const float* __restrict__ wv,
                                                 ushort* __restrict__ dst) {
  int z = blockIdx.z, zz = z >> 4, h = z & 15;
  const float* src = (zz == 0 ? wq : (zz == 1 ? wk : wv)) + (size_t)h * Cc * HSz;
  ushort* d = dst + (size_t)(zz * 1024 + h * 64) * 1024;
  tcast_body(src, d, HSz, Cc, blockIdx.x * 32, blockIdx.y * 32);
}

__global__ __launch_bounds__(256) void bias_concat(const float* __restrict__ bq,
                                                   const float* __restrict__ bk,
                                                   const float* __restrict__ bv,
                                                   float* __restrict__ dst) {
  int i = blockIdx.x * 256 + threadIdx.x;
  dst[i] = i < 1024 ? bq[i] : (i < 2048 ? bk[i - 1024] : bv[i - 2048]);
}

// ---------------- bf16 MFMA GEMM mainloop (128x128, BK=32) ----------------
__device__ __forceinline__ void gemm_main(const ushort* __restrict__ A, int lda,
                                          const ushort* __restrict__ Bt, int ldb,
                                          int K, int m0, int n0,
                                          ushort* __restrict__ As,
                                          ushort* __restrict__ Bs,
                                          f32x4 (&acc)[4][4]) {
  int tid = threadIdx.x, wid = tid >> 6, lane = tid & 63;
  int wr = wid >> 1, wc = wid & 1, fr = lane & 15, fq = lane >> 4;
  const ushort* Ag = A + (size_t)m0 * lda;
  const ushort* Bg = Bt + (size_t)n0 * ldb;
  for (int k0 = 0; k0 < K; k0 += 32) {
#pragma unroll
    for (int c = 0; c < 2; ++c) {
      int off = wid * 1024 + c * 512 + lane * 8;
      int row = off >> 5, kk = off & 31;
      gload16(Ag + (size_t)row * lda + k0 + kk, &As[wid * 1024 + c * 512]);
      gload16(Bg + (size_t)row * ldb + k0 + kk, &Bs[wid * 1024 + c * 512]);
    }
    __syncthreads();
    bf16x8 av[4], bv[4];
#pragma unroll
    for (int m = 0; m < 4; ++m)
      av[m] = *(const bf16x8*)&As[(wr * 64 + m * 16 + fr) * 32 + fq * 8];
#pragma unroll
    for (int n = 0; n < 4; ++n)
      bv[n] = *(const bf16x8*)&Bs[(wc * 64 + n * 16 + fr) * 32 + fq * 8];
#pragma unroll
    for (int m = 0; m < 4; ++m)
#pragma unroll
      for (int n = 0; n < 4; ++n)
        acc[m][n] = __builtin_amdgcn_mfma_f32_16x16x32_bf16(av[m], bv[n],
                                                            acc[m][n], 0, 0, 0);
    __syncthreads();
  }
}

template <bool RELU, bool HASRES, bool OUTBF16>
__global__ __launch_bounds__(256) void gemm_bf16(
    const ushort* __restrict__ A, int lda, const ushort* __restrict__ Bt,
    int ldb, const float* __restrict__ bias, const float* __restrict__ res,
    void* __restrict__ Cout, int ldc, int K) {
  __shared__ __align__(16) ushort As[128 * 32];
  __shared__ __align__(16) ushort Bs[128 * 32];
  f32x4 acc[4][4] = {};
  int m0 = blockIdx.y * 128, n0 = blockIdx.x * 128;
  gemm_main(A, lda, Bt, ldb, K, m0, n0, As, Bs, acc);
  int lane = threadIdx.x & 63, wid = threadIdx.x >> 6;
  int wr = wid >> 1, wc = wid & 1, fr = lane & 15, fq = lane >> 4;
#pragma unroll
  for (int m = 0; m < 4; ++m) {
    int gm = m0 + wr * 64 + m * 16 + fq * 4;
#pragma unroll
    for (int n = 0; n < 4; ++n) {
      int gn = n0 + wc * 64 + n * 16 + fr;
      float bsv = bias[gn];
#pragma unroll
      for (int j = 0; j < 4; ++j) {
        int row = gm + j;
        float v = acc[m][n][j] + bsv;
        if constexpr (HASRES) v += res[(size_t)row * ldc + gn];
        if constexpr (RELU) v = fmaxf(v, 0.f);
        if constexpr (OUTBF16)
          ((ushort*)Cout)[(size_t)row * ldc + gn] = f2bf(v);
        else
          ((float*)Cout)[(size_t)row * ldc + gn] = v;
      }
    }
  }
}

// QKV GEMM: N-cols [0,1024)->Q rows, [1024,2048)->K rows, [2048,3072)->Vt
// transposed [B][H][HS][T]. Branch is uniform per 128-col block.
__global__ __launch_bounds__(256) void gemm_qkv(const ushort* __restrict__ A,
                                                const ushort* __restrict__ Bt,
                                                const float* __restrict__ bias,
                                                ushort* __restrict__ q,
                                                ushort* __restrict__ k,
                                                ushort* __restrict__ vt) {
  __shared__ __align__(16) ushort As[128 * 32];
  __shared__ __align__(16) ushort Bs[128 * 32];
  f32x4 acc[4][4] = {};
  int m0 = blockIdx.y * 128, n0 = blockIdx.x * 128;
  gemm_main(A, 1024, Bt, 1024, 1024, m0, n0, As, Bs, acc);
  int lane = threadIdx.x & 63, wid = threadIdx.x >> 6;
  int wr = wid >> 1, wc = wid & 1, fr = lane & 15, fq = lane >> 4;
#pragma unroll
  for (int m = 0; m < 4; ++m) {
    int gm = m0 + wr * 64 + m * 16 + fq * 4;
#pragma unroll
    for (int n = 0; n < 4; ++n) {
      int gn = n0 + wc * 64 + n * 16 + fr;
      float bsv = bias[gn];
#pragma unroll
      for (int j = 0; j < 4; ++j) {
        int row = gm + j;
        float v = acc[m][n][j] + bsv;
        ushort bvv = f2bf(v);
        if (gn < 1024) {
          q[(size_t)row * 1024 + gn] = bvv;
        } else if (gn < 2048) {
          k[(size_t)row * 1024 + (gn - 1024)] = bvv;
        } else {
          int dd = gn - 2048, h = dd >> 6, d = dd & 63;
          int bbr = row >> 11, t = row & 2047;
          vt[(((size_t)(bbr * 16 + h)) * 64 + d) * 2048 + t] = bvv;
        }
      }
    }
  }
}

// ---------------- MFMA flash attention ----------------
// Block: 256 thr = 4 waves; wave owns 32 q-rows; KV tile = 64.
// Swapped QK^T: S^T tile, lane holds q=fr, k=fq*4+reg. P routed through
// per-wave LDS ([32][64] bf16, XOR-swizzled rows). V staged transposed.
constexpr int QB = 128, KVB = 64;
__global__ __launch_bounds__(256) void attn_kernel(const ushort* __restrict__ Qb,
                                                   const ushort* __restrict__ Kb,
                                                   const ushort* __restrict__ Vt,
                                                   ushort* __restrict__ att) {
  __shared__ __align__(16) ushort Klds[64 * 64];  // [kv][d], rows XOR-swizzled
  __shared__ __align__(16) ushort Vlds[64 * 64];  // [d][kv], rows XOR-swizzled
  __shared__ __align__(16) ushort Plds[4][32 * 64];  // per-wave [q][k]
  int tid = threadIdx.x, wid = tid >> 6, lane = tid & 63;
  int fr = lane & 15, fq = lane >> 4;
  int bh = blockIdx.y, bb = bh >> 4, hh = bh & 15;
  int q0 = blockIdx.x * QB;
  int q0w = q0 + wid * 32;
  const float c = 1.4426950408889634f / 32.0f;  // log2e * C^-0.5

  // Q fragments in registers: lane holds Q[q=qs*16+fr][d=ds2*32+fq*8 ..+7]
  bf16x8 Qreg[2][2];
  {
    const ushort* qbase = Qb + ((size_t)bb * Tt) * Cc + hh * HSz;
#pragma unroll
    for (int qs = 0; qs < 2; ++qs)
#pragma unroll
      for (int d2 = 0; d2 < 2; ++d2)
        Qreg[qs][d2] = *(const bf16x8*)(qbase +
            (size_t)(q0w + qs * 16 + fr) * Cc + d2 * 32 + fq * 8);
  }
  f32x4 Oa[2][4] = {};  // [qs][ds]; lane holds O[q=fq*4+reg][d=fr]
  float mrow[2] = {-1e30f, -1e30f}, lrow[2] = {0.f, 0.f};

  const ushort* Kbase = Kb + ((size_t)bb * Tt) * Cc + hh * HSz;
  const ushort* Vbase = Vt + ((size_t)(bb * Hh + hh)) * HSz * Tt;
  int nt = q0 / KVB + 2;

  for (int kt = 0; kt < nt; ++kt) {
    int t0 = kt * KVB;
    __syncthreads();  // previous tile's LDS reads complete
    // stage K[64][64] and V^T[64][64]: linear LDS dest, inverse-swz source
#pragma unroll
    for (int cch = 0; cch < 2; ++cch) {
      int s = cch * 256 + tid;       // 16B slot index (512 total per matrix)
      int row = s >> 3;              // kv row (K) / d row (V)
      int b = (s & 7) * 16;          // byte offset within 128B row
      int sw = (b >> 1) ^ ((row & 7) << 3);  // swizzled ushort offset
      void* dst = (char*)Klds + (cch * 256 + wid * 64) * 16;
      gload16(Kbase + (size_t)(t0 + row) * Cc + sw, dst);
      void* dstv = (char*)Vlds + (cch * 256 + wid * 64) * 16;
      gload16(Vbase + (size_t)row * Tt + t0 + sw, dstv);
    }
    __syncthreads();
    if (q0w + 31 < t0) continue;  // wave fully masked (barrier counts match)

    // ---- QK^T swapped: accs[qs][ks] = S^T (16k x 16q) ----
    bf16x8 kf[4][2];
#pragma unroll
    for (int ks = 0; ks < 4; ++ks)
#pragma unroll
      for (int d2 = 0; d2 < 2; ++d2) {
        int row = ks * 16 + fr;
        int off = (d2 * 64 + fq * 16) ^ ((row & 7) << 4);
        kf[ks][d2] = *(const bf16x8*)((const char*)Klds + row * 128 + off);
      }
    f32x4 accs[2][4] = {};
#pragma unroll
    for (int qs = 0; qs < 2; ++qs)
#pragma unroll
      for (int ks = 0; ks < 4; ++ks) {
        accs[qs][ks] = __builtin_amdgcn_mfma_f32_16x16x32_bf16(
            kf[ks][0], Qreg[qs][0], accs[qs][ks], 0, 0, 0);
        accs[qs][ks] = __builtin_amdgcn_mfma_f32_16x16x32_bf16(
            kf[ks][1], Qreg[qs][1], accs[qs][ks], 0, 0, 0);
      }

    // ---- softmax (per qs): row q=fr spread over 4 fq lanes ----
#pragma unroll
    for (int qs = 0; qs < 2; ++qs) {
      int qg = q0w + qs * 16 + fr;
      float sv[4][4];
      float vmax = -1e30f;
#pragma unroll
      for (int ks = 0; ks < 4; ++ks)
#pragma unroll
        for (int j = 0; j < 4; ++j) {
          int kg = t0 + ks * 16 + fq * 4 + j;
          float s = accs[qs][ks][j] * c;
          s = (kg <= qg) ? s : -1e30f;
          sv[ks][j] = s;
          vmax = fmaxf(vmax, s);
        }
      vmax = fmaxf(vmax, __shfl_xor(vmax, 16));
      vmax = fmaxf(vmax, __shfl_xor(vmax, 32));
      float mnew = fmaxf(mrow[qs], vmax);
      float sf = exp2f(mrow[qs] - mnew);
      mrow[qs] = mnew;
      float ls = 0.f;
      int qrow = qs * 16 + fr;
      char* pbase = (char*)Plds[wid] + qrow * 128;
#pragma unroll
      for (int ks = 0; ks < 4; ++ks) {
        float p0 = exp2f(sv[ks][0] - mnew);
        float p1 = exp2f(sv[ks][1] - mnew);
        float p2 = exp2f(sv[ks][2] - mnew);
        float p3 = exp2f(sv[ks][3] - mnew);
        ls += (p0 + p1) + (p2 + p3);
        ushort4 pw = {f2bf(p0), f2bf(p1), f2bf(p2), f2bf(p3)};
        int off = (ks * 32 + fq * 8) ^ ((qrow & 7) << 4);
        *(ushort4*)(pbase + off) = pw;
      }
      ls += __shfl_xor(ls, 16);
      ls += __shfl_xor(ls, 32);
      lrow[qs] = lrow[qs] * sf + ls;
      // rescale O (O rows are q=fq*4+j -> fetch sf from lane fq*4+j)
#pragma unroll
      for (int j = 0; j < 4; ++j) {
        float sfo = __shfl(sf, fq * 4 + j);
#pragma unroll
        for (int ds = 0; ds < 4; ++ds) Oa[qs][ds][j] *= sfo;
      }
    }

    // ---- PV: O += P(32q x 64k) * V(64k x 64d) ----
    bf16x8 vf[4][2];
#pragma unroll
    for (int ds = 0; ds < 4; ++ds)
#pragma unroll
      for (int k2 = 0; k2 < 2; ++k2) {
        int row = ds * 16 + fr;
        int off = (k2 * 64 + fq * 16) ^ ((row & 7) << 4);
        vf[ds][k2] = *(const bf16x8*)((const char*)Vlds + row * 128 + off);
      }
#pragma unroll
    for (int qs = 0; qs < 2; ++qs) {
      int qrow = qs * 16 + fr;
      bf16x8 pf[2];
#pragma unroll
      for (int k2 = 0; k2 < 2; ++k2) {
        int off = (k2 * 64 + fq * 16) ^ ((qrow & 7) << 4);
        pf[k2] = *(const bf16x8*)((const char*)Plds[wid] + qrow * 128 + off);
      }
#pragma unroll
      for (int ds = 0; ds < 4; ++ds) {
        Oa[qs][ds] = __builtin_amdgcn_mfma_f32_16x16x32_bf16(pf[0], vf[ds][0],
                                                             Oa[qs][ds], 0, 0, 0);
        Oa[qs][ds] = __builtin_amdgcn_mfma_f32_16x16x32_bf16(pf[1], vf[ds][1],
                                                             Oa[qs][ds], 0, 0, 0);
      }
    }
  }

  // ---- epilogue: normalize by l (redistribute across lanes), write bf16 ----
#pragma unroll
  for (int qs = 0; qs < 2; ++qs) {
    float linv = 1.f / lrow[qs];
#pragma unroll
    for (int j = 0; j < 4; ++j) {
      float lo = __shfl(linv, fq * 4 + j);
      int qg = q0w + qs * 16 + fq * 4 + j;
      ushort* orow = att + (size_t)(bb * Tt + qg) * Cc + hh * HSz;
#pragma unroll
      for (int ds = 0; ds < 4; ++ds)
        orow[ds * 16 + fr] = f2bf(Oa[qs][ds][j] * lo);
    }
  }
}

extern "C" void kernel_launch(void* const* d_in, const int* in_sizes, int n_in,
                              void* d_out, int out_size, void* d_ws,
                              size_t ws_size, hipStream_t stream) {
  const float* x = (const float*)d_in[0];
  const float* wq = (const float*)d_in[1];
  const float* bq = (const float*)d_in[2];
  const float* wk = (const float*)d_in[3];
  const float* bk = (const float*)d_in[4];
  const float* wv = (const float*)d_in[5];
  const float* bv = (const float*)d_in[6];
  const float* wp = (const float*)d_in[7];
  const float* bp = (const float*)d_in[8];
  const float* w1 = (const float*)d_in[9];
  const float* b1 = (const float*)d_in[10];
  const float* w2 = (const float*)d_in[11];
  const float* b2 = (const float*)d_in[12];
  const float* g1 = (const float*)d_in[13];
  const float* be1 = (const float*)d_in[14];
  const float* g2 = (const float*)d_in[15];
  const float* be2 = (const float*)d_in[16];
  float* out = (float*)d_out;

  ushort* Qb = (ushort*)d_ws;                 // [8192][1024]
  ushort* Kb = Qb + (size_t)8388608;          // [8192][1024]
  ushort* Vt = Kb + (size_t)8388608;          // [4][16][64][2048]
  ushort* att = Vt + (size_t)8388608;         // [8192][1024]
  ushort* ffh = Qb;                           // [8192][4096] overlay
  ushort* h1b = att + (size_t)8388608;        // LN1/LN2 out
  float* x2 = (float*)(h1b + (size_t)8388608);
  ushort* wqkvT = (ushort*)(x2 + (size_t)8388608);  // [3072][1024]
  ushort* wpT = wqkvT + (size_t)3145728;            // [1024][1024]
  ushort* w1T = wpT + (size_t)1048576;              // [4096][1024]
  ushort* w2T = w1T + (size_t)4194304;              // [1024][4096]
  float* bqkv = (float*)(w2T + (size_t)4194304);    // [3072]

  tcast_qkv<<<dim3(32, 2, 48), 256, 0, stream>>>(wq, wk, wv, wqkvT);
  tcast_kernel<<<dim3(32, 32), 256, 0, stream>>>(wp, wpT, 1024, 1024);
  tcast_kernel<<<dim3(32, 128), 256, 0, stream>>>(w1, w1T, 4096, 1024);
  tcast_kernel<<<dim3(128, 32), 256, 0, stream>>>(w2, w2T, 1024, 4096);
  bias_concat<<<dim3(12), 256, 0, stream>>>(bq, bk, bv, bqkv);

  // 1) h1b = LN(x)
  ln_kernel<<<dim3(Mrows), 256, 0, stream>>>(x, g1, be1, h1b);
  // 2) Q,K,Vt = h1b @ WqkvT^T + bqkv (V written transposed)
  gemm_qkv<<<dim3(24, 64), 256, 0, stream>>>(h1b, wqkvT, bqkv, Qb, Kb, Vt);
  // 3) att = causal_softmax(Q K^T / 32) V
  attn_kernel<<<dim3(Tt / QB, Bb * Hh), 256, 0, stream>>>(Qb, Kb, Vt, att);
  // 4) x2 = x + att @ wp + bp
  gemm_bf16<false, true, false><<<dim3(8, 64), 256, 0, stream>>>(
      att, 1024, wpT, 1024, bp, x, x2, 1024, 1024);
  // 5) h2b = LN(x2)
  ln_kernel<<<dim3(Mrows), 256, 0, stream>>>(x2, g2, be2, h1b);
  // 6) ffh = relu(h2b @ w1 + b1)
  gemm_bf16<true, false, true><<<dim3(32, 64), 256, 0, stream>>>(
      h1b, 1024, w1T, 1024, b1, nullptr, ffh, 4096, 1024);
  // 7) out = x2 + ffh @ w2 + b2
  gemm_bf16<false, true, false><<<dim3(8, 64), 256, 0, stream>>>(
      ffh, 4096, w2T, 4096, b2, x2, out, 1024, 4096);
}

// Round 4
// 465.807 us; speedup vs baseline: 10.1974x; 1.1960x over previous
//
#include <hip/hip_runtime.h>

// Transformer block. Round 3: attention load-balancing (paired causal tiles,
// uniform 34 KV-tiles/block), T13 defer-rescale, T5 setprio; coalesced Vt
// stores in the QKV GEMM epilogue. GEMM mainloops unchanged (m97 structure).
//
// Workspace (~136 MiB):
//   [Q 16M | K 16M | Vt 16M | att 16M]  <- ffh bf16 64M overlays exactly
//   [h1b 16M][x2 f32 32M][wqkvT 6M][wpT 2M][w1T 8M][w2T 8M][bqkv]

constexpr int Bb = 4, Tt = 2048, Cc = 1024, Hh = 16, HSz = 64, Ff = 4096;
constexpr int Mrows = Bb * Tt;  // 8192

typedef __attribute__((ext_vector_type(8))) short bf16x8;
typedef __attribute__((ext_vector_type(4))) float f32x4;

__device__ __forceinline__ ushort f2bf(float f) {
  uint u = __builtin_bit_cast(uint, f);
  uint r = (u + 0x7fffu + ((u >> 16) & 1u)) >> 16;
  return (ushort)r;
}
__device__ __forceinline__ float bf2f(ushort s) {
  return __builtin_bit_cast(float, ((uint)s) << 16);
}
__device__ __forceinline__ void gload16(const void* g, void* l) {
  __builtin_amdgcn_global_load_lds(
      (const __attribute__((address_space(1))) void*)g,
      (__attribute__((address_space(3))) void*)l, 16, 0, 0);
}

// ---------------- LayerNorm: fp32 in, bf16 out ----------------
__global__ __launch_bounds__(256) void ln_kernel(const float* __restrict__ x,
                                                 const float* __restrict__ g,
                                                 const float* __restrict__ b,
                                                 ushort* __restrict__ out) {
  int row = blockIdx.x;
  const float* xr = x + (size_t)row * Cc;
  int c4 = threadIdx.x * 4;
  float4 v = *(const float4*)(xr + c4);
  float s1 = v.x + v.y + v.z + v.w;
  float s2 = v.x * v.x + v.y * v.y + v.z * v.z + v.w * v.w;
#pragma unroll
  for (int off = 32; off >= 1; off >>= 1) {
    s1 += __shfl_xor(s1, off);
    s2 += __shfl_xor(s2, off);
  }
  __shared__ float red[8];
  int wid = threadIdx.x >> 6, lane = threadIdx.x & 63;
  if (lane == 0) { red[wid] = s1; red[4 + wid] = s2; }
  __syncthreads();
  float t1 = red[0] + red[1] + red[2] + red[3];
  float t2 = red[4] + red[5] + red[6] + red[7];
  float mu = t1 * (1.0f / Cc);
  float var = t2 * (1.0f / Cc) - mu * mu;
  float rs = rsqrtf(var + 1e-5f);
  float4 gv = *(const float4*)(g + c4);
  float4 bv = *(const float4*)(b + c4);
  ushort4 o;
  o.x = f2bf((v.x - mu) * rs * gv.x + bv.x);
  o.y = f2bf((v.y - mu) * rs * gv.y + bv.y);
  o.z = f2bf((v.z - mu) * rs * gv.z + bv.z);
  o.w = f2bf((v.w - mu) * rs * gv.w + bv.w);
  *(ushort4*)(out + (size_t)row * Cc + c4) = o;
}

// ---------------- Transpose-cast fp32 [R][C] -> bf16 [C][R] ----------------
__device__ __forceinline__ void tcast_body(const float* __restrict__ src,
                                           ushort* __restrict__ dst, int ldS,
                                           int ldD, int r0, int c0) {
  __shared__ float t[32][33];
  int c = threadIdx.x & 31, r8 = threadIdx.x >> 5;
#pragma unroll
  for (int i = 0; i < 4; ++i) {
    int r = r8 + i * 8;
    t[r][c] = src[(size_t)(r0 + r) * ldS + c0 + c];
  }
  __syncthreads();
#pragma unroll
  for (int i = 0; i < 4; ++i) {
    int rr = r8 + i * 8;
    dst[(size_t)(c0 + rr) * ldD + r0 + c] = f2bf(t[c][rr]);
  }
}

__global__ __launch_bounds__(256) void tcast_kernel(const float* __restrict__ src,
                                                    ushort* __restrict__ dst,
                                                    int ldS, int ldD) {
  tcast_body(src, dst, ldS, ldD, blockIdx.x * 32, blockIdx.y * 32);
}

__global__ __launch_bounds__(256) void tcast_qkv(const float* __restrict__ wq,
                                                 const float* __restrict__ wk,
                                                 const float* __restrict__ wv,
                                                 ushort* __restrict__ dst) {
  int z = blockIdx.z, zz = z >> 4, h = z & 15;
  const float* src = (zz == 0 ? wq : (zz == 1 ? wk : wv)) + (size_t)h * Cc * HSz;
  ushort* d = dst + (size_t)(zz * 1024 + h * 64) * 1024;
  tcast_body(src, d, HSz, Cc, blockIdx.x * 32, blockIdx.y * 32);
}

__global__ __launch_bounds__(256) void bias_concat(const float* __restrict__ bq,
                                                   const float* __restrict__ bk,
                                                   const float* __restrict__ bv,
                                                   float* __restrict__ dst) {
  int i = blockIdx.x * 256 + threadIdx.x;
  dst[i] = i < 1024 ? bq[i] : (i < 2048 ? bk[i - 1024] : bv[i - 2048]);
}

// ---------------- bf16 MFMA GEMM mainloop (128x128, BK=32) ----------------
__device__ __forceinline__ void gemm_main(const ushort* __restrict__ A, int lda,
                                          const ushort* __restrict__ Bt, int ldb,
                                          int K, int m0, int n0,
                                          ushort* __restrict__ As,
                                          ushort* __restrict__ Bs,
                                          f32x4 (&acc)[4][4]) {
  int tid = threadIdx.x, wid = tid >> 6, lane = tid & 63;
  int wr = wid >> 1, wc = wid & 1, fr = lane & 15, fq = lane >> 4;
  const ushort* Ag = A + (size_t)m0 * lda;
  const ushort* Bg = Bt + (size_t)n0 * ldb;
  for (int k0 = 0; k0 < K; k0 += 32) {
#pragma unroll
    for (int c = 0; c < 2; ++c) {
      int off = wid * 1024 + c * 512 + lane * 8;
      int row = off >> 5, kk = off & 31;
      gload16(Ag + (size_t)row * lda + k0 + kk, &As[wid * 1024 + c * 512]);
      gload16(Bg + (size_t)row * ldb + k0 + kk, &Bs[wid * 1024 + c * 512]);
    }
    __syncthreads();
    bf16x8 av[4], bv[4];
#pragma unroll
    for (int m = 0; m < 4; ++m)
      av[m] = *(const bf16x8*)&As[(wr * 64 + m * 16 + fr) * 32 + fq * 8];
#pragma unroll
    for (int n = 0; n < 4; ++n)
      bv[n] = *(const bf16x8*)&Bs[(wc * 64 + n * 16 + fr) * 32 + fq * 8];
#pragma unroll
    for (int m = 0; m < 4; ++m)
#pragma unroll
      for (int n = 0; n < 4; ++n)
        acc[m][n] = __builtin_amdgcn_mfma_f32_16x16x32_bf16(av[m], bv[n],
                                                            acc[m][n], 0, 0, 0);
    __syncthreads();
  }
}

template <bool RELU, bool HASRES, bool OUTBF16>
__global__ __launch_bounds__(256) void gemm_bf16(
    const ushort* __restrict__ A, int lda, const ushort* __restrict__ Bt,
    int ldb, const float* __restrict__ bias, const float* __restrict__ res,
    void* __restrict__ Cout, int ldc, int K) {
  __shared__ __align__(16) ushort As[128 * 32];
  __shared__ __align__(16) ushort Bs[128 * 32];
  f32x4 acc[4][4] = {};
  int m0 = blockIdx.y * 128, n0 = blockIdx.x * 128;
  gemm_main(A, lda, Bt, ldb, K, m0, n0, As, Bs, acc);
  int lane = threadIdx.x & 63, wid = threadIdx.x >> 6;
  int wr = wid >> 1, wc = wid & 1, fr = lane & 15, fq = lane >> 4;
#pragma unroll
  for (int m = 0; m < 4; ++m) {
    int gm = m0 + wr * 64 + m * 16 + fq * 4;
#pragma unroll
    for (int n = 0; n < 4; ++n) {
      int gn = n0 + wc * 64 + n * 16 + fr;
      float bsv = bias[gn];
#pragma unroll
      for (int j = 0; j < 4; ++j) {
        int row = gm + j;
        float v = acc[m][n][j] + bsv;
        if constexpr (HASRES) v += res[(size_t)row * ldc + gn];
        if constexpr (RELU) v = fmaxf(v, 0.f);
        if constexpr (OUTBF16)
          ((ushort*)Cout)[(size_t)row * ldc + gn] = f2bf(v);
        else
          ((float*)Cout)[(size_t)row * ldc + gn] = v;
      }
    }
  }
}

// QKV GEMM: N-cols [0,1024)->Q, [1024,2048)->K, [2048,3072)->Vt transposed
// [B][H][HS][T]. Branch uniform per 128-col block. Vt: j-values are
// t-contiguous -> ushort4 stores (coalesced 32B/fq-group).
__global__ __launch_bounds__(256) void gemm_qkv(const ushort* __restrict__ A,
                                                const ushort* __restrict__ Bt,
                                                const float* __restrict__ bias,
                                                ushort* __restrict__ q,
                                                ushort* __restrict__ k,
                                                ushort* __restrict__ vt) {
  __shared__ __align__(16) ushort As[128 * 32];
  __shared__ __align__(16) ushort Bs[128 * 32];
  f32x4 acc[4][4] = {};
  int m0 = blockIdx.y * 128, n0 = blockIdx.x * 128;
  gemm_main(A, 1024, Bt, 1024, 1024, m0, n0, As, Bs, acc);
  int lane = threadIdx.x & 63, wid = threadIdx.x >> 6;
  int wr = wid >> 1, wc = wid & 1, fr = lane & 15, fq = lane >> 4;
#pragma unroll
  for (int m = 0; m < 4; ++m) {
    int gm = m0 + wr * 64 + m * 16 + fq * 4;
#pragma unroll
    for (int n = 0; n < 4; ++n) {
      int gn = n0 + wc * 64 + n * 16 + fr;
      float bsv = bias[gn];
      if (gn < 2048) {
        ushort* dst = gn < 1024 ? q : k;
        int col = gn & 1023;
#pragma unroll
        for (int j = 0; j < 4; ++j)
          dst[(size_t)(gm + j) * 1024 + col] = f2bf(acc[m][n][j] + bsv);
      } else {
        int dd = gn - 2048, h = dd >> 6, d = dd & 63;
        int bbr = gm >> 11, t = gm & 2047;
        ushort4 pw = {f2bf(acc[m][n][0] + bsv), f2bf(acc[m][n][1] + bsv),
                      f2bf(acc[m][n][2] + bsv), f2bf(acc[m][n][3] + bsv)};
        *(ushort4*)&vt[(((size_t)(bbr * 16 + h)) * 64 + d) * 2048 + t] = pw;
      }
    }
  }
}

// ---------------- MFMA flash attention (pair-balanced) ----------------
// grid (8, 64): block handles q-tiles {pair, 15-pair} -> uniform 34 KV-tiles.
// 4 waves; wave owns 32 q-rows. Swapped QK^T; P via swizzled per-wave LDS;
// V staged transposed. Defer-rescale (THR=11 log2); setprio around MFMA.
constexpr int QB = 128, KVB = 64;
__global__ __launch_bounds__(256) void attn_kernel(const ushort* __restrict__ Qb,
                                                   const ushort* __restrict__ Kb,
                                                   const ushort* __restrict__ Vt,
                                                   ushort* __restrict__ att) {
  __shared__ __align__(16) ushort Klds[64 * 64];  // [kv][d], rows XOR-swizzled
  __shared__ __align__(16) ushort Vlds[64 * 64];  // [d][kv], rows XOR-swizzled
  __shared__ __align__(16) ushort Plds[4][32 * 64];  // per-wave [q][k]
  int tid = threadIdx.x, wid = tid >> 6, lane = tid & 63;
  int fr = lane & 15, fq = lane >> 4;
  int bh = blockIdx.y, bb = bh >> 4, hh = bh & 15;
  const float c = 1.4426950408889634f / 32.0f;  // log2e * C^-0.5
  const ushort* qkbase = Qb + ((size_t)bb * Tt) * Cc + hh * HSz;
  const ushort* Kbase = Kb + ((size_t)bb * Tt) * Cc + hh * HSz;
  const ushort* Vbase = Vt + ((size_t)(bb * Hh + hh)) * HSz * Tt;

#pragma unroll 1
  for (int pass = 0; pass < 2; ++pass) {
    int qt = pass ? (Tt / QB - 1 - (int)blockIdx.x) : (int)blockIdx.x;
    int q0 = qt * QB;
    int q0w = q0 + wid * 32;

    bf16x8 Qreg[2][2];
#pragma unroll
    for (int qs = 0; qs < 2; ++qs)
#pragma unroll
      for (int d2 = 0; d2 < 2; ++d2)
        Qreg[qs][d2] = *(const bf16x8*)(qkbase +
            (size_t)(q0w + qs * 16 + fr) * Cc + d2 * 32 + fq * 8);
    f32x4 Oa[2][4] = {};  // [qs][ds]; lane holds O[q=fq*4+reg][d=fr]
    float mrow[2] = {-1e30f, -1e30f}, lrow[2] = {0.f, 0.f};
    int nt = q0 / KVB + 2;

    for (int kt = 0; kt < nt; ++kt) {
      int t0 = kt * KVB;
      __syncthreads();  // previous tile's LDS reads complete
#pragma unroll
      for (int cch = 0; cch < 2; ++cch) {
        int s = cch * 256 + tid;
        int row = s >> 3;
        int b = (s & 7) * 16;
        int sw = (b >> 1) ^ ((row & 7) << 3);  // inverse-swz source (ushort)
        void* dst = (char*)Klds + (cch * 256 + wid * 64) * 16;
        gload16(Kbase + (size_t)(t0 + row) * Cc + sw, dst);
        void* dstv = (char*)Vlds + (cch * 256 + wid * 64) * 16;
        gload16(Vbase + (size_t)row * Tt + t0 + sw, dstv);
      }
      __syncthreads();
      if (q0w + 31 < t0) continue;  // wave fully masked

      // ---- QK^T swapped: accs[qs][ks] = S^T (16k x 16q) ----
      bf16x8 kf[4][2];
#pragma unroll
      for (int ks = 0; ks < 4; ++ks)
#pragma unroll
        for (int d2 = 0; d2 < 2; ++d2) {
          int row = ks * 16 + fr;
          int off = (d2 * 64 + fq * 16) ^ ((row & 7) << 4);
          kf[ks][d2] = *(const bf16x8*)((const char*)Klds + row * 128 + off);
        }
      f32x4 accs[2][4] = {};
      __builtin_amdgcn_s_setprio(1);
#pragma unroll
      for (int qs = 0; qs < 2; ++qs)
#pragma unroll
        for (int ks = 0; ks < 4; ++ks) {
          accs[qs][ks] = __builtin_amdgcn_mfma_f32_16x16x32_bf16(
              kf[ks][0], Qreg[qs][0], accs[qs][ks], 0, 0, 0);
          accs[qs][ks] = __builtin_amdgcn_mfma_f32_16x16x32_bf16(
              kf[ks][1], Qreg[qs][1], accs[qs][ks], 0, 0, 0);
        }
      __builtin_amdgcn_s_setprio(0);

      // ---- softmax (per qs): row q=fr spread over 4 fq lanes ----
#pragma unroll
      for (int qs = 0; qs < 2; ++qs) {
        int qg = q0w + qs * 16 + fr;
        float sv[4][4];
        float vmax = -1e30f;
#pragma unroll
        for (int ks = 0; ks < 4; ++ks)
#pragma unroll
          for (int j = 0; j < 4; ++j) {
            int kg = t0 + ks * 16 + fq * 4 + j;
            float s = accs[qs][ks][j] * c;
            s = (kg <= qg) ? s : -1e30f;
            sv[ks][j] = s;
            vmax = fmaxf(vmax, s);
          }
        vmax = fmaxf(vmax, __shfl_xor(vmax, 16));
        vmax = fmaxf(vmax, __shfl_xor(vmax, 32));
        // T13 defer-rescale: only rescale when some row's max grew > THR
        float mnew = mrow[qs];
        if (!__all(vmax <= mnew + 11.0f)) {
          mnew = fmaxf(mrow[qs], vmax);
          float sf = exp2f(mrow[qs] - mnew);
          mrow[qs] = mnew;
          lrow[qs] *= sf;
#pragma unroll
          for (int j = 0; j < 4; ++j) {
            float sfo = __shfl(sf, fq * 4 + j);
#pragma unroll
            for (int ds = 0; ds < 4; ++ds) Oa[qs][ds][j] *= sfo;
          }
        }
        float ls = 0.f;
        int qrow = qs * 16 + fr;
        char* pbase = (char*)Plds[wid] + qrow * 128;
#pragma unroll
        for (int ks = 0; ks < 4; ++ks) {
          float p0 = exp2f(sv[ks][0] - mnew);
          float p1 = exp2f(sv[ks][1] - mnew);
          float p2 = exp2f(sv[ks][2] - mnew);
          float p3 = exp2f(sv[ks][3] - mnew);
          ls += (p0 + p1) + (p2 + p3);
          ushort4 pw = {f2bf(p0), f2bf(p1), f2bf(p2), f2bf(p3)};
          int off = (ks * 32 + fq * 8) ^ ((qrow & 7) << 4);
          *(ushort4*)(pbase + off) = pw;
        }
        ls += __shfl_xor(ls, 16);
        ls += __shfl_xor(ls, 32);
        lrow[qs] += ls;
      }

      // ---- PV: O += P(32q x 64k) * V(64k x 64d) ----
      bf16x8 vf[4][2];
#pragma unroll
      for (int ds = 0; ds < 4; ++ds)
#pragma unroll
        for (int k2 = 0; k2 < 2; ++k2) {
          int row = ds * 16 + fr;
          int off = (k2 * 64 + fq * 16) ^ ((row & 7) << 4);
          vf[ds][k2] = *(const bf16x8*)((const char*)Vlds + row * 128 + off);
        }
      __builtin_amdgcn_s_setprio(1);
#pragma unroll
      for (int qs = 0; qs < 2; ++qs) {
        int qrow = qs * 16 + fr;
        bf16x8 pf[2];
#pragma unroll
        for (int k2 = 0; k2 < 2; ++k2) {
          int off = (k2 * 64 + fq * 16) ^ ((qrow & 7) << 4);
          pf[k2] = *(const bf16x8*)((const char*)Plds[wid] + qrow * 128 + off);
        }
#pragma unroll
        for (int ds = 0; ds < 4; ++ds) {
          Oa[qs][ds] = __builtin_amdgcn_mfma_f32_16x16x32_bf16(
              pf[0], vf[ds][0], Oa[qs][ds], 0, 0, 0);
          Oa[qs][ds] = __builtin_amdgcn_mfma_f32_16x16x32_bf16(
              pf[1], vf[ds][1], Oa[qs][ds], 0, 0, 0);
        }
      }
      __builtin_amdgcn_s_setprio(0);
    }

    // ---- epilogue ----
#pragma unroll
    for (int qs = 0; qs < 2; ++qs) {
      float linv = 1.f / lrow[qs];
#pragma unroll
      for (int j = 0; j < 4; ++j) {
        float lo = __shfl(linv, fq * 4 + j);
        int qg = q0w + qs * 16 + fq * 4 + j;
        ushort* orow = att + (size_t)(bb * Tt + qg) * Cc + hh * HSz;
#pragma unroll
        for (int ds = 0; ds < 4; ++ds)
          orow[ds * 16 + fr] = f2bf(Oa[qs][ds][j] * lo);
      }
    }
  }
}

extern "C" void kernel_launch(void* const* d_in, const int* in_sizes, int n_in,
                              void* d_out, int out_size, void* d_ws,
                              size_t ws_size, hipStream_t stream) {
  const float* x = (const float*)d_in[0];
  const float* wq = (const float*)d_in[1];
  const float* bq = (const float*)d_in[2];
  const float* wk = (const float*)d_in[3];
  const float* bk = (const float*)d_in[4];
  const float* wv = (const float*)d_in[5];
  const float* bv = (const float*)d_in[6];
  const float* wp = (const float*)d_in[7];
  const float* bp = (const float*)d_in[8];
  const float* w1 = (const float*)d_in[9];
  const float* b1 = (const float*)d_in[10];
  const float* w2 = (const float*)d_in[11];
  const float* b2 = (const float*)d_in[12];
  const float* g1 = (const float*)d_in[13];
  const float* be1 = (const float*)d_in[14];
  const float* g2 = (const float*)d_in[15];
  const float* be2 = (const float*)d_in[16];
  float* out = (float*)d_out;

  ushort* Qb = (ushort*)d_ws;                 // [8192][1024]
  ushort* Kb = Qb + (size_t)8388608;          // [8192][1024]
  ushort* Vt = Kb + (size_t)8388608;          // [4][16][64][2048]
  ushort* att = Vt + (size_t)8388608;         // [8192][1024]
  ushort* ffh = Qb;                           // [8192][4096] overlay
  ushort* h1b = att + (size_t)8388608;        // LN1/LN2 out
  float* x2 = (float*)(h1b + (size_t)8388608);
  ushort* wqkvT = (ushort*)(x2 + (size_t)8388608);  // [3072][1024]
  ushort* wpT = wqkvT + (size_t)3145728;            // [1024][1024]
  ushort* w1T = wpT + (size_t)1048576;              // [4096][1024]
  ushort* w2T = w1T + (size_t)4194304;              // [1024][4096]
  float* bqkv = (float*)(w2T + (size_t)4194304);    // [3072]

  tcast_qkv<<<dim3(32, 2, 48), 256, 0, stream>>>(wq, wk, wv, wqkvT);
  tcast_kernel<<<dim3(32, 32), 256, 0, stream>>>(wp, wpT, 1024, 1024);
  tcast_kernel<<<dim3(32, 128), 256, 0, stream>>>(w1, w1T, 4096, 1024);
  tcast_kernel<<<dim3(128, 32), 256, 0, stream>>>(w2, w2T, 1024, 4096);
  bias_concat<<<dim3(12), 256, 0, stream>>>(bq, bk, bv, bqkv);

  // 1) h1b = LN(x)
  ln_kernel<<<dim3(Mrows), 256, 0, stream>>>(x, g1, be1, h1b);
  // 2) Q,K,Vt = h1b @ WqkvT^T + bqkv (V written transposed)
  gemm_qkv<<<dim3(24, 64), 256, 0, stream>>>(h1b, wqkvT, bqkv, Qb, Kb, Vt);
  // 3) att = causal_softmax(Q K^T / 32) V  (paired q-tiles)
  attn_kernel<<<dim3(Tt / QB / 2, Bb * Hh), 256, 0, stream>>>(Qb, Kb, Vt, att);
  // 4) x2 = x + att @ wp + bp
  gemm_bf16<false, true, false><<<dim3(8, 64), 256, 0, stream>>>(
      att, 1024, wpT, 1024, bp, x, x2, 1024, 1024);
  // 5) h2b = LN(x2)
  ln_kernel<<<dim3(Mrows), 256, 0, stream>>>(x2, g2, be2, h1b);
  // 6) ffh = relu(h2b @ w1 + b1)
  gemm_bf16<true, false, true><<<dim3(32, 64), 256, 0, stream>>>(
      h1b, 1024, w1T, 1024, b1, nullptr, ffh, 4096, 1024);
  // 7) out = x2 + ffh @ w2 + b2
  gemm_bf16<false, true, false><<<dim3(8, 64), 256, 0, stream>>>(
      ffh, 4096, w2T, 4096, b2, x2, out, 1024, 4096);
}

// Round 5
// 394.593 us; speedup vs baseline: 12.0377x; 1.1805x over previous
//
#include <hip/hip_runtime.h>

// Transformer block. Round 4: GEMM upgrade — 8 waves/block (2x4), BK=64,
// XOR-swizzled LDS (conflict-free ds_read_b128), XCD-chunked block swizzle.
// Attention unchanged (round-3 pair-balanced MFMA flash).
//
// Workspace (~136 MiB):
//   [Q 16M | K 16M | Vt 16M | att 16M]  <- ffh bf16 64M overlays exactly
//   [h1b 16M][x2 f32 32M][wqkvT 6M][wpT 2M][w1T 8M][w2T 8M][bqkv]

constexpr int Bb = 4, Tt = 2048, Cc = 1024, Hh = 16, HSz = 64, Ff = 4096;
constexpr int Mrows = Bb * Tt;  // 8192

typedef __attribute__((ext_vector_type(8))) short bf16x8;
typedef __attribute__((ext_vector_type(4))) float f32x4;

__device__ __forceinline__ ushort f2bf(float f) {
  uint u = __builtin_bit_cast(uint, f);
  uint r = (u + 0x7fffu + ((u >> 16) & 1u)) >> 16;
  return (ushort)r;
}
__device__ __forceinline__ float bf2f(ushort s) {
  return __builtin_bit_cast(float, ((uint)s) << 16);
}
__device__ __forceinline__ void gload16(const void* g, void* l) {
  __builtin_amdgcn_global_load_lds(
      (const __attribute__((address_space(1))) void*)g,
      (__attribute__((address_space(3))) void*)l, 16, 0, 0);
}

// ---------------- LayerNorm: fp32 in, bf16 out ----------------
__global__ __launch_bounds__(256) void ln_kernel(const float* __restrict__ x,
                                                 const float* __restrict__ g,
                                                 const float* __restrict__ b,
                                                 ushort* __restrict__ out) {
  int row = blockIdx.x;
  const float* xr = x + (size_t)row * Cc;
  int c4 = threadIdx.x * 4;
  float4 v = *(const float4*)(xr + c4);
  float s1 = v.x + v.y + v.z + v.w;
  float s2 = v.x * v.x + v.y * v.y + v.z * v.z + v.w * v.w;
#pragma unroll
  for (int off = 32; off >= 1; off >>= 1) {
    s1 += __shfl_xor(s1, off);
    s2 += __shfl_xor(s2, off);
  }
  __shared__ float red[8];
  int wid = threadIdx.x >> 6, lane = threadIdx.x & 63;
  if (lane == 0) { red[wid] = s1; red[4 + wid] = s2; }
  __syncthreads();
  float t1 = red[0] + red[1] + red[2] + red[3];
  float t2 = red[4] + red[5] + red[6] + red[7];
  float mu = t1 * (1.0f / Cc);
  float var = t2 * (1.0f / Cc) - mu * mu;
  float rs = rsqrtf(var + 1e-5f);
  float4 gv = *(const float4*)(g + c4);
  float4 bv = *(const float4*)(b + c4);
  ushort4 o;
  o.x = f2bf((v.x - mu) * rs * gv.x + bv.x);
  o.y = f2bf((v.y - mu) * rs * gv.y + bv.y);
  o.z = f2bf((v.z - mu) * rs * gv.z + bv.z);
  o.w = f2bf((v.w - mu) * rs * gv.w + bv.w);
  *(ushort4*)(out + (size_t)row * Cc + c4) = o;
}

// ---------------- Transpose-cast fp32 [R][C] -> bf16 [C][R] ----------------
__device__ __forceinline__ void tcast_body(const float* __restrict__ src,
                                           ushort* __restrict__ dst, int ldS,
                                           int ldD, int r0, int c0) {
  __shared__ float t[32][33];
  int c = threadIdx.x & 31, r8 = threadIdx.x >> 5;
#pragma unroll
  for (int i = 0; i < 4; ++i) {
    int r = r8 + i * 8;
    t[r][c] = src[(size_t)(r0 + r) * ldS + c0 + c];
  }
  __syncthreads();
#pragma unroll
  for (int i = 0; i < 4; ++i) {
    int rr = r8 + i * 8;
    dst[(size_t)(c0 + rr) * ldD + r0 + c] = f2bf(t[c][rr]);
  }
}

__global__ __launch_bounds__(256) void tcast_kernel(const float* __restrict__ src,
                                                    ushort* __restrict__ dst,
                                                    int ldS, int ldD) {
  tcast_body(src, dst, ldS, ldD, blockIdx.x * 32, blockIdx.y * 32);
}

__global__ __launch_bounds__(256) void tcast_qkv(const float* __restrict__ wq,
                                                 const float* __restrict__ wk,
                                                 const float* __restrict__ wv,
                                                 ushort* __restrict__ dst) {
  int z = blockIdx.z, zz = z >> 4, h = z & 15;
  const float* src = (zz == 0 ? wq : (zz == 1 ? wk : wv)) + (size_t)h * Cc * HSz;
  ushort* d = dst + (size_t)(zz * 1024 + h * 64) * 1024;
  tcast_body(src, d, HSz, Cc, blockIdx.x * 32, blockIdx.y * 32);
}

__global__ __launch_bounds__(256) void bias_concat(const float* __restrict__ bq,
                                                   const float* __restrict__ bk,
                                                   const float* __restrict__ bv,
                                                   float* __restrict__ dst) {
  int i = blockIdx.x * 256 + threadIdx.x;
  dst[i] = i < 1024 ? bq[i] : (i < 2048 ? bk[i - 1024] : bv[i - 2048]);
}

// -------- bf16 MFMA GEMM: 128x128 tile, BK=64, 8 waves (2Mx4N) ----------
// LDS rows 128 B, XOR-swizzled (slot ^= row&7): fragment ds_read_b128 is
// conflict-free; staged via global_load_lds w=16 with inverse-swz source.
__device__ __forceinline__ void gemm_main(const ushort* __restrict__ A, int lda,
                                          const ushort* __restrict__ Bt, int ldb,
                                          int K, int m0, int n0,
                                          ushort* __restrict__ As,
                                          ushort* __restrict__ Bs,
                                          f32x4 (&acc)[4][2]) {
  int tid = threadIdx.x, wid = tid >> 6, lane = tid & 63;
  int wr = wid >> 2, wc = wid & 3, fr = lane & 15, fq = lane >> 4;
  const ushort* Ag = A + (size_t)m0 * lda;
  const ushort* Bg = Bt + (size_t)n0 * ldb;
  for (int k0 = 0; k0 < K; k0 += 64) {
    // stage A[128][64], B[128][64]: 1024 16B-slots each, 2 per thread
#pragma unroll
    for (int c = 0; c < 2; ++c) {
      int slot = c * 512 + tid;
      int row = slot >> 3, s = slot & 7;
      int sw = (s << 3) ^ ((row & 7) << 3);  // inverse-swz source (ushorts)
      gload16(Ag + (size_t)row * lda + k0 + sw, As + (size_t)(c * 512 + wid * 64) * 8);
      gload16(Bg + (size_t)row * ldb + k0 + sw, Bs + (size_t)(c * 512 + wid * 64) * 8);
    }
    __syncthreads();
    bf16x8 av[4][2], bv[2][2];
#pragma unroll
    for (int m = 0; m < 4; ++m) {
      int row = wr * 64 + m * 16 + fr;
#pragma unroll
      for (int ks = 0; ks < 2; ++ks)
        av[m][ks] = *(const bf16x8*)&As[row * 64 + (((ks * 4 + fq) ^ (row & 7)) << 3)];
    }
#pragma unroll
    for (int n = 0; n < 2; ++n) {
      int row = wc * 32 + n * 16 + fr;
#pragma unroll
      for (int ks = 0; ks < 2; ++ks)
        bv[n][ks] = *(const bf16x8*)&Bs[row * 64 + (((ks * 4 + fq) ^ (row & 7)) << 3)];
    }
#pragma unroll
    for (int m = 0; m < 4; ++m)
#pragma unroll
      for (int n = 0; n < 2; ++n)
#pragma unroll
        for (int ks = 0; ks < 2; ++ks)
          acc[m][n] = __builtin_amdgcn_mfma_f32_16x16x32_bf16(
              av[m][ks], bv[n][ks], acc[m][n], 0, 0, 0);
    __syncthreads();
  }
}

// XCD-chunked bijective block swizzle (all grids %8 == 0): XCD gets a
// contiguous band of 1/8 of the grid -> A-panels L2-resident per XCD.
__device__ __forceinline__ void xcd_swz(int& bx, int& by) {
  int bid = blockIdx.x + blockIdx.y * gridDim.x;
  int cpx = (gridDim.x * gridDim.y) >> 3;
  int id = (bid & 7) * cpx + (bid >> 3);
  bx = id % gridDim.x;
  by = id / gridDim.x;
}

template <bool RELU, bool HASRES, bool OUTBF16>
__global__ __launch_bounds__(512) void gemm_bf16(
    const ushort* __restrict__ A, int lda, const ushort* __restrict__ Bt,
    int ldb, const float* __restrict__ bias, const float* __restrict__ res,
    void* __restrict__ Cout, int ldc, int K) {
  __shared__ __align__(16) ushort As[128 * 64];
  __shared__ __align__(16) ushort Bs[128 * 64];
  f32x4 acc[4][2] = {};
  int bx, by;
  xcd_swz(bx, by);
  int m0 = by * 128, n0 = bx * 128;
  gemm_main(A, lda, Bt, ldb, K, m0, n0, As, Bs, acc);
  int lane = threadIdx.x & 63, wid = threadIdx.x >> 6;
  int wr = wid >> 2, wc = wid & 3, fr = lane & 15, fq = lane >> 4;
#pragma unroll
  for (int m = 0; m < 4; ++m) {
    int gm = m0 + wr * 64 + m * 16 + fq * 4;
#pragma unroll
    for (int n = 0; n < 2; ++n) {
      int gn = n0 + wc * 32 + n * 16 + fr;
      float bsv = bias[gn];
#pragma unroll
      for (int j = 0; j < 4; ++j) {
        int row = gm + j;
        float v = acc[m][n][j] + bsv;
        if constexpr (HASRES) v += res[(size_t)row * ldc + gn];
        if constexpr (RELU) v = fmaxf(v, 0.f);
        if constexpr (OUTBF16)
          ((ushort*)Cout)[(size_t)row * ldc + gn] = f2bf(v);
        else
          ((float*)Cout)[(size_t)row * ldc + gn] = v;
      }
    }
  }
}

// QKV GEMM: N-cols [0,1024)->Q, [1024,2048)->K, [2048,3072)->Vt transposed
// [B][H][HS][T]. Branch uniform per fragment. Vt: j-contiguous ushort4.
__global__ __launch_bounds__(512) void gemm_qkv(const ushort* __restrict__ A,
                                                const ushort* __restrict__ Bt,
                                                const float* __restrict__ bias,
                                                ushort* __restrict__ q,
                                                ushort* __restrict__ k,
                                                ushort* __restrict__ vt) {
  __shared__ __align__(16) ushort As[128 * 64];
  __shared__ __align__(16) ushort Bs[128 * 64];
  f32x4 acc[4][2] = {};
  int bx, by;
  xcd_swz(bx, by);
  int m0 = by * 128, n0 = bx * 128;
  gemm_main(A, 1024, Bt, 1024, 1024, m0, n0, As, Bs, acc);
  int lane = threadIdx.x & 63, wid = threadIdx.x >> 6;
  int wr = wid >> 2, wc = wid & 3, fr = lane & 15, fq = lane >> 4;
#pragma unroll
  for (int m = 0; m < 4; ++m) {
    int gm = m0 + wr * 64 + m * 16 + fq * 4;
#pragma unroll
    for (int n = 0; n < 2; ++n) {
      int gn = n0 + wc * 32 + n * 16 + fr;
      float bsv = bias[gn];
      if (gn < 2048) {
        ushort* dst = gn < 1024 ? q : k;
        int col = gn & 1023;
#pragma unroll
        for (int j = 0; j < 4; ++j)
          dst[(size_t)(gm + j) * 1024 + col] = f2bf(acc[m][n][j] + bsv);
      } else {
        int dd = gn - 2048, h = dd >> 6, d = dd & 63;
        int bbr = gm >> 11, t = gm & 2047;
        ushort4 pw = {f2bf(acc[m][n][0] + bsv), f2bf(acc[m][n][1] + bsv),
                      f2bf(acc[m][n][2] + bsv), f2bf(acc[m][n][3] + bsv)};
        *(ushort4*)&vt[(((size_t)(bbr * 16 + h)) * 64 + d) * 2048 + t] = pw;
      }
    }
  }
}

// ---------------- MFMA flash attention (pair-balanced) ----------------
// grid (8, 64): block handles q-tiles {pair, 15-pair} -> uniform 34 KV-tiles.
// 4 waves; wave owns 32 q-rows. Swapped QK^T; P via swizzled per-wave LDS;
// V staged transposed. Defer-rescale (THR=11 log2); setprio around MFMA.
constexpr int QB = 128, KVB = 64;
__global__ __launch_bounds__(256) void attn_kernel(const ushort* __restrict__ Qb,
                                                   const ushort* __restrict__ Kb,
                                                   const ushort* __restrict__ Vt,
                                                   ushort* __restrict__ att) {
  __shared__ __align__(16) ushort Klds[64 * 64];  // [kv][d], rows XOR-swizzled
  __shared__ __align__(16) ushort Vlds[64 * 64];  // [d][kv], rows XOR-swizzled
  __shared__ __align__(16) ushort Plds[4][32 * 64];  // per-wave [q][k]
  int tid = threadIdx.x, wid = tid >> 6, lane = tid & 63;
  int fr = lane & 15, fq = lane >> 4;
  int bh = blockIdx.y, bb = bh >> 4, hh = bh & 15;
  const float c = 1.4426950408889634f / 32.0f;  // log2e * C^-0.5
  const ushort* qkbase = Qb + ((size_t)bb * Tt) * Cc + hh * HSz;
  const ushort* Kbase = Kb + ((size_t)bb * Tt) * Cc + hh * HSz;
  const ushort* Vbase = Vt + ((size_t)(bb * Hh + hh)) * HSz * Tt;

#pragma unroll 1
  for (int pass = 0; pass < 2; ++pass) {
    int qt = pass ? (Tt / QB - 1 - (int)blockIdx.x) : (int)blockIdx.x;
    int q0 = qt * QB;
    int q0w = q0 + wid * 32;

    bf16x8 Qreg[2][2];
#pragma unroll
    for (int qs = 0; qs < 2; ++qs)
#pragma unroll
      for (int d2 = 0; d2 < 2; ++d2)
        Qreg[qs][d2] = *(const bf16x8*)(qkbase +
            (size_t)(q0w + qs * 16 + fr) * Cc + d2 * 32 + fq * 8);
    f32x4 Oa[2][4] = {};  // [qs][ds]; lane holds O[q=fq*4+reg][d=fr]
    float mrow[2] = {-1e30f, -1e30f}, lrow[2] = {0.f, 0.f};
    int nt = q0 / KVB + 2;

    for (int kt = 0; kt < nt; ++kt) {
      int t0 = kt * KVB;
      __syncthreads();  // previous tile's LDS reads complete
#pragma unroll
      for (int cch = 0; cch < 2; ++cch) {
        int s = cch * 256 + tid;
        int row = s >> 3;
        int b = (s & 7) * 16;
        int sw = (b >> 1) ^ ((row & 7) << 3);  // inverse-swz source (ushort)
        void* dst = (char*)Klds + (cch * 256 + wid * 64) * 16;
        gload16(Kbase + (size_t)(t0 + row) * Cc + sw, dst);
        void* dstv = (char*)Vlds + (cch * 256 + wid * 64) * 16;
        gload16(Vbase + (size_t)row * Tt + t0 + sw, dstv);
      }
      __syncthreads();
      if (q0w + 31 < t0) continue;  // wave fully masked

      // ---- QK^T swapped: accs[qs][ks] = S^T (16k x 16q) ----
      bf16x8 kf[4][2];
#pragma unroll
      for (int ks = 0; ks < 4; ++ks)
#pragma unroll
        for (int d2 = 0; d2 < 2; ++d2) {
          int row = ks * 16 + fr;
          int off = (d2 * 64 + fq * 16) ^ ((row & 7) << 4);
          kf[ks][d2] = *(const bf16x8*)((const char*)Klds + row * 128 + off);
        }
      f32x4 accs[2][4] = {};
      __builtin_amdgcn_s_setprio(1);
#pragma unroll
      for (int qs = 0; qs < 2; ++qs)
#pragma unroll
        for (int ks = 0; ks < 4; ++ks) {
          accs[qs][ks] = __builtin_amdgcn_mfma_f32_16x16x32_bf16(
              kf[ks][0], Qreg[qs][0], accs[qs][ks], 0, 0, 0);
          accs[qs][ks] = __builtin_amdgcn_mfma_f32_16x16x32_bf16(
              kf[ks][1], Qreg[qs][1], accs[qs][ks], 0, 0, 0);
        }
      __builtin_amdgcn_s_setprio(0);

      // ---- softmax (per qs): row q=fr spread over 4 fq lanes ----
#pragma unroll
      for (int qs = 0; qs < 2; ++qs) {
        int qg = q0w + qs * 16 + fr;
        float sv[4][4];
        float vmax = -1e30f;
#pragma unroll
        for (int ks = 0; ks < 4; ++ks)
#pragma unroll
          for (int j = 0; j < 4; ++j) {
            int kg = t0 + ks * 16 + fq * 4 + j;
            float s = accs[qs][ks][j] * c;
            s = (kg <= qg) ? s : -1e30f;
            sv[ks][j] = s;
            vmax = fmaxf(vmax, s);
          }
        vmax = fmaxf(vmax, __shfl_xor(vmax, 16));
        vmax = fmaxf(vmax, __shfl_xor(vmax, 32));
        // T13 defer-rescale: only rescale when some row's max grew > THR
        float mnew = mrow[qs];
        if (!__all(vmax <= mnew + 11.0f)) {
          mnew = fmaxf(mrow[qs], vmax);
          float sf = exp2f(mrow[qs] - mnew);
          mrow[qs] = mnew;
          lrow[qs] *= sf;
#pragma unroll
          for (int j = 0; j < 4; ++j) {
            float sfo = __shfl(sf, fq * 4 + j);
#pragma unroll
            for (int ds = 0; ds < 4; ++ds) Oa[qs][ds][j] *= sfo;
          }
        }
        float ls = 0.f;
        int qrow = qs * 16 + fr;
        char* pbase = (char*)Plds[wid] + qrow * 128;
#pragma unroll
        for (int ks = 0; ks < 4; ++ks) {
          float p0 = exp2f(sv[ks][0] - mnew);
          float p1 = exp2f(sv[ks][1] - mnew);
          float p2 = exp2f(sv[ks][2] - mnew);
          float p3 = exp2f(sv[ks][3] - mnew);
          ls += (p0 + p1) + (p2 + p3);
          ushort4 pw = {f2bf(p0), f2bf(p1), f2bf(p2), f2bf(p3)};
          int off = (ks * 32 + fq * 8) ^ ((qrow & 7) << 4);
          *(ushort4*)(pbase + off) = pw;
        }
        ls += __shfl_xor(ls, 16);
        ls += __shfl_xor(ls, 32);
        lrow[qs] += ls;
      }

      // ---- PV: O += P(32q x 64k) * V(64k x 64d) ----
      bf16x8 vf[4][2];
#pragma unroll
      for (int ds = 0; ds < 4; ++ds)
#pragma unroll
        for (int k2 = 0; k2 < 2; ++k2) {
          int row = ds * 16 + fr;
          int off = (k2 * 64 + fq * 16) ^ ((row & 7) << 4);
          vf[ds][k2] = *(const bf16x8*)((const char*)Vlds + row * 128 + off);
        }
      __builtin_amdgcn_s_setprio(1);
#pragma unroll
      for (int qs = 0; qs < 2; ++qs) {
        int qrow = qs * 16 + fr;
        bf16x8 pf[2];
#pragma unroll
        for (int k2 = 0; k2 < 2; ++k2) {
          int off = (k2 * 64 + fq * 16) ^ ((qrow & 7) << 4);
          pf[k2] = *(const bf16x8*)((const char*)Plds[wid] + qrow * 128 + off);
        }
#pragma unroll
        for (int ds = 0; ds < 4; ++ds) {
          Oa[qs][ds] = __builtin_amdgcn_mfma_f32_16x16x32_bf16(
              pf[0], vf[ds][0], Oa[qs][ds], 0, 0, 0);
          Oa[qs][ds] = __builtin_amdgcn_mfma_f32_16x16x32_bf16(
              pf[1], vf[ds][1], Oa[qs][ds], 0, 0, 0);
        }
      }
      __builtin_amdgcn_s_setprio(0);
    }

    // ---- epilogue ----
#pragma unroll
    for (int qs = 0; qs < 2; ++qs) {
      float linv = 1.f / lrow[qs];
#pragma unroll
      for (int j = 0; j < 4; ++j) {
        float lo = __shfl(linv, fq * 4 + j);
        int qg = q0w + qs * 16 + fq * 4 + j;
        ushort* orow = att + (size_t)(bb * Tt + qg) * Cc + hh * HSz;
#pragma unroll
        for (int ds = 0; ds < 4; ++ds)
          orow[ds * 16 + fr] = f2bf(Oa[qs][ds][j] * lo);
      }
    }
  }
}

extern "C" void kernel_launch(void* const* d_in, const int* in_sizes, int n_in,
                              void* d_out, int out_size, void* d_ws,
                              size_t ws_size, hipStream_t stream) {
  const float* x = (const float*)d_in[0];
  const float* wq = (const float*)d_in[1];
  const float* bq = (const float*)d_in[2];
  const float* wk = (const float*)d_in[3];
  const float* bk = (const float*)d_in[4];
  const float* wv = (const float*)d_in[5];
  const float* bv = (const float*)d_in[6];
  const float* wp = (const float*)d_in[7];
  const float* bp = (const float*)d_in[8];
  const float* w1 = (const float*)d_in[9];
  const float* b1 = (const float*)d_in[10];
  const float* w2 = (const float*)d_in[11];
  const float* b2 = (const float*)d_in[12];
  const float* g1 = (const float*)d_in[13];
  const float* be1 = (const float*)d_in[14];
  const float* g2 = (const float*)d_in[15];
  const float* be2 = (const float*)d_in[16];
  float* out = (float*)d_out;

  ushort* Qb = (ushort*)d_ws;                 // [8192][1024]
  ushort* Kb = Qb + (size_t)8388608;          // [8192][1024]
  ushort* Vt = Kb + (size_t)8388608;          // [4][16][64][2048]
  ushort* att = Vt + (size_t)8388608;         // [8192][1024]
  ushort* ffh = Qb;                           // [8192][4096] overlay
  ushort* h1b = att + (size_t)8388608;        // LN1/LN2 out
  float* x2 = (float*)(h1b + (size_t)8388608);
  ushort* wqkvT = (ushort*)(x2 + (size_t)8388608);  // [3072][1024]
  ushort* wpT = wqkvT + (size_t)3145728;            // [1024][1024]
  ushort* w1T = wpT + (size_t)1048576;              // [4096][1024]
  ushort* w2T = w1T + (size_t)4194304;              // [1024][4096]
  float* bqkv = (float*)(w2T + (size_t)4194304);    // [3072]

  tcast_qkv<<<dim3(32, 2, 48), 256, 0, stream>>>(wq, wk, wv, wqkvT);
  tcast_kernel<<<dim3(32, 32), 256, 0, stream>>>(wp, wpT, 1024, 1024);
  tcast_kernel<<<dim3(32, 128), 256, 0, stream>>>(w1, w1T, 4096, 1024);
  tcast_kernel<<<dim3(128, 32), 256, 0, stream>>>(w2, w2T, 1024, 4096);
  bias_concat<<<dim3(12), 256, 0, stream>>>(bq, bk, bv, bqkv);

  // 1) h1b = LN(x)
  ln_kernel<<<dim3(Mrows), 256, 0, stream>>>(x, g1, be1, h1b);
  // 2) Q,K,Vt = h1b @ WqkvT^T + bqkv (V written transposed)
  gemm_qkv<<<dim3(24, 64), 512, 0, stream>>>(h1b, wqkvT, bqkv, Qb, Kb, Vt);
  // 3) att = causal_softmax(Q K^T / 32) V  (paired q-tiles)
  attn_kernel<<<dim3(Tt / QB / 2, Bb * Hh), 256, 0, stream>>>(Qb, Kb, Vt, att);
  // 4) x2 = x + att @ wp + bp
  gemm_bf16<false, true, false><<<dim3(8, 64), 512, 0, stream>>>(
      att, 1024, wpT, 1024, bp, x, x2, 1024, 1024);
  // 5) h2b = LN(x2)
  ln_kernel<<<dim3(Mrows), 256, 0, stream>>>(x2, g2, be2, h1b);
  // 6) ffh = relu(h2b @ w1 + b1)
  gemm_bf16<true, false, true><<<dim3(32, 64), 512, 0, stream>>>(
      h1b, 1024, w1T, 1024, b1, nullptr, ffh, 4096, 1024);
  // 7) out = x2 + ffh @ w2 + b2
  gemm_bf16<false, true, false><<<dim3(8, 64), 512, 0, stream>>>(
      ffh, 4096, w2T, 4096, b2, x2, out, 1024, 4096);
}

// Round 6
// 383.955 us; speedup vs baseline: 12.3712x; 1.0277x over previous
//
#include <hip/hip_runtime.h>

// Transformer block. Round 5: attn VALU cut — qscale folded into Q (QKV
// epilogue), interior-tile unmasked fast path, P-pack via v_cvt_pk_bf16_f32.
// GEMMs unchanged (round-4: 8 waves, BK=64, XOR-swizzle, XCD-chunked).
//
// Workspace (~136 MiB):
//   [Q 16M | K 16M | Vt 16M | att 16M]  <- ffh bf16 64M overlays exactly
//   [h1b 16M][x2 f32 32M][wqkvT 6M][wpT 2M][w1T 8M][w2T 8M][bqkv]

constexpr int Bb = 4, Tt = 2048, Cc = 1024, Hh = 16, HSz = 64, Ff = 4096;
constexpr int Mrows = Bb * Tt;  // 8192

typedef __attribute__((ext_vector_type(8))) short bf16x8;
typedef __attribute__((ext_vector_type(4))) float f32x4;

__device__ __forceinline__ ushort f2bf(float f) {
  uint u = __builtin_bit_cast(uint, f);
  uint r = (u + 0x7fffu + ((u >> 16) & 1u)) >> 16;
  return (ushort)r;
}
__device__ __forceinline__ float bf2f(ushort s) {
  return __builtin_bit_cast(float, ((uint)s) << 16);
}
__device__ __forceinline__ uint cvtpk_bf16(float lo, float hi) {
  uint r;
  asm("v_cvt_pk_bf16_f32 %0, %1, %2" : "=v"(r) : "v"(lo), "v"(hi));
  return r;
}
__device__ __forceinline__ void gload16(const void* g, void* l) {
  __builtin_amdgcn_global_load_lds(
      (const __attribute__((address_space(1))) void*)g,
      (__attribute__((address_space(3))) void*)l, 16, 0, 0);
}

// ---------------- LayerNorm: fp32 in, bf16 out ----------------
__global__ __launch_bounds__(256) void ln_kernel(const float* __restrict__ x,
                                                 const float* __restrict__ g,
                                                 const float* __restrict__ b,
                                                 ushort* __restrict__ out) {
  int row = blockIdx.x;
  const float* xr = x + (size_t)row * Cc;
  int c4 = threadIdx.x * 4;
  float4 v = *(const float4*)(xr + c4);
  float s1 = v.x + v.y + v.z + v.w;
  float s2 = v.x * v.x + v.y * v.y + v.z * v.z + v.w * v.w;
#pragma unroll
  for (int off = 32; off >= 1; off >>= 1) {
    s1 += __shfl_xor(s1, off);
    s2 += __shfl_xor(s2, off);
  }
  __shared__ float red[8];
  int wid = threadIdx.x >> 6, lane = threadIdx.x & 63;
  if (lane == 0) { red[wid] = s1; red[4 + wid] = s2; }
  __syncthreads();
  float t1 = red[0] + red[1] + red[2] + red[3];
  float t2 = red[4] + red[5] + red[6] + red[7];
  float mu = t1 * (1.0f / Cc);
  float var = t2 * (1.0f / Cc) - mu * mu;
  float rs = rsqrtf(var + 1e-5f);
  float4 gv = *(const float4*)(g + c4);
  float4 bv = *(const float4*)(b + c4);
  ushort4 o;
  o.x = f2bf((v.x - mu) * rs * gv.x + bv.x);
  o.y = f2bf((v.y - mu) * rs * gv.y + bv.y);
  o.z = f2bf((v.z - mu) * rs * gv.z + bv.z);
  o.w = f2bf((v.w - mu) * rs * gv.w + bv.w);
  *(ushort4*)(out + (size_t)row * Cc + c4) = o;
}

// ---------------- Transpose-cast fp32 [R][C] -> bf16 [C][R] ----------------
__device__ __forceinline__ void tcast_body(const float* __restrict__ src,
                                           ushort* __restrict__ dst, int ldS,
                                           int ldD, int r0, int c0) {
  __shared__ float t[32][33];
  int c = threadIdx.x & 31, r8 = threadIdx.x >> 5;
#pragma unroll
  for (int i = 0; i < 4; ++i) {
    int r = r8 + i * 8;
    t[r][c] = src[(size_t)(r0 + r) * ldS + c0 + c];
  }
  __syncthreads();
#pragma unroll
  for (int i = 0; i < 4; ++i) {
    int rr = r8 + i * 8;
    dst[(size_t)(c0 + rr) * ldD + r0 + c] = f2bf(t[c][rr]);
  }
}

__global__ __launch_bounds__(256) void tcast_kernel(const float* __restrict__ src,
                                                    ushort* __restrict__ dst,
                                                    int ldS, int ldD) {
  tcast_body(src, dst, ldS, ldD, blockIdx.x * 32, blockIdx.y * 32);
}

__global__ __launch_bounds__(256) void tcast_qkv(const float* __restrict__ wq,
                                                 const float* __restrict__ wk,
                                                 const float* __restrict__ wv,
                                                 ushort* __restrict__ dst) {
  int z = blockIdx.z, zz = z >> 4, h = z & 15;
  const float* src = (zz == 0 ? wq : (zz == 1 ? wk : wv)) + (size_t)h * Cc * HSz;
  ushort* d = dst + (size_t)(zz * 1024 + h * 64) * 1024;
  tcast_body(src, d, HSz, Cc, blockIdx.x * 32, blockIdx.y * 32);
}

__global__ __launch_bounds__(256) void bias_concat(const float* __restrict__ bq,
                                                   const float* __restrict__ bk,
                                                   const float* __restrict__ bv,
                                                   float* __restrict__ dst) {
  int i = blockIdx.x * 256 + threadIdx.x;
  dst[i] = i < 1024 ? bq[i] : (i < 2048 ? bk[i - 1024] : bv[i - 2048]);
}

// -------- bf16 MFMA GEMM: 128x128 tile, BK=64, 8 waves (2Mx4N) ----------
// LDS rows 128 B, XOR-swizzled (slot ^= row&7): fragment ds_read_b128 is
// conflict-free; staged via global_load_lds w=16 with inverse-swz source.
__device__ __forceinline__ void gemm_main(const ushort* __restrict__ A, int lda,
                                          const ushort* __restrict__ Bt, int ldb,
                                          int K, int m0, int n0,
                                          ushort* __restrict__ As,
                                          ushort* __restrict__ Bs,
                                          f32x4 (&acc)[4][2]) {
  int tid = threadIdx.x, wid = tid >> 6, lane = tid & 63;
  int wr = wid >> 2, wc = wid & 3, fr = lane & 15, fq = lane >> 4;
  const ushort* Ag = A + (size_t)m0 * lda;
  const ushort* Bg = Bt + (size_t)n0 * ldb;
  for (int k0 = 0; k0 < K; k0 += 64) {
    // stage A[128][64], B[128][64]: 1024 16B-slots each, 2 per thread
#pragma unroll
    for (int c = 0; c < 2; ++c) {
      int slot = c * 512 + tid;
      int row = slot >> 3, s = slot & 7;
      int sw = (s << 3) ^ ((row & 7) << 3);  // inverse-swz source (ushorts)
      gload16(Ag + (size_t)row * lda + k0 + sw, As + (size_t)(c * 512 + wid * 64) * 8);
      gload16(Bg + (size_t)row * ldb + k0 + sw, Bs + (size_t)(c * 512 + wid * 64) * 8);
    }
    __syncthreads();
    bf16x8 av[4][2], bv[2][2];
#pragma unroll
    for (int m = 0; m < 4; ++m) {
      int row = wr * 64 + m * 16 + fr;
#pragma unroll
      for (int ks = 0; ks < 2; ++ks)
        av[m][ks] = *(const bf16x8*)&As[row * 64 + (((ks * 4 + fq) ^ (row & 7)) << 3)];
    }
#pragma unroll
    for (int n = 0; n < 2; ++n) {
      int row = wc * 32 + n * 16 + fr;
#pragma unroll
      for (int ks = 0; ks < 2; ++ks)
        bv[n][ks] = *(const bf16x8*)&Bs[row * 64 + (((ks * 4 + fq) ^ (row & 7)) << 3)];
    }
#pragma unroll
    for (int m = 0; m < 4; ++m)
#pragma unroll
      for (int n = 0; n < 2; ++n)
#pragma unroll
        for (int ks = 0; ks < 2; ++ks)
          acc[m][n] = __builtin_amdgcn_mfma_f32_16x16x32_bf16(
              av[m][ks], bv[n][ks], acc[m][n], 0, 0, 0);
    __syncthreads();
  }
}

// XCD-chunked bijective block swizzle (all grids %8 == 0).
__device__ __forceinline__ void xcd_swz(int& bx, int& by) {
  int bid = blockIdx.x + blockIdx.y * gridDim.x;
  int cpx = (gridDim.x * gridDim.y) >> 3;
  int id = (bid & 7) * cpx + (bid >> 3);
  bx = id % gridDim.x;
  by = id / gridDim.x;
}

template <bool RELU, bool HASRES, bool OUTBF16>
__global__ __launch_bounds__(512) void gemm_bf16(
    const ushort* __restrict__ A, int lda, const ushort* __restrict__ Bt,
    int ldb, const float* __restrict__ bias, const float* __restrict__ res,
    void* __restrict__ Cout, int ldc, int K) {
  __shared__ __align__(16) ushort As[128 * 64];
  __shared__ __align__(16) ushort Bs[128 * 64];
  f32x4 acc[4][2] = {};
  int bx, by;
  xcd_swz(bx, by);
  int m0 = by * 128, n0 = bx * 128;
  gemm_main(A, lda, Bt, ldb, K, m0, n0, As, Bs, acc);
  int lane = threadIdx.x & 63, wid = threadIdx.x >> 6;
  int wr = wid >> 2, wc = wid & 3, fr = lane & 15, fq = lane >> 4;
#pragma unroll
  for (int m = 0; m < 4; ++m) {
    int gm = m0 + wr * 64 + m * 16 + fq * 4;
#pragma unroll
    for (int n = 0; n < 2; ++n) {
      int gn = n0 + wc * 32 + n * 16 + fr;
      float bsv = bias[gn];
#pragma unroll
      for (int j = 0; j < 4; ++j) {
        int row = gm + j;
        float v = acc[m][n][j] + bsv;
        if constexpr (HASRES) v += res[(size_t)row * ldc + gn];
        if constexpr (RELU) v = fmaxf(v, 0.f);
        if constexpr (OUTBF16)
          ((ushort*)Cout)[(size_t)row * ldc + gn] = f2bf(v);
        else
          ((float*)Cout)[(size_t)row * ldc + gn] = v;
      }
    }
  }
}

// QKV GEMM: N-cols [0,1024)->Q (pre-scaled by log2e/32), [1024,2048)->K,
// [2048,3072)->Vt transposed [B][H][HS][T] (j-contiguous ushort4 stores).
__global__ __launch_bounds__(512) void gemm_qkv(const ushort* __restrict__ A,
                                                const ushort* __restrict__ Bt,
                                                const float* __restrict__ bias,
                                                ushort* __restrict__ q,
                                                ushort* __restrict__ k,
                                                ushort* __restrict__ vt) {
  __shared__ __align__(16) ushort As[128 * 64];
  __shared__ __align__(16) ushort Bs[128 * 64];
  f32x4 acc[4][2] = {};
  int bx, by;
  xcd_swz(bx, by);
  int m0 = by * 128, n0 = bx * 128;
  gemm_main(A, 1024, Bt, 1024, 1024, m0, n0, As, Bs, acc);
  int lane = threadIdx.x & 63, wid = threadIdx.x >> 6;
  int wr = wid >> 2, wc = wid & 3, fr = lane & 15, fq = lane >> 4;
  const float qscale = 1.4426950408889634f / 32.0f;  // log2e * C^-0.5
#pragma unroll
  for (int m = 0; m < 4; ++m) {
    int gm = m0 + wr * 64 + m * 16 + fq * 4;
#pragma unroll
    for (int n = 0; n < 2; ++n) {
      int gn = n0 + wc * 32 + n * 16 + fr;
      float bsv = bias[gn];
      if (gn < 1024) {
#pragma unroll
        for (int j = 0; j < 4; ++j)
          q[(size_t)(gm + j) * 1024 + gn] = f2bf((acc[m][n][j] + bsv) * qscale);
      } else if (gn < 2048) {
        int col = gn - 1024;
#pragma unroll
        for (int j = 0; j < 4; ++j)
          k[(size_t)(gm + j) * 1024 + col] = f2bf(acc[m][n][j] + bsv);
      } else {
        int dd = gn - 2048, h = dd >> 6, d = dd & 63;
        int bbr = gm >> 11, t = gm & 2047;
        ushort4 pw = {f2bf(acc[m][n][0] + bsv), f2bf(acc[m][n][1] + bsv),
                      f2bf(acc[m][n][2] + bsv), f2bf(acc[m][n][3] + bsv)};
        *(ushort4*)&vt[(((size_t)(bbr * 16 + h)) * 64 + d) * 2048 + t] = pw;
      }
    }
  }
}

// ---------------- MFMA flash attention (pair-balanced) ----------------
// grid (8, 64): block handles q-tiles {pair, 15-pair} -> uniform 34 KV-tiles.
// 4 waves; wave owns 32 q-rows. Swapped QK^T (scale pre-folded into Q);
// interior tiles skip causal masking; P packed via v_cvt_pk_bf16_f32.
constexpr int QB = 128, KVB = 64;
__global__ __launch_bounds__(256) void attn_kernel(const ushort* __restrict__ Qb,
                                                   const ushort* __restrict__ Kb,
                                                   const ushort* __restrict__ Vt,
                                                   ushort* __restrict__ att) {
  __shared__ __align__(16) ushort Klds[64 * 64];  // [kv][d], rows XOR-swizzled
  __shared__ __align__(16) ushort Vlds[64 * 64];  // [d][kv], rows XOR-swizzled
  __shared__ __align__(16) ushort Plds[4][32 * 64];  // per-wave [q][k]
  int tid = threadIdx.x, wid = tid >> 6, lane = tid & 63;
  int fr = lane & 15, fq = lane >> 4;
  int bh = blockIdx.y, bb = bh >> 4, hh = bh & 15;
  const ushort* qkbase = Qb + ((size_t)bb * Tt) * Cc + hh * HSz;
  const ushort* Kbase = Kb + ((size_t)bb * Tt) * Cc + hh * HSz;
  const ushort* Vbase = Vt + ((size_t)(bb * Hh + hh)) * HSz * Tt;

#pragma unroll 1
  for (int pass = 0; pass < 2; ++pass) {
    int qt = pass ? (Tt / QB - 1 - (int)blockIdx.x) : (int)blockIdx.x;
    int q0 = qt * QB;
    int q0w = q0 + wid * 32;

    bf16x8 Qreg[2][2];
#pragma unroll
    for (int qs = 0; qs < 2; ++qs)
#pragma unroll
      for (int d2 = 0; d2 < 2; ++d2)
        Qreg[qs][d2] = *(const bf16x8*)(qkbase +
            (size_t)(q0w + qs * 16 + fr) * Cc + d2 * 32 + fq * 8);
    f32x4 Oa[2][4] = {};  // [qs][ds]; lane holds O[q=fq*4+reg][d=fr]
    float mrow[2] = {-1e30f, -1e30f}, lrow[2] = {0.f, 0.f};
    int nt = q0 / KVB + 2;

    for (int kt = 0; kt < nt; ++kt) {
      int t0 = kt * KVB;
      __syncthreads();  // previous tile's LDS reads complete
#pragma unroll
      for (int cch = 0; cch < 2; ++cch) {
        int s = cch * 256 + tid;
        int row = s >> 3;
        int b = (s & 7) * 16;
        int sw = (b >> 1) ^ ((row & 7) << 3);  // inverse-swz source (ushort)
        void* dst = (char*)Klds + (cch * 256 + wid * 64) * 16;
        gload16(Kbase + (size_t)(t0 + row) * Cc + sw, dst);
        void* dstv = (char*)Vlds + (cch * 256 + wid * 64) * 16;
        gload16(Vbase + (size_t)row * Tt + t0 + sw, dstv);
      }
      __syncthreads();
      if (q0w + 31 < t0) continue;  // wave fully masked

      // ---- QK^T swapped: accs[qs][ks] = S^T (16k x 16q) ----
      bf16x8 kf[4][2];
#pragma unroll
      for (int ks = 0; ks < 4; ++ks)
#pragma unroll
        for (int d2 = 0; d2 < 2; ++d2) {
          int row = ks * 16 + fr;
          int off = (d2 * 64 + fq * 16) ^ ((row & 7) << 4);
          kf[ks][d2] = *(const bf16x8*)((const char*)Klds + row * 128 + off);
        }
      f32x4 accs[2][4] = {};
      __builtin_amdgcn_s_setprio(1);
#pragma unroll
      for (int qs = 0; qs < 2; ++qs)
#pragma unroll
        for (int ks = 0; ks < 4; ++ks) {
          accs[qs][ks] = __builtin_amdgcn_mfma_f32_16x16x32_bf16(
              kf[ks][0], Qreg[qs][0], accs[qs][ks], 0, 0, 0);
          accs[qs][ks] = __builtin_amdgcn_mfma_f32_16x16x32_bf16(
              kf[ks][1], Qreg[qs][1], accs[qs][ks], 0, 0, 0);
        }
      __builtin_amdgcn_s_setprio(0);

      // ---- softmax (per qs): row q=fr spread over 4 fq lanes ----
#pragma unroll
      for (int qs = 0; qs < 2; ++qs) {
        float sv[4][4];
        float vmax = -1e30f;
        if (t0 + 63 <= q0w + qs * 16) {  // interior: no causal mask needed
#pragma unroll
          for (int ks = 0; ks < 4; ++ks)
#pragma unroll
            for (int j = 0; j < 4; ++j) {
              sv[ks][j] = accs[qs][ks][j];
              vmax = fmaxf(vmax, sv[ks][j]);
            }
        } else {
          int qg = q0w + qs * 16 + fr;
#pragma unroll
          for (int ks = 0; ks < 4; ++ks)
#pragma unroll
            for (int j = 0; j < 4; ++j) {
              int kg = t0 + ks * 16 + fq * 4 + j;
              float s = accs[qs][ks][j];
              s = (kg <= qg) ? s : -1e30f;
              sv[ks][j] = s;
              vmax = fmaxf(vmax, s);
            }
        }
        vmax = fmaxf(vmax, __shfl_xor(vmax, 16));
        vmax = fmaxf(vmax, __shfl_xor(vmax, 32));
        // T13 defer-rescale: only rescale when some row's max grew > THR
        float mnew = mrow[qs];
        if (!__all(vmax <= mnew + 11.0f)) {
          mnew = fmaxf(mrow[qs], vmax);
          float sf = exp2f(mrow[qs] - mnew);
          mrow[qs] = mnew;
          lrow[qs] *= sf;
#pragma unroll
          for (int j = 0; j < 4; ++j) {
            float sfo = __shfl(sf, fq * 4 + j);
#pragma unroll
            for (int ds = 0; ds < 4; ++ds) Oa[qs][ds][j] *= sfo;
          }
        }
        float ls = 0.f;
        int qrow = qs * 16 + fr;
        char* pbase = (char*)Plds[wid] + qrow * 128;
#pragma unroll
        for (int ks = 0; ks < 4; ++ks) {
          float p0 = exp2f(sv[ks][0] - mnew);
          float p1 = exp2f(sv[ks][1] - mnew);
          float p2 = exp2f(sv[ks][2] - mnew);
          float p3 = exp2f(sv[ks][3] - mnew);
          ls += (p0 + p1) + (p2 + p3);
          uint2 pw = {cvtpk_bf16(p0, p1), cvtpk_bf16(p2, p3)};
          int off = (ks * 32 + fq * 8) ^ ((qrow & 7) << 4);
          *(uint2*)(pbase + off) = pw;
        }
        ls += __shfl_xor(ls, 16);
        ls += __shfl_xor(ls, 32);
        lrow[qs] += ls;
      }

      // ---- PV: O += P(32q x 64k) * V(64k x 64d) ----
      bf16x8 vf[4][2];
#pragma unroll
      for (int ds = 0; ds < 4; ++ds)
#pragma unroll
        for (int k2 = 0; k2 < 2; ++k2) {
          int row = ds * 16 + fr;
          int off = (k2 * 64 + fq * 16) ^ ((row & 7) << 4);
          vf[ds][k2] = *(const bf16x8*)((const char*)Vlds + row * 128 + off);
        }
      __builtin_amdgcn_s_setprio(1);
#pragma unroll
      for (int qs = 0; qs < 2; ++qs) {
        int qrow = qs * 16 + fr;
        bf16x8 pf[2];
#pragma unroll
        for (int k2 = 0; k2 < 2; ++k2) {
          int off = (k2 * 64 + fq * 16) ^ ((qrow & 7) << 4);
          pf[k2] = *(const bf16x8*)((const char*)Plds[wid] + qrow * 128 + off);
        }
#pragma unroll
        for (int ds = 0; ds < 4; ++ds) {
          Oa[qs][ds] = __builtin_amdgcn_mfma_f32_16x16x32_bf16(
              pf[0], vf[ds][0], Oa[qs][ds], 0, 0, 0);
          Oa[qs][ds] = __builtin_amdgcn_mfma_f32_16x16x32_bf16(
              pf[1], vf[ds][1], Oa[qs][ds], 0, 0, 0);
        }
      }
      __builtin_amdgcn_s_setprio(0);
    }

    // ---- epilogue ----
#pragma unroll
    for (int qs = 0; qs < 2; ++qs) {
      float linv = 1.f / lrow[qs];
#pragma unroll
      for (int j = 0; j < 4; ++j) {
        float lo = __shfl(linv, fq * 4 + j);
        int qg = q0w + qs * 16 + fq * 4 + j;
        ushort* orow = att + (size_t)(bb * Tt + qg) * Cc + hh * HSz;
#pragma unroll
        for (int ds = 0; ds < 4; ++ds)
          orow[ds * 16 + fr] = f2bf(Oa[qs][ds][j] * lo);
      }
    }
  }
}

extern "C" void kernel_launch(void* const* d_in, const int* in_sizes, int n_in,
                              void* d_out, int out_size, void* d_ws,
                              size_t ws_size, hipStream_t stream) {
  const float* x = (const float*)d_in[0];
  const float* wq = (const float*)d_in[1];
  const float* bq = (const float*)d_in[2];
  const float* wk = (const float*)d_in[3];
  const float* bk = (const float*)d_in[4];
  const float* wv = (const float*)d_in[5];
  const float* bv = (const float*)d_in[6];
  const float* wp = (const float*)d_in[7];
  const float* bp = (const float*)d_in[8];
  const float* w1 = (const float*)d_in[9];
  const float* b1 = (const float*)d_in[10];
  const float* w2 = (const float*)d_in[11];
  const float* b2 = (const float*)d_in[12];
  const float* g1 = (const float*)d_in[13];
  const float* be1 = (const float*)d_in[14];
  const float* g2 = (const float*)d_in[15];
  const float* be2 = (const float*)d_in[16];
  float* out = (float*)d_out;

  ushort* Qb = (ushort*)d_ws;                 // [8192][1024]
  ushort* Kb = Qb + (size_t)8388608;          // [8192][1024]
  ushort* Vt = Kb + (size_t)8388608;          // [4][16][64][2048]
  ushort* att = Vt + (size_t)8388608;         // [8192][1024]
  ushort* ffh = Qb;                           // [8192][4096] overlay
  ushort* h1b = att + (size_t)8388608;        // LN1/LN2 out
  float* x2 = (float*)(h1b + (size_t)8388608);
  ushort* wqkvT = (ushort*)(x2 + (size_t)8388608);  // [3072][1024]
  ushort* wpT = wqkvT + (size_t)3145728;            // [1024][1024]
  ushort* w1T = wpT + (size_t)1048576;              // [4096][1024]
  ushort* w2T = w1T + (size_t)4194304;              // [1024][4096]
  float* bqkv = (float*)(w2T + (size_t)4194304);    // [3072]

  tcast_qkv<<<dim3(32, 2, 48), 256, 0, stream>>>(wq, wk, wv, wqkvT);
  tcast_kernel<<<dim3(32, 32), 256, 0, stream>>>(wp, wpT, 1024, 1024);
  tcast_kernel<<<dim3(32, 128), 256, 0, stream>>>(w1, w1T, 4096, 1024);
  tcast_kernel<<<dim3(128, 32), 256, 0, stream>>>(w2, w2T, 1024, 4096);
  bias_concat<<<dim3(12), 256, 0, stream>>>(bq, bk, bv, bqkv);

  // 1) h1b = LN(x)
  ln_kernel<<<dim3(Mrows), 256, 0, stream>>>(x, g1, be1, h1b);
  // 2) Q,K,Vt = h1b @ WqkvT^T + bqkv (Q pre-scaled; V written transposed)
  gemm_qkv<<<dim3(24, 64), 512, 0, stream>>>(h1b, wqkvT, bqkv, Qb, Kb, Vt);
  // 3) att = causal_softmax(Q K^T) V  (paired q-tiles)
  attn_kernel<<<dim3(Tt / QB / 2, Bb * Hh), 256, 0, stream>>>(Qb, Kb, Vt, att);
  // 4) x2 = x + att @ wp + bp
  gemm_bf16<false, true, false><<<dim3(8, 64), 512, 0, stream>>>(
      att, 1024, wpT, 1024, bp, x, x2, 1024, 1024);
  // 5) h2b = LN(x2)
  ln_kernel<<<dim3(Mrows), 256, 0, stream>>>(x2, g2, be2, h1b);
  // 6) ffh = relu(h2b @ w1 + b1)
  gemm_bf16<true, false, true><<<dim3(32, 64), 512, 0, stream>>>(
      h1b, 1024, w1T, 1024, b1, nullptr, ffh, 4096, 1024);
  // 7) out = x2 + ffh @ w2 + b2
  gemm_bf16<false, true, false><<<dim3(8, 64), 512, 0, stream>>>(
      ffh, 4096, w2T, 4096, b2, x2, out, 1024, 4096);
}

// Round 7
// 370.875 us; speedup vs baseline: 12.8076x; 1.0353x over previous
//
#include <hip/hip_runtime.h>

// Transformer block. Round 6: attn occupancy — 8 waves/block (512 thr), wave
// owns 16 q-rows (qs=1), same QB=128 pair-balanced grid -> 16 waves/CU so
// softmax VALU overlaps other waves' MFMA. GEMMs unchanged (round-4/5).
//
// Workspace (~136 MiB):
//   [Q 16M | K 16M | Vt 16M | att 16M]  <- ffh bf16 64M overlays exactly
//   [h1b 16M][x2 f32 32M][wqkvT 6M][wpT 2M][w1T 8M][w2T 8M][bqkv]

constexpr int Bb = 4, Tt = 2048, Cc = 1024, Hh = 16, HSz = 64, Ff = 4096;
constexpr int Mrows = Bb * Tt;  // 8192

typedef __attribute__((ext_vector_type(8))) short bf16x8;
typedef __attribute__((ext_vector_type(4))) float f32x4;

__device__ __forceinline__ ushort f2bf(float f) {
  uint u = __builtin_bit_cast(uint, f);
  uint r = (u + 0x7fffu + ((u >> 16) & 1u)) >> 16;
  return (ushort)r;
}
__device__ __forceinline__ float bf2f(ushort s) {
  return __builtin_bit_cast(float, ((uint)s) << 16);
}
__device__ __forceinline__ uint cvtpk_bf16(float lo, float hi) {
  uint r;
  asm("v_cvt_pk_bf16_f32 %0, %1, %2" : "=v"(r) : "v"(lo), "v"(hi));
  return r;
}
__device__ __forceinline__ void gload16(const void* g, void* l) {
  __builtin_amdgcn_global_load_lds(
      (const __attribute__((address_space(1))) void*)g,
      (__attribute__((address_space(3))) void*)l, 16, 0, 0);
}

// ---------------- LayerNorm: fp32 in, bf16 out ----------------
__global__ __launch_bounds__(256) void ln_kernel(const float* __restrict__ x,
                                                 const float* __restrict__ g,
                                                 const float* __restrict__ b,
                                                 ushort* __restrict__ out) {
  int row = blockIdx.x;
  const float* xr = x + (size_t)row * Cc;
  int c4 = threadIdx.x * 4;
  float4 v = *(const float4*)(xr + c4);
  float s1 = v.x + v.y + v.z + v.w;
  float s2 = v.x * v.x + v.y * v.y + v.z * v.z + v.w * v.w;
#pragma unroll
  for (int off = 32; off >= 1; off >>= 1) {
    s1 += __shfl_xor(s1, off);
    s2 += __shfl_xor(s2, off);
  }
  __shared__ float red[8];
  int wid = threadIdx.x >> 6, lane = threadIdx.x & 63;
  if (lane == 0) { red[wid] = s1; red[4 + wid] = s2; }
  __syncthreads();
  float t1 = red[0] + red[1] + red[2] + red[3];
  float t2 = red[4] + red[5] + red[6] + red[7];
  float mu = t1 * (1.0f / Cc);
  float var = t2 * (1.0f / Cc) - mu * mu;
  float rs = rsqrtf(var + 1e-5f);
  float4 gv = *(const float4*)(g + c4);
  float4 bv = *(const float4*)(b + c4);
  ushort4 o;
  o.x = f2bf((v.x - mu) * rs * gv.x + bv.x);
  o.y = f2bf((v.y - mu) * rs * gv.y + bv.y);
  o.z = f2bf((v.z - mu) * rs * gv.z + bv.z);
  o.w = f2bf((v.w - mu) * rs * gv.w + bv.w);
  *(ushort4*)(out + (size_t)row * Cc + c4) = o;
}

// ---------------- Transpose-cast fp32 [R][C] -> bf16 [C][R] ----------------
__device__ __forceinline__ void tcast_body(const float* __restrict__ src,
                                           ushort* __restrict__ dst, int ldS,
                                           int ldD, int r0, int c0) {
  __shared__ float t[32][33];
  int c = threadIdx.x & 31, r8 = threadIdx.x >> 5;
#pragma unroll
  for (int i = 0; i < 4; ++i) {
    int r = r8 + i * 8;
    t[r][c] = src[(size_t)(r0 + r) * ldS + c0 + c];
  }
  __syncthreads();
#pragma unroll
  for (int i = 0; i < 4; ++i) {
    int rr = r8 + i * 8;
    dst[(size_t)(c0 + rr) * ldD + r0 + c] = f2bf(t[c][rr]);
  }
}

__global__ __launch_bounds__(256) void tcast_kernel(const float* __restrict__ src,
                                                    ushort* __restrict__ dst,
                                                    int ldS, int ldD) {
  tcast_body(src, dst, ldS, ldD, blockIdx.x * 32, blockIdx.y * 32);
}

__global__ __launch_bounds__(256) void tcast_qkv(const float* __restrict__ wq,
                                                 const float* __restrict__ wk,
                                                 const float* __restrict__ wv,
                                                 ushort* __restrict__ dst) {
  int z = blockIdx.z, zz = z >> 4, h = z & 15;
  const float* src = (zz == 0 ? wq : (zz == 1 ? wk : wv)) + (size_t)h * Cc * HSz;
  ushort* d = dst + (size_t)(zz * 1024 + h * 64) * 1024;
  tcast_body(src, d, HSz, Cc, blockIdx.x * 32, blockIdx.y * 32);
}

__global__ __launch_bounds__(256) void bias_concat(const float* __restrict__ bq,
                                                   const float* __restrict__ bk,
                                                   const float* __restrict__ bv,
                                                   float* __restrict__ dst) {
  int i = blockIdx.x * 256 + threadIdx.x;
  dst[i] = i < 1024 ? bq[i] : (i < 2048 ? bk[i - 1024] : bv[i - 2048]);
}

// -------- bf16 MFMA GEMM: 128x128 tile, BK=64, 8 waves (2Mx4N) ----------
// LDS rows 128 B, XOR-swizzled (slot ^= row&7): fragment ds_read_b128 is
// conflict-free; staged via global_load_lds w=16 with inverse-swz source.
__device__ __forceinline__ void gemm_main(const ushort* __restrict__ A, int lda,
                                          const ushort* __restrict__ Bt, int ldb,
                                          int K, int m0, int n0,
                                          ushort* __restrict__ As,
                                          ushort* __restrict__ Bs,
                                          f32x4 (&acc)[4][2]) {
  int tid = threadIdx.x, wid = tid >> 6, lane = tid & 63;
  int wr = wid >> 2, wc = wid & 3, fr = lane & 15, fq = lane >> 4;
  const ushort* Ag = A + (size_t)m0 * lda;
  const ushort* Bg = Bt + (size_t)n0 * ldb;
  for (int k0 = 0; k0 < K; k0 += 64) {
    // stage A[128][64], B[128][64]: 1024 16B-slots each, 2 per thread
#pragma unroll
    for (int c = 0; c < 2; ++c) {
      int slot = c * 512 + tid;
      int row = slot >> 3, s = slot & 7;
      int sw = (s << 3) ^ ((row & 7) << 3);  // inverse-swz source (ushorts)
      gload16(Ag + (size_t)row * lda + k0 + sw, As + (size_t)(c * 512 + wid * 64) * 8);
      gload16(Bg + (size_t)row * ldb + k0 + sw, Bs + (size_t)(c * 512 + wid * 64) * 8);
    }
    __syncthreads();
    bf16x8 av[4][2], bv[2][2];
#pragma unroll
    for (int m = 0; m < 4; ++m) {
      int row = wr * 64 + m * 16 + fr;
#pragma unroll
      for (int ks = 0; ks < 2; ++ks)
        av[m][ks] = *(const bf16x8*)&As[row * 64 + (((ks * 4 + fq) ^ (row & 7)) << 3)];
    }
#pragma unroll
    for (int n = 0; n < 2; ++n) {
      int row = wc * 32 + n * 16 + fr;
#pragma unroll
      for (int ks = 0; ks < 2; ++ks)
        bv[n][ks] = *(const bf16x8*)&Bs[row * 64 + (((ks * 4 + fq) ^ (row & 7)) << 3)];
    }
#pragma unroll
    for (int m = 0; m < 4; ++m)
#pragma unroll
      for (int n = 0; n < 2; ++n)
#pragma unroll
        for (int ks = 0; ks < 2; ++ks)
          acc[m][n] = __builtin_amdgcn_mfma_f32_16x16x32_bf16(
              av[m][ks], bv[n][ks], acc[m][n], 0, 0, 0);
    __syncthreads();
  }
}

// XCD-chunked bijective block swizzle (all grids %8 == 0).
__device__ __forceinline__ void xcd_swz(int& bx, int& by) {
  int bid = blockIdx.x + blockIdx.y * gridDim.x;
  int cpx = (gridDim.x * gridDim.y) >> 3;
  int id = (bid & 7) * cpx + (bid >> 3);
  bx = id % gridDim.x;
  by = id / gridDim.x;
}

template <bool RELU, bool HASRES, bool OUTBF16>
__global__ __launch_bounds__(512) void gemm_bf16(
    const ushort* __restrict__ A, int lda, const ushort* __restrict__ Bt,
    int ldb, const float* __restrict__ bias, const float* __restrict__ res,
    void* __restrict__ Cout, int ldc, int K) {
  __shared__ __align__(16) ushort As[128 * 64];
  __shared__ __align__(16) ushort Bs[128 * 64];
  f32x4 acc[4][2] = {};
  int bx, by;
  xcd_swz(bx, by);
  int m0 = by * 128, n0 = bx * 128;
  gemm_main(A, lda, Bt, ldb, K, m0, n0, As, Bs, acc);
  int lane = threadIdx.x & 63, wid = threadIdx.x >> 6;
  int wr = wid >> 2, wc = wid & 3, fr = lane & 15, fq = lane >> 4;
#pragma unroll
  for (int m = 0; m < 4; ++m) {
    int gm = m0 + wr * 64 + m * 16 + fq * 4;
#pragma unroll
    for (int n = 0; n < 2; ++n) {
      int gn = n0 + wc * 32 + n * 16 + fr;
      float bsv = bias[gn];
#pragma unroll
      for (int j = 0; j < 4; ++j) {
        int row = gm + j;
        float v = acc[m][n][j] + bsv;
        if constexpr (HASRES) v += res[(size_t)row * ldc + gn];
        if constexpr (RELU) v = fmaxf(v, 0.f);
        if constexpr (OUTBF16)
          ((ushort*)Cout)[(size_t)row * ldc + gn] = f2bf(v);
        else
          ((float*)Cout)[(size_t)row * ldc + gn] = v;
      }
    }
  }
}

// QKV GEMM: N-cols [0,1024)->Q (pre-scaled by log2e/32), [1024,2048)->K,
// [2048,3072)->Vt transposed [B][H][HS][T] (j-contiguous ushort4 stores).
__global__ __launch_bounds__(512) void gemm_qkv(const ushort* __restrict__ A,
                                                const ushort* __restrict__ Bt,
                                                const float* __restrict__ bias,
                                                ushort* __restrict__ q,
                                                ushort* __restrict__ k,
                                                ushort* __restrict__ vt) {
  __shared__ __align__(16) ushort As[128 * 64];
  __shared__ __align__(16) ushort Bs[128 * 64];
  f32x4 acc[4][2] = {};
  int bx, by;
  xcd_swz(bx, by);
  int m0 = by * 128, n0 = bx * 128;
  gemm_main(A, 1024, Bt, 1024, 1024, m0, n0, As, Bs, acc);
  int lane = threadIdx.x & 63, wid = threadIdx.x >> 6;
  int wr = wid >> 2, wc = wid & 3, fr = lane & 15, fq = lane >> 4;
  const float qscale = 1.4426950408889634f / 32.0f;  // log2e * C^-0.5
#pragma unroll
  for (int m = 0; m < 4; ++m) {
    int gm = m0 + wr * 64 + m * 16 + fq * 4;
#pragma unroll
    for (int n = 0; n < 2; ++n) {
      int gn = n0 + wc * 32 + n * 16 + fr;
      float bsv = bias[gn];
      if (gn < 1024) {
#pragma unroll
        for (int j = 0; j < 4; ++j)
          q[(size_t)(gm + j) * 1024 + gn] = f2bf((acc[m][n][j] + bsv) * qscale);
      } else if (gn < 2048) {
        int col = gn - 1024;
#pragma unroll
        for (int j = 0; j < 4; ++j)
          k[(size_t)(gm + j) * 1024 + col] = f2bf(acc[m][n][j] + bsv);
      } else {
        int dd = gn - 2048, h = dd >> 6, d = dd & 63;
        int bbr = gm >> 11, t = gm & 2047;
        ushort4 pw = {f2bf(acc[m][n][0] + bsv), f2bf(acc[m][n][1] + bsv),
                      f2bf(acc[m][n][2] + bsv), f2bf(acc[m][n][3] + bsv)};
        *(ushort4*)&vt[(((size_t)(bbr * 16 + h)) * 64 + d) * 2048 + t] = pw;
      }
    }
  }
}

// ---------------- MFMA flash attention (pair-balanced, 8 waves) ----------
// grid (8, 64), 512 thr = 8 waves; wave owns 16 q-rows; block q-tile = 128.
// Block handles q-tiles {i, 15-i} -> uniform 34 KV-tiles. Swapped QK^T
// (scale folded into Q); interior tiles skip masking; P via swizzled LDS.
constexpr int QB = 128, KVB = 64;
__global__ __launch_bounds__(512) void attn_kernel(const ushort* __restrict__ Qb,
                                                   const ushort* __restrict__ Kb,
                                                   const ushort* __restrict__ Vt,
                                                   ushort* __restrict__ att) {
  __shared__ __align__(16) ushort Klds[64 * 64];  // [kv][d], rows XOR-swizzled
  __shared__ __align__(16) ushort Vlds[64 * 64];  // [d][kv], rows XOR-swizzled
  __shared__ __align__(16) ushort Plds[8][16 * 64];  // per-wave [q][k]
  int tid = threadIdx.x, wid = tid >> 6, lane = tid & 63;
  int fr = lane & 15, fq = lane >> 4;
  int bh = blockIdx.y, bb = bh >> 4, hh = bh & 15;
  const ushort* qkbase = Qb + ((size_t)bb * Tt) * Cc + hh * HSz;
  const ushort* Kbase = Kb + ((size_t)bb * Tt) * Cc + hh * HSz;
  const ushort* Vbase = Vt + ((size_t)(bb * Hh + hh)) * HSz * Tt;

#pragma unroll 1
  for (int pass = 0; pass < 2; ++pass) {
    int qt = pass ? (Tt / QB - 1 - (int)blockIdx.x) : (int)blockIdx.x;
    int q0 = qt * QB;
    int q0w = q0 + wid * 16;

    bf16x8 Qreg[2];
#pragma unroll
    for (int d2 = 0; d2 < 2; ++d2)
      Qreg[d2] = *(const bf16x8*)(qkbase + (size_t)(q0w + fr) * Cc + d2 * 32 + fq * 8);
    f32x4 Oa[4] = {};  // [ds]; lane holds O[q=fq*4+reg][d=ds*16+fr]
    float mrow = -1e30f, lrow = 0.f;
    int nt = q0 / KVB + 2;

    for (int kt = 0; kt < nt; ++kt) {
      int t0 = kt * KVB;
      __syncthreads();  // previous tile's LDS reads complete
      {
        // stage K[64][64] and Vt[64][64]: 512 slots each, 1 per thread
        int row = tid >> 3;
        int b = (tid & 7) * 16;
        int sw = (b >> 1) ^ ((row & 7) << 3);  // inverse-swz source (ushort)
        gload16(Kbase + (size_t)(t0 + row) * Cc + sw, (char*)Klds + wid * 1024);
        gload16(Vbase + (size_t)row * Tt + t0 + sw, (char*)Vlds + wid * 1024);
      }
      __syncthreads();
      if (q0w + 15 < t0) continue;  // wave fully masked

      // ---- QK^T swapped: accs[ks] = S^T (16k x 16q) ----
      bf16x8 kf[4][2];
#pragma unroll
      for (int ks = 0; ks < 4; ++ks)
#pragma unroll
        for (int d2 = 0; d2 < 2; ++d2) {
          int row = ks * 16 + fr;
          int off = (d2 * 64 + fq * 16) ^ ((row & 7) << 4);
          kf[ks][d2] = *(const bf16x8*)((const char*)Klds + row * 128 + off);
        }
      f32x4 accs[4] = {};
      __builtin_amdgcn_s_setprio(1);
#pragma unroll
      for (int ks = 0; ks < 4; ++ks) {
        accs[ks] = __builtin_amdgcn_mfma_f32_16x16x32_bf16(
            kf[ks][0], Qreg[0], accs[ks], 0, 0, 0);
        accs[ks] = __builtin_amdgcn_mfma_f32_16x16x32_bf16(
            kf[ks][1], Qreg[1], accs[ks], 0, 0, 0);
      }
      __builtin_amdgcn_s_setprio(0);

      // ---- softmax: row q=fr spread over 4 fq lanes ----
      float sv[4][4];
      float vmax = -1e30f;
      if (t0 + 63 <= q0w) {  // interior: no causal mask needed
#pragma unroll
        for (int ks = 0; ks < 4; ++ks)
#pragma unroll
          for (int j = 0; j < 4; ++j) {
            sv[ks][j] = accs[ks][j];
            vmax = fmaxf(vmax, sv[ks][j]);
          }
      } else {
        int qg = q0w + fr;
#pragma unroll
        for (int ks = 0; ks < 4; ++ks)
#pragma unroll
          for (int j = 0; j < 4; ++j) {
            int kg = t0 + ks * 16 + fq * 4 + j;
            float s = accs[ks][j];
            s = (kg <= qg) ? s : -1e30f;
            sv[ks][j] = s;
            vmax = fmaxf(vmax, s);
          }
      }
      vmax = fmaxf(vmax, __shfl_xor(vmax, 16));
      vmax = fmaxf(vmax, __shfl_xor(vmax, 32));
      // T13 defer-rescale: only rescale when some row's max grew > THR
      float mnew = mrow;
      if (!__all(vmax <= mnew + 11.0f)) {
        mnew = fmaxf(mrow, vmax);
        float sf = exp2f(mrow - mnew);
        mrow = mnew;
        lrow *= sf;
#pragma unroll
        for (int j = 0; j < 4; ++j) {
          float sfo = __shfl(sf, fq * 4 + j);
#pragma unroll
          for (int ds = 0; ds < 4; ++ds) Oa[ds][j] *= sfo;
        }
      }
      float ls = 0.f;
      char* pbase = (char*)Plds[wid] + fr * 128;
#pragma unroll
      for (int ks = 0; ks < 4; ++ks) {
        float p0 = exp2f(sv[ks][0] - mnew);
        float p1 = exp2f(sv[ks][1] - mnew);
        float p2 = exp2f(sv[ks][2] - mnew);
        float p3 = exp2f(sv[ks][3] - mnew);
        ls += (p0 + p1) + (p2 + p3);
        uint2 pw = {cvtpk_bf16(p0, p1), cvtpk_bf16(p2, p3)};
        int off = (ks * 32 + fq * 8) ^ ((fr & 7) << 4);
        *(uint2*)(pbase + off) = pw;
      }
      ls += __shfl_xor(ls, 16);
      ls += __shfl_xor(ls, 32);
      lrow += ls;

      // ---- PV: O += P(16q x 64k) * V(64k x 64d) ----
      bf16x8 vf[4][2];
#pragma unroll
      for (int ds = 0; ds < 4; ++ds)
#pragma unroll
        for (int k2 = 0; k2 < 2; ++k2) {
          int row = ds * 16 + fr;
          int off = (k2 * 64 + fq * 16) ^ ((row & 7) << 4);
          vf[ds][k2] = *(const bf16x8*)((const char*)Vlds + row * 128 + off);
        }
      bf16x8 pf[2];
#pragma unroll
      for (int k2 = 0; k2 < 2; ++k2) {
        int off = (k2 * 64 + fq * 16) ^ ((fr & 7) << 4);
        pf[k2] = *(const bf16x8*)((const char*)Plds[wid] + fr * 128 + off);
      }
      __builtin_amdgcn_s_setprio(1);
#pragma unroll
      for (int ds = 0; ds < 4; ++ds) {
        Oa[ds] = __builtin_amdgcn_mfma_f32_16x16x32_bf16(
            pf[0], vf[ds][0], Oa[ds], 0, 0, 0);
        Oa[ds] = __builtin_amdgcn_mfma_f32_16x16x32_bf16(
            pf[1], vf[ds][1], Oa[ds], 0, 0, 0);
      }
      __builtin_amdgcn_s_setprio(0);
    }

    // ---- epilogue ----
    {
      float linv = 1.f / lrow;
#pragma unroll
      for (int j = 0; j < 4; ++j) {
        float lo = __shfl(linv, fq * 4 + j);
        int qg = q0w + fq * 4 + j;
        ushort* orow = att + (size_t)(bb * Tt + qg) * Cc + hh * HSz;
#pragma unroll
        for (int ds = 0; ds < 4; ++ds)
          orow[ds * 16 + fr] = f2bf(Oa[ds][j] * lo);
      }
    }
  }
}

extern "C" void kernel_launch(void* const* d_in, const int* in_sizes, int n_in,
                              void* d_out, int out_size, void* d_ws,
                              size_t ws_size, hipStream_t stream) {
  const float* x = (const float*)d_in[0];
  const float* wq = (const float*)d_in[1];
  const float* bq = (const float*)d_in[2];
  const float* wk = (const float*)d_in[3];
  const float* bk = (const float*)d_in[4];
  const float* wv = (const float*)d_in[5];
  const float* bv = (const float*)d_in[6];
  const float* wp = (const float*)d_in[7];
  const float* bp = (const float*)d_in[8];
  const float* w1 = (const float*)d_in[9];
  const float* b1 = (const float*)d_in[10];
  const float* w2 = (const float*)d_in[11];
  const float* b2 = (const float*)d_in[12];
  const float* g1 = (const float*)d_in[13];
  const float* be1 = (const float*)d_in[14];
  const float* g2 = (const float*)d_in[15];
  const float* be2 = (const float*)d_in[16];
  float* out = (float*)d_out;

  ushort* Qb = (ushort*)d_ws;                 // [8192][1024]
  ushort* Kb = Qb + (size_t)8388608;          // [8192][1024]
  ushort* Vt = Kb + (size_t)8388608;          // [4][16][64][2048]
  ushort* att = Vt + (size_t)8388608;         // [8192][1024]
  ushort* ffh = Qb;                           // [8192][4096] overlay
  ushort* h1b = att + (size_t)8388608;        // LN1/LN2 out
  float* x2 = (float*)(h1b + (size_t)8388608);
  ushort* wqkvT = (ushort*)(x2 + (size_t)8388608);  // [3072][1024]
  ushort* wpT = wqkvT + (size_t)3145728;            // [1024][1024]
  ushort* w1T = wpT + (size_t)1048576;              // [4096][1024]
  ushort* w2T = w1T + (size_t)4194304;              // [1024][4096]
  float* bqkv = (float*)(w2T + (size_t)4194304);    // [3072]

  tcast_qkv<<<dim3(32, 2, 48), 256, 0, stream>>>(wq, wk, wv, wqkvT);
  tcast_kernel<<<dim3(32, 32), 256, 0, stream>>>(wp, wpT, 1024, 1024);
  tcast_kernel<<<dim3(32, 128), 256, 0, stream>>>(w1, w1T, 4096, 1024);
  tcast_kernel<<<dim3(128, 32), 256, 0, stream>>>(w2, w2T, 1024, 4096);
  bias_concat<<<dim3(12), 256, 0, stream>>>(bq, bk, bv, bqkv);

  // 1) h1b = LN(x)
  ln_kernel<<<dim3(Mrows), 256, 0, stream>>>(x, g1, be1, h1b);
  // 2) Q,K,Vt = h1b @ WqkvT^T + bqkv (Q pre-scaled; V written transposed)
  gemm_qkv<<<dim3(24, 64), 512, 0, stream>>>(h1b, wqkvT, bqkv, Qb, Kb, Vt);
  // 3) att = causal_softmax(Q K^T) V  (paired q-tiles, 8 waves)
  attn_kernel<<<dim3(Tt / QB / 2, Bb * Hh), 512, 0, stream>>>(Qb, Kb, Vt, att);
  // 4) x2 = x + att @ wp + bp
  gemm_bf16<false, true, false><<<dim3(8, 64), 512, 0, stream>>>(
      att, 1024, wpT, 1024, bp, x, x2, 1024, 1024);
  // 5) h2b = LN(x2)
  ln_kernel<<<dim3(Mrows), 256, 0, stream>>>(x2, g2, be2, h1b);
  // 6) ffh = relu(h2b @ w1 + b1)
  gemm_bf16<true, false, true><<<dim3(32, 64), 512, 0, stream>>>(
      h1b, 1024, w1T, 1024, b1, nullptr, ffh, 4096, 1024);
  // 7) out = x2 + ffh @ w2 + b2
  gemm_bf16<false, true, false><<<dim3(8, 64), 512, 0, stream>>>(
      ffh, 4096, w2T, 4096, b2, x2, out, 1024, 4096);
}

// Round 8
// 367.967 us; speedup vs baseline: 12.9088x; 1.0079x over previous
//
#include <hip/hip_runtime.h>

// Transformer block. Round 7: attn latency — K/V LDS double-buffer with
// issue-after-barrier prefetch (1 barrier/tile, HBM latency hidden under
// previous tile's compute) + shuffle-free softmax common path (defer test on
// local max, per-lane partial l, epilogue reduce). GEMMs unchanged (round 4/5).
//
// Workspace (~136 MiB):
//   [Q 16M | K 16M | Vt 16M | att 16M]  <- ffh bf16 64M overlays exactly
//   [h1b 16M][x2 f32 32M][wqkvT 6M][wpT 2M][w1T 8M][w2T 8M][bqkv]

constexpr int Bb = 4, Tt = 2048, Cc = 1024, Hh = 16, HSz = 64, Ff = 4096;
constexpr int Mrows = Bb * Tt;  // 8192

typedef __attribute__((ext_vector_type(8))) short bf16x8;
typedef __attribute__((ext_vector_type(4))) float f32x4;

__device__ __forceinline__ ushort f2bf(float f) {
  uint u = __builtin_bit_cast(uint, f);
  uint r = (u + 0x7fffu + ((u >> 16) & 1u)) >> 16;
  return (ushort)r;
}
__device__ __forceinline__ float bf2f(ushort s) {
  return __builtin_bit_cast(float, ((uint)s) << 16);
}
__device__ __forceinline__ uint cvtpk_bf16(float lo, float hi) {
  uint r;
  asm("v_cvt_pk_bf16_f32 %0, %1, %2" : "=v"(r) : "v"(lo), "v"(hi));
  return r;
}
__device__ __forceinline__ void gload16(const void* g, void* l) {
  __builtin_amdgcn_global_load_lds(
      (const __attribute__((address_space(1))) void*)g,
      (__attribute__((address_space(3))) void*)l, 16, 0, 0);
}

// ---------------- LayerNorm: fp32 in, bf16 out ----------------
__global__ __launch_bounds__(256) void ln_kernel(const float* __restrict__ x,
                                                 const float* __restrict__ g,
                                                 const float* __restrict__ b,
                                                 ushort* __restrict__ out) {
  int row = blockIdx.x;
  const float* xr = x + (size_t)row * Cc;
  int c4 = threadIdx.x * 4;
  float4 v = *(const float4*)(xr + c4);
  float s1 = v.x + v.y + v.z + v.w;
  float s2 = v.x * v.x + v.y * v.y + v.z * v.z + v.w * v.w;
#pragma unroll
  for (int off = 32; off >= 1; off >>= 1) {
    s1 += __shfl_xor(s1, off);
    s2 += __shfl_xor(s2, off);
  }
  __shared__ float red[8];
  int wid = threadIdx.x >> 6, lane = threadIdx.x & 63;
  if (lane == 0) { red[wid] = s1; red[4 + wid] = s2; }
  __syncthreads();
  float t1 = red[0] + red[1] + red[2] + red[3];
  float t2 = red[4] + red[5] + red[6] + red[7];
  float mu = t1 * (1.0f / Cc);
  float var = t2 * (1.0f / Cc) - mu * mu;
  float rs = rsqrtf(var + 1e-5f);
  float4 gv = *(const float4*)(g + c4);
  float4 bv = *(const float4*)(b + c4);
  ushort4 o;
  o.x = f2bf((v.x - mu) * rs * gv.x + bv.x);
  o.y = f2bf((v.y - mu) * rs * gv.y + bv.y);
  o.z = f2bf((v.z - mu) * rs * gv.z + bv.z);
  o.w = f2bf((v.w - mu) * rs * gv.w + bv.w);
  *(ushort4*)(out + (size_t)row * Cc + c4) = o;
}

// ---------------- Transpose-cast fp32 [R][C] -> bf16 [C][R] ----------------
__device__ __forceinline__ void tcast_body(const float* __restrict__ src,
                                           ushort* __restrict__ dst, int ldS,
                                           int ldD, int r0, int c0) {
  __shared__ float t[32][33];
  int c = threadIdx.x & 31, r8 = threadIdx.x >> 5;
#pragma unroll
  for (int i = 0; i < 4; ++i) {
    int r = r8 + i * 8;
    t[r][c] = src[(size_t)(r0 + r) * ldS + c0 + c];
  }
  __syncthreads();
#pragma unroll
  for (int i = 0; i < 4; ++i) {
    int rr = r8 + i * 8;
    dst[(size_t)(c0 + rr) * ldD + r0 + c] = f2bf(t[c][rr]);
  }
}

__global__ __launch_bounds__(256) void tcast_kernel(const float* __restrict__ src,
                                                    ushort* __restrict__ dst,
                                                    int ldS, int ldD) {
  tcast_body(src, dst, ldS, ldD, blockIdx.x * 32, blockIdx.y * 32);
}

__global__ __launch_bounds__(256) void tcast_qkv(const float* __restrict__ wq,
                                                 const float* __restrict__ wk,
                                                 const float* __restrict__ wv,
                                                 ushort* __restrict__ dst) {
  int z = blockIdx.z, zz = z >> 4, h = z & 15;
  const float* src = (zz == 0 ? wq : (zz == 1 ? wk : wv)) + (size_t)h * Cc * HSz;
  ushort* d = dst + (size_t)(zz * 1024 + h * 64) * 1024;
  tcast_body(src, d, HSz, Cc, blockIdx.x * 32, blockIdx.y * 32);
}

__global__ __launch_bounds__(256) void bias_concat(const float* __restrict__ bq,
                                                   const float* __restrict__ bk,
                                                   const float* __restrict__ bv,
                                                   float* __restrict__ dst) {
  int i = blockIdx.x * 256 + threadIdx.x;
  dst[i] = i < 1024 ? bq[i] : (i < 2048 ? bk[i - 1024] : bv[i - 2048]);
}

// -------- bf16 MFMA GEMM: 128x128 tile, BK=64, 8 waves (2Mx4N) ----------
__device__ __forceinline__ void gemm_main(const ushort* __restrict__ A, int lda,
                                          const ushort* __restrict__ Bt, int ldb,
                                          int K, int m0, int n0,
                                          ushort* __restrict__ As,
                                          ushort* __restrict__ Bs,
                                          f32x4 (&acc)[4][2]) {
  int tid = threadIdx.x, wid = tid >> 6, lane = tid & 63;
  int wr = wid >> 2, wc = wid & 3, fr = lane & 15, fq = lane >> 4;
  const ushort* Ag = A + (size_t)m0 * lda;
  const ushort* Bg = Bt + (size_t)n0 * ldb;
  for (int k0 = 0; k0 < K; k0 += 64) {
#pragma unroll
    for (int c = 0; c < 2; ++c) {
      int slot = c * 512 + tid;
      int row = slot >> 3, s = slot & 7;
      int sw = (s << 3) ^ ((row & 7) << 3);  // inverse-swz source (ushorts)
      gload16(Ag + (size_t)row * lda + k0 + sw, As + (size_t)(c * 512 + wid * 64) * 8);
      gload16(Bg + (size_t)row * ldb + k0 + sw, Bs + (size_t)(c * 512 + wid * 64) * 8);
    }
    __syncthreads();
    bf16x8 av[4][2], bv[2][2];
#pragma unroll
    for (int m = 0; m < 4; ++m) {
      int row = wr * 64 + m * 16 + fr;
#pragma unroll
      for (int ks = 0; ks < 2; ++ks)
        av[m][ks] = *(const bf16x8*)&As[row * 64 + (((ks * 4 + fq) ^ (row & 7)) << 3)];
    }
#pragma unroll
    for (int n = 0; n < 2; ++n) {
      int row = wc * 32 + n * 16 + fr;
#pragma unroll
      for (int ks = 0; ks < 2; ++ks)
        bv[n][ks] = *(const bf16x8*)&Bs[row * 64 + (((ks * 4 + fq) ^ (row & 7)) << 3)];
    }
#pragma unroll
    for (int m = 0; m < 4; ++m)
#pragma unroll
      for (int n = 0; n < 2; ++n)
#pragma unroll
        for (int ks = 0; ks < 2; ++ks)
          acc[m][n] = __builtin_amdgcn_mfma_f32_16x16x32_bf16(
              av[m][ks], bv[n][ks], acc[m][n], 0, 0, 0);
    __syncthreads();
  }
}

// XCD-chunked bijective block swizzle (all grids %8 == 0).
__device__ __forceinline__ void xcd_swz(int& bx, int& by) {
  int bid = blockIdx.x + blockIdx.y * gridDim.x;
  int cpx = (gridDim.x * gridDim.y) >> 3;
  int id = (bid & 7) * cpx + (bid >> 3);
  bx = id % gridDim.x;
  by = id / gridDim.x;
}

template <bool RELU, bool HASRES, bool OUTBF16>
__global__ __launch_bounds__(512) void gemm_bf16(
    const ushort* __restrict__ A, int lda, const ushort* __restrict__ Bt,
    int ldb, const float* __restrict__ bias, const float* __restrict__ res,
    void* __restrict__ Cout, int ldc, int K) {
  __shared__ __align__(16) ushort As[128 * 64];
  __shared__ __align__(16) ushort Bs[128 * 64];
  f32x4 acc[4][2] = {};
  int bx, by;
  xcd_swz(bx, by);
  int m0 = by * 128, n0 = bx * 128;
  gemm_main(A, lda, Bt, ldb, K, m0, n0, As, Bs, acc);
  int lane = threadIdx.x & 63, wid = threadIdx.x >> 6;
  int wr = wid >> 2, wc = wid & 3, fr = lane & 15, fq = lane >> 4;
#pragma unroll
  for (int m = 0; m < 4; ++m) {
    int gm = m0 + wr * 64 + m * 16 + fq * 4;
#pragma unroll
    for (int n = 0; n < 2; ++n) {
      int gn = n0 + wc * 32 + n * 16 + fr;
      float bsv = bias[gn];
#pragma unroll
      for (int j = 0; j < 4; ++j) {
        int row = gm + j;
        float v = acc[m][n][j] + bsv;
        if constexpr (HASRES) v += res[(size_t)row * ldc + gn];
        if constexpr (RELU) v = fmaxf(v, 0.f);
        if constexpr (OUTBF16)
          ((ushort*)Cout)[(size_t)row * ldc + gn] = f2bf(v);
        else
          ((float*)Cout)[(size_t)row * ldc + gn] = v;
      }
    }
  }
}

// QKV GEMM: N-cols [0,1024)->Q (pre-scaled by log2e/32), [1024,2048)->K,
// [2048,3072)->Vt transposed [B][H][HS][T] (j-contiguous ushort4 stores).
__global__ __launch_bounds__(512) void gemm_qkv(const ushort* __restrict__ A,
                                                const ushort* __restrict__ Bt,
                                                const float* __restrict__ bias,
                                                ushort* __restrict__ q,
                                                ushort* __restrict__ k,
                                                ushort* __restrict__ vt) {
  __shared__ __align__(16) ushort As[128 * 64];
  __shared__ __align__(16) ushort Bs[128 * 64];
  f32x4 acc[4][2] = {};
  int bx, by;
  xcd_swz(bx, by);
  int m0 = by * 128, n0 = bx * 128;
  gemm_main(A, 1024, Bt, 1024, 1024, m0, n0, As, Bs, acc);
  int lane = threadIdx.x & 63, wid = threadIdx.x >> 6;
  int wr = wid >> 2, wc = wid & 3, fr = lane & 15, fq = lane >> 4;
  const float qscale = 1.4426950408889634f / 32.0f;  // log2e * C^-0.5
#pragma unroll
  for (int m = 0; m < 4; ++m) {
    int gm = m0 + wr * 64 + m * 16 + fq * 4;
#pragma unroll
    for (int n = 0; n < 2; ++n) {
      int gn = n0 + wc * 32 + n * 16 + fr;
      float bsv = bias[gn];
      if (gn < 1024) {
#pragma unroll
        for (int j = 0; j < 4; ++j)
          q[(size_t)(gm + j) * 1024 + gn] = f2bf((acc[m][n][j] + bsv) * qscale);
      } else if (gn < 2048) {
        int col = gn - 1024;
#pragma unroll
        for (int j = 0; j < 4; ++j)
          k[(size_t)(gm + j) * 1024 + col] = f2bf(acc[m][n][j] + bsv);
      } else {
        int dd = gn - 2048, h = dd >> 6, d = dd & 63;
        int bbr = gm >> 11, t = gm & 2047;
        ushort4 pw = {f2bf(acc[m][n][0] + bsv), f2bf(acc[m][n][1] + bsv),
                      f2bf(acc[m][n][2] + bsv), f2bf(acc[m][n][3] + bsv)};
        *(ushort4*)&vt[(((size_t)(bbr * 16 + h)) * 64 + d) * 2048 + t] = pw;
      }
    }
  }
}

// ---------------- MFMA flash attention (pair-balanced, 8 waves, dbuf) ------
// grid (8, 64), 512 thr = 8 waves; wave owns 16 q-rows; block q-tile = 128.
// K/V double-buffered: stage of tile k+1 issued right after the single
// per-tile barrier -> HBM latency hides under tile k's compute. Softmax
// common path has zero cross-lane shuffles (defer test on local max,
// per-lane partial l reduced in the epilogue).
constexpr int QB = 128, KVB = 64;
__global__ __launch_bounds__(512) void attn_kernel(const ushort* __restrict__ Qb,
                                                   const ushort* __restrict__ Kb,
                                                   const ushort* __restrict__ Vt,
                                                   ushort* __restrict__ att) {
  __shared__ __align__(16) ushort Klds[2][64 * 64];  // [buf][kv][d], swizzled
  __shared__ __align__(16) ushort Vlds[2][64 * 64];  // [buf][d][kv], swizzled
  __shared__ __align__(16) ushort Plds[8][16 * 64];  // per-wave [q][k]
  int tid = threadIdx.x, wid = tid >> 6, lane = tid & 63;
  int fr = lane & 15, fq = lane >> 4;
  int bh = blockIdx.y, bb = bh >> 4, hh = bh & 15;
  const ushort* qkbase = Qb + ((size_t)bb * Tt) * Cc + hh * HSz;
  const ushort* Kbase = Kb + ((size_t)bb * Tt) * Cc + hh * HSz;
  const ushort* Vbase = Vt + ((size_t)(bb * Hh + hh)) * HSz * Tt;
  // per-thread staging slot (constant across tiles)
  int srow = tid >> 3;
  int ssw = ((tid & 7) << 3) ^ ((srow & 7) << 3);  // inverse-swz src (ushort)

#pragma unroll 1
  for (int pass = 0; pass < 2; ++pass) {
    int qt = pass ? (Tt / QB - 1 - (int)blockIdx.x) : (int)blockIdx.x;
    int q0 = qt * QB;
    int q0w = q0 + wid * 16;

    bf16x8 Qreg[2];
#pragma unroll
    for (int d2 = 0; d2 < 2; ++d2)
      Qreg[d2] = *(const bf16x8*)(qkbase + (size_t)(q0w + fr) * Cc + d2 * 32 + fq * 8);
    f32x4 Oa[4] = {};  // [ds]; lane holds O[q=fq*4+reg][d=ds*16+fr]
    float mrow = -1e30f, lrow = 0.f;  // lrow = per-lane PARTIAL sum
    int nt = q0 / KVB + 2;

    __syncthreads();  // protect buf0 from previous pass's readers
    // prologue: stage tile 0 -> buf 0
    gload16(Kbase + (size_t)srow * Cc + ssw, (char*)Klds[0] + wid * 1024);
    gload16(Vbase + (size_t)srow * Tt + ssw, (char*)Vlds[0] + wid * 1024);

#pragma unroll 1
    for (int kt = 0; kt < nt; ++kt) {
      int t0 = kt * KVB;
      int c = kt & 1;
      __syncthreads();  // drains vmcnt(0): tile kt landed; WAR for buf c^1
      if (kt + 1 < nt) {  // stage tile kt+1 -> buf c^1 (lands during compute)
        int t0n = t0 + KVB;
        gload16(Kbase + (size_t)(t0n + srow) * Cc + ssw,
                (char*)Klds[c ^ 1] + wid * 1024);
        gload16(Vbase + (size_t)srow * Tt + t0n + ssw,
                (char*)Vlds[c ^ 1] + wid * 1024);
      }
      if (q0w + 15 < t0) continue;  // wave fully masked

      // ---- QK^T swapped: accs[ks] = S^T (16k x 16q) ----
      const char* Kc = (const char*)Klds[c];
      const char* Vc = (const char*)Vlds[c];
      bf16x8 kf[4][2];
#pragma unroll
      for (int ks = 0; ks < 4; ++ks)
#pragma unroll
        for (int d2 = 0; d2 < 2; ++d2) {
          int row = ks * 16 + fr;
          int off = (d2 * 64 + fq * 16) ^ ((row & 7) << 4);
          kf[ks][d2] = *(const bf16x8*)(Kc + row * 128 + off);
        }
      f32x4 accs[4] = {};
      __builtin_amdgcn_s_setprio(1);
#pragma unroll
      for (int ks = 0; ks < 4; ++ks) {
        accs[ks] = __builtin_amdgcn_mfma_f32_16x16x32_bf16(
            kf[ks][0], Qreg[0], accs[ks], 0, 0, 0);
        accs[ks] = __builtin_amdgcn_mfma_f32_16x16x32_bf16(
            kf[ks][1], Qreg[1], accs[ks], 0, 0, 0);
      }
      __builtin_amdgcn_s_setprio(0);

      // ---- softmax: shuffle-free common path ----
      float sv[4][4];
      float vmax = -1e30f;  // LOCAL max over this lane's 16 values
      if (t0 + 63 <= q0w) {  // interior: no causal mask needed
#pragma unroll
        for (int ks = 0; ks < 4; ++ks)
#pragma unroll
          for (int j = 0; j < 4; ++j) {
            sv[ks][j] = accs[ks][j];
            vmax = fmaxf(vmax, sv[ks][j]);
          }
      } else {
        int qg = q0w + fr;
#pragma unroll
        for (int ks = 0; ks < 4; ++ks)
#pragma unroll
          for (int j = 0; j < 4; ++j) {
            int kg = t0 + ks * 16 + fq * 4 + j;
            float s = accs[ks][j];
            s = (kg <= qg) ? s : -1e30f;
            sv[ks][j] = s;
            vmax = fmaxf(vmax, s);
          }
      }
      // T13 defer-rescale: trigger iff row max grew > THR (local test is
      // equivalent: any lane's local max over THR <=> row max over THR)
      float mnew = mrow;
      if (!__all(vmax <= mrow + 11.0f)) {
        float rmax = fmaxf(vmax, __shfl_xor(vmax, 16));
        rmax = fmaxf(rmax, __shfl_xor(rmax, 32));
        mnew = fmaxf(mrow, rmax);
        float sf = exp2f(mrow - mnew);
        mrow = mnew;
        lrow *= sf;
#pragma unroll
        for (int j = 0; j < 4; ++j) {
          float sfo = __shfl(sf, fq * 4 + j);
#pragma unroll
          for (int ds = 0; ds < 4; ++ds) Oa[ds][j] *= sfo;
        }
      }
      char* pbase = (char*)Plds[wid] + fr * 128;
#pragma unroll
      for (int ks = 0; ks < 4; ++ks) {
        float p0 = exp2f(sv[ks][0] - mnew);
        float p1 = exp2f(sv[ks][1] - mnew);
        float p2 = exp2f(sv[ks][2] - mnew);
        float p3 = exp2f(sv[ks][3] - mnew);
        lrow += (p0 + p1) + (p2 + p3);  // partial only; reduce at epilogue
        uint2 pw = {cvtpk_bf16(p0, p1), cvtpk_bf16(p2, p3)};
        int off = (ks * 32 + fq * 8) ^ ((fr & 7) << 4);
        *(uint2*)(pbase + off) = pw;
      }

      // ---- PV: O += P(16q x 64k) * V(64k x 64d) ----
      bf16x8 vf[4][2];
#pragma unroll
      for (int ds = 0; ds < 4; ++ds)
#pragma unroll
        for (int k2 = 0; k2 < 2; ++k2) {
          int row = ds * 16 + fr;
          int off = (k2 * 64 + fq * 16) ^ ((row & 7) << 4);
          vf[ds][k2] = *(const bf16x8*)(Vc + row * 128 + off);
        }
      bf16x8 pf[2];
#pragma unroll
      for (int k2 = 0; k2 < 2; ++k2) {
        int off = (k2 * 64 + fq * 16) ^ ((fr & 7) << 4);
        pf[k2] = *(const bf16x8*)((const char*)Plds[wid] + fr * 128 + off);
      }
      __builtin_amdgcn_s_setprio(1);
#pragma unroll
      for (int ds = 0; ds < 4; ++ds) {
        Oa[ds] = __builtin_amdgcn_mfma_f32_16x16x32_bf16(
            pf[0], vf[ds][0], Oa[ds], 0, 0, 0);
        Oa[ds] = __builtin_amdgcn_mfma_f32_16x16x32_bf16(
            pf[1], vf[ds][1], Oa[ds], 0, 0, 0);
      }
      __builtin_amdgcn_s_setprio(0);
    }

    // ---- epilogue: reduce partial l across the fq group, normalize ----
    {
      lrow += __shfl_xor(lrow, 16);
      lrow += __shfl_xor(lrow, 32);
      float linv = 1.f / lrow;
#pragma unroll
      for (int j = 0; j < 4; ++j) {
        float lo = __shfl(linv, fq * 4 + j);
        int qg = q0w + fq * 4 + j;
        ushort* orow = att + (size_t)(bb * Tt + qg) * Cc + hh * HSz;
#pragma unroll
        for (int ds = 0; ds < 4; ++ds)
          orow[ds * 16 + fr] = f2bf(Oa[ds][j] * lo);
      }
    }
  }
}

extern "C" void kernel_launch(void* const* d_in, const int* in_sizes, int n_in,
                              void* d_out, int out_size, void* d_ws,
                              size_t ws_size, hipStream_t stream) {
  const float* x = (const float*)d_in[0];
  const float* wq = (const float*)d_in[1];
  const float* bq = (const float*)d_in[2];
  const float* wk = (const float*)d_in[3];
  const float* bk = (const float*)d_in[4];
  const float* wv = (const float*)d_in[5];
  const float* bv = (const float*)d_in[6];
  const float* wp = (const float*)d_in[7];
  const float* bp = (const float*)d_in[8];
  const float* w1 = (const float*)d_in[9];
  const float* b1 = (const float*)d_in[10];
  const float* w2 = (const float*)d_in[11];
  const float* b2 = (const float*)d_in[12];
  const float* g1 = (const float*)d_in[13];
  const float* be1 = (const float*)d_in[14];
  const float* g2 = (const float*)d_in[15];
  const float* be2 = (const float*)d_in[16];
  float* out = (float*)d_out;

  ushort* Qb = (ushort*)d_ws;                 // [8192][1024]
  ushort* Kb = Qb + (size_t)8388608;          // [8192][1024]
  ushort* Vt = Kb + (size_t)8388608;          // [4][16][64][2048]
  ushort* att = Vt + (size_t)8388608;         // [8192][1024]
  ushort* ffh = Qb;                           // [8192][4096] overlay
  ushort* h1b = att + (size_t)8388608;        // LN1/LN2 out
  float* x2 = (float*)(h1b + (size_t)8388608);
  ushort* wqkvT = (ushort*)(x2 + (size_t)8388608);  // [3072][1024]
  ushort* wpT = wqkvT + (size_t)3145728;            // [1024][1024]
  ushort* w1T = wpT + (size_t)1048576;              // [4096][1024]
  ushort* w2T = w1T + (size_t)4194304;              // [1024][4096]
  float* bqkv = (float*)(w2T + (size_t)4194304);    // [3072]

  tcast_qkv<<<dim3(32, 2, 48), 256, 0, stream>>>(wq, wk, wv, wqkvT);
  tcast_kernel<<<dim3(32, 32), 256, 0, stream>>>(wp, wpT, 1024, 1024);
  tcast_kernel<<<dim3(32, 128), 256, 0, stream>>>(w1, w1T, 4096, 1024);
  tcast_kernel<<<dim3(128, 32), 256, 0, stream>>>(w2, w2T, 1024, 4096);
  bias_concat<<<dim3(12), 256, 0, stream>>>(bq, bk, bv, bqkv);

  // 1) h1b = LN(x)
  ln_kernel<<<dim3(Mrows), 256, 0, stream>>>(x, g1, be1, h1b);
  // 2) Q,K,Vt = h1b @ WqkvT^T + bqkv (Q pre-scaled; V written transposed)
  gemm_qkv<<<dim3(24, 64), 512, 0, stream>>>(h1b, wqkvT, bqkv, Qb, Kb, Vt);
  // 3) att = causal_softmax(Q K^T) V  (paired q-tiles, 8 waves, dbuf)
  attn_kernel<<<dim3(Tt / QB / 2, Bb * Hh), 512, 0, stream>>>(Qb, Kb, Vt, att);
  // 4) x2 = x + att @ wp + bp
  gemm_bf16<false, true, false><<<dim3(8, 64), 512, 0, stream>>>(
      att, 1024, wpT, 1024, bp, x, x2, 1024, 1024);
  // 5) h2b = LN(x2)
  ln_kernel<<<dim3(Mrows), 256, 0, stream>>>(x2, g2, be2, h1b);
  // 6) ffh = relu(h2b @ w1 + b1)
  gemm_bf16<true, false, true><<<dim3(32, 64), 512, 0, stream>>>(
      h1b, 1024, w1T, 1024, b1, nullptr, ffh, 4096, 1024);
  // 7) out = x2 + ffh @ w2 + b2
  gemm_bf16<false, true, false><<<dim3(8, 64), 512, 0, stream>>>(
      ffh, 4096, w2T, 4096, b2, x2, out, 1024, 4096);
}

// Round 9
// 358.243 us; speedup vs baseline: 13.2591x; 1.0271x over previous
//
#include <hip/hip_runtime.h>

// Transformer block. Round 8: FFN1 + QKV GEMMs -> 256x256 tile, 8-wave,
// 4-phase K-loop (stage-1-K-tile-ahead into 2-slot LDS ring, raw barriers,
// counted head-start before a single per-K-tile vmcnt(0) drain, setprio
// around MFMA clusters). proj/FFN2 stay on the 128^2 kernel; attn unchanged.
//
// Workspace (~136 MiB): [Q|K|Vt|att] <- ffh overlay; [h1b][x2][weights][bqkv]

constexpr int Bb = 4, Tt = 2048, Cc = 1024, Hh = 16, HSz = 64, Ff = 4096;
constexpr int Mrows = Bb * Tt;  // 8192

typedef __attribute__((ext_vector_type(8))) short bf16x8;
typedef __attribute__((ext_vector_type(4))) float f32x4;

__device__ __forceinline__ ushort f2bf(float f) {
  uint u = __builtin_bit_cast(uint, f);
  uint r = (u + 0x7fffu + ((u >> 16) & 1u)) >> 16;
  return (ushort)r;
}
__device__ __forceinline__ float bf2f(ushort s) {
  return __builtin_bit_cast(float, ((uint)s) << 16);
}
__device__ __forceinline__ uint cvtpk_bf16(float lo, float hi) {
  uint r;
  asm("v_cvt_pk_bf16_f32 %0, %1, %2" : "=v"(r) : "v"(lo), "v"(hi));
  return r;
}
__device__ __forceinline__ void gload16(const void* g, void* l) {
  __builtin_amdgcn_global_load_lds(
      (const __attribute__((address_space(1))) void*)g,
      (__attribute__((address_space(3))) void*)l, 16, 0, 0);
}
#define VMCNT0 asm volatile("s_waitcnt vmcnt(0)" ::: "memory")
#define LGKM0                                        \
  do {                                               \
    asm volatile("s_waitcnt lgkmcnt(0)" ::: "memory"); \
    __builtin_amdgcn_sched_barrier(0);               \
  } while (0)
#define BARRIER __builtin_amdgcn_s_barrier()

// ---------------- LayerNorm: fp32 in, bf16 out ----------------
__global__ __launch_bounds__(256) void ln_kernel(const float* __restrict__ x,
                                                 const float* __restrict__ g,
                                                 const float* __restrict__ b,
                                                 ushort* __restrict__ out) {
  int row = blockIdx.x;
  const float* xr = x + (size_t)row * Cc;
  int c4 = threadIdx.x * 4;
  float4 v = *(const float4*)(xr + c4);
  float s1 = v.x + v.y + v.z + v.w;
  float s2 = v.x * v.x + v.y * v.y + v.z * v.z + v.w * v.w;
#pragma unroll
  for (int off = 32; off >= 1; off >>= 1) {
    s1 += __shfl_xor(s1, off);
    s2 += __shfl_xor(s2, off);
  }
  __shared__ float red[8];
  int wid = threadIdx.x >> 6, lane = threadIdx.x & 63;
  if (lane == 0) { red[wid] = s1; red[4 + wid] = s2; }
  __syncthreads();
  float t1 = red[0] + red[1] + red[2] + red[3];
  float t2 = red[4] + red[5] + red[6] + red[7];
  float mu = t1 * (1.0f / Cc);
  float var = t2 * (1.0f / Cc) - mu * mu;
  float rs = rsqrtf(var + 1e-5f);
  float4 gv = *(const float4*)(g + c4);
  float4 bv = *(const float4*)(b + c4);
  ushort4 o;
  o.x = f2bf((v.x - mu) * rs * gv.x + bv.x);
  o.y = f2bf((v.y - mu) * rs * gv.y + bv.y);
  o.z = f2bf((v.z - mu) * rs * gv.z + bv.z);
  o.w = f2bf((v.w - mu) * rs * gv.w + bv.w);
  *(ushort4*)(out + (size_t)row * Cc + c4) = o;
}

// ---------------- Transpose-cast fp32 [R][C] -> bf16 [C][R] ----------------
__device__ __forceinline__ void tcast_body(const float* __restrict__ src,
                                           ushort* __restrict__ dst, int ldS,
                                           int ldD, int r0, int c0) {
  __shared__ float t[32][33];
  int c = threadIdx.x & 31, r8 = threadIdx.x >> 5;
#pragma unroll
  for (int i = 0; i < 4; ++i) {
    int r = r8 + i * 8;
    t[r][c] = src[(size_t)(r0 + r) * ldS + c0 + c];
  }
  __syncthreads();
#pragma unroll
  for (int i = 0; i < 4; ++i) {
    int rr = r8 + i * 8;
    dst[(size_t)(c0 + rr) * ldD + r0 + c] = f2bf(t[c][rr]);
  }
}

__global__ __launch_bounds__(256) void tcast_kernel(const float* __restrict__ src,
                                                    ushort* __restrict__ dst,
                                                    int ldS, int ldD) {
  tcast_body(src, dst, ldS, ldD, blockIdx.x * 32, blockIdx.y * 32);
}

__global__ __launch_bounds__(256) void tcast_qkv(const float* __restrict__ wq,
                                                 const float* __restrict__ wk,
                                                 const float* __restrict__ wv,
                                                 ushort* __restrict__ dst) {
  int z = blockIdx.z, zz = z >> 4, h = z & 15;
  const float* src = (zz == 0 ? wq : (zz == 1 ? wk : wv)) + (size_t)h * Cc * HSz;
  ushort* d = dst + (size_t)(zz * 1024 + h * 64) * 1024;
  tcast_body(src, d, HSz, Cc, blockIdx.x * 32, blockIdx.y * 32);
}

__global__ __launch_bounds__(256) void bias_concat(const float* __restrict__ bq,
                                                   const float* __restrict__ bk,
                                                   const float* __restrict__ bv,
                                                   float* __restrict__ dst) {
  int i = blockIdx.x * 256 + threadIdx.x;
  dst[i] = i < 1024 ? bq[i] : (i < 2048 ? bk[i - 1024] : bv[i - 2048]);
}

// XCD-chunked bijective block swizzle (all grids %8 == 0).
__device__ __forceinline__ void xcd_swz(int& bx, int& by) {
  int bid = blockIdx.x + blockIdx.y * gridDim.x;
  int cpx = (gridDim.x * gridDim.y) >> 3;
  int id = (bid & 7) * cpx + (bid >> 3);
  bx = id % gridDim.x;
  by = id / gridDim.x;
}

// ============ 256x256 tile, BK=64, 8 waves (2Mx4N), 4-phase K-loop =========
// K fixed at 1024 (16 K-tiles). LDS: 2-slot ring, 32 KB A + 32 KB B per slot
// (128 KiB total). Per K-tile: stage next K-tile's 4 half-tiles during
// phases 0-1 (head start ~2.5 phases), single vmcnt(0) drain at tile end.
// Rows 128 B, XOR-swizzled (slot ^= row&7) -> conflict-free ds_read_b128.
template <int MH, int NH>
__device__ __forceinline__ void mfma16(f32x4 (&acc)[8][4], bf16x8 (&a)[4][2],
                                       bf16x8 (&b)[2][2]) {
#pragma unroll
  for (int m = 0; m < 4; ++m)
#pragma unroll
    for (int n = 0; n < 2; ++n)
#pragma unroll
      for (int kk = 0; kk < 2; ++kk)
        acc[MH * 4 + m][NH * 2 + n] = __builtin_amdgcn_mfma_f32_16x16x32_bf16(
            a[m][kk], b[n][kk], acc[MH * 4 + m][NH * 2 + n], 0, 0, 0);
}

__device__ __forceinline__ void gemm256_main(const ushort* __restrict__ A,
                                             const ushort* __restrict__ Bt,
                                             int m0, int n0,
                                             ushort* __restrict__ As,
                                             ushort* __restrict__ Bs,
                                             f32x4 (&acc)[8][4]) {
  constexpr int NKT = 16;  // K = 1024
  int tid = threadIdx.x, wid = tid >> 6, lane = tid & 63;
  int wr = wid >> 2, wc = wid & 3, fr = lane & 15, fq = lane >> 4;
  const ushort* Ag = A + (size_t)m0 * 1024;
  const ushort* Bg = Bt + (size_t)n0 * 1024;
  // per-thread staging geometry (c=0: rows 0-63 of half; c=1: rows 64-127)
  int r0 = tid >> 3, r1 = 64 + (tid >> 3);
  int sc = ((tid & 7) ^ ((tid >> 3) & 7)) << 3;  // inverse-swz src col (ushort)

  auto stage = [&](int ktn, int h, int ns) {  // h: 0=A-h0 1=A-h1 2=B-h0 3=B-h1
    const ushort* g = (h < 2) ? Ag : Bg;
    ushort* l = ((h < 2) ? As : Bs) + ns * 16384 + (h & 1) * 8192;
    int kcol = ktn * 64, rbase = (h & 1) * 128;
    gload16(g + (size_t)(rbase + r0) * 1024 + kcol + sc, l + (size_t)wid * 512);
    gload16(g + (size_t)(rbase + r1) * 1024 + kcol + sc,
            l + (size_t)(512 + wid * 64) * 8);
  };
  auto readA = [&](int slot, int mh, bf16x8 (&a)[4][2]) {
#pragma unroll
    for (int m = 0; m < 4; ++m) {
      int row = wr * 128 + mh * 64 + m * 16 + fr;
#pragma unroll
      for (int kk = 0; kk < 2; ++kk)
        a[m][kk] = *(const bf16x8*)&As[slot * 16384 + row * 64 +
                                       (((kk * 4 + fq) ^ (row & 7)) << 3)];
    }
  };
  auto readB = [&](int slot, int nh, bf16x8 (&b)[2][2]) {
#pragma unroll
    for (int n = 0; n < 2; ++n) {
      int row = wc * 64 + nh * 32 + n * 16 + fr;
#pragma unroll
      for (int kk = 0; kk < 2; ++kk)
        b[n][kk] = *(const bf16x8*)&Bs[slot * 16384 + row * 64 +
                                       (((kk * 4 + fq) ^ (row & 7)) << 3)];
    }
  };

  // prologue: stage K-tile 0 into slot 0, drain, barrier
  stage(0, 0, 0); stage(0, 1, 0); stage(0, 2, 0); stage(0, 3, 0);
  VMCNT0;
  BARRIER;

  bf16x8 a[4][2], b0[2][2], b1[2][2];
#pragma unroll 1
  for (int kt = 0; kt < NKT; ++kt) {
    int slot = kt & 1, ns = slot ^ 1;
    bool st = (kt + 1 < NKT);  // uniform
    // ---- phase 0: quad (mh0, nh0); stage A-h0 + B-h0 of kt+1 ----
    readA(slot, 0, a);
    readB(slot, 0, b0);
    if (st) { stage(kt + 1, 0, ns); stage(kt + 1, 2, ns); }
    BARRIER;
    LGKM0;
    __builtin_amdgcn_s_setprio(1);
    mfma16<0, 0>(acc, a, b0);
    __builtin_amdgcn_s_setprio(0);
    BARRIER;
    // ---- phase 1: quad (mh0, nh1); stage A-h1 + B-h1 of kt+1 ----
    readB(slot, 1, b1);
    if (st) { stage(kt + 1, 1, ns); stage(kt + 1, 3, ns); }
    BARRIER;
    LGKM0;
    __builtin_amdgcn_s_setprio(1);
    mfma16<0, 1>(acc, a, b1);
    __builtin_amdgcn_s_setprio(0);
    BARRIER;
    // ---- phase 2: quad (mh1, nh0) ----
    readA(slot, 1, a);
    BARRIER;
    LGKM0;
    __builtin_amdgcn_s_setprio(1);
    mfma16<1, 0>(acc, a, b0);
    __builtin_amdgcn_s_setprio(0);
    BARRIER;
    // ---- phase 3: quad (mh1, nh1); drain staged loads, flip slot ----
    __builtin_amdgcn_s_setprio(1);
    mfma16<1, 1>(acc, a, b1);
    __builtin_amdgcn_s_setprio(0);
    VMCNT0;
    BARRIER;
  }
}

// FFN1: ffh = relu(h1b @ w1T^T + b1), bf16 out [8192][4096]
__global__ __launch_bounds__(512, 2) void gemm256_relu(
    const ushort* __restrict__ A, const ushort* __restrict__ Bt,
    const float* __restrict__ bias, ushort* __restrict__ Cout, int ldc) {
  __shared__ __align__(16) ushort As[2 * 256 * 64];
  __shared__ __align__(16) ushort Bs[2 * 256 * 64];
  f32x4 acc[8][4] = {};
  int bx, by;
  xcd_swz(bx, by);
  int m0 = by * 256, n0 = bx * 256;
  gemm256_main(A, Bt, m0, n0, As, Bs, acc);
  int lane = threadIdx.x & 63, wid = threadIdx.x >> 6;
  int wr = wid >> 2, wc = wid & 3, fr = lane & 15, fq = lane >> 4;
#pragma unroll
  for (int i = 0; i < 8; ++i) {
    int gm = m0 + wr * 128 + (i >> 2) * 64 + (i & 3) * 16 + fq * 4;
#pragma unroll
    for (int j2 = 0; j2 < 4; ++j2) {
      int gn = n0 + wc * 64 + (j2 >> 1) * 32 + (j2 & 1) * 16 + fr;
      float bsv = bias[gn];
#pragma unroll
      for (int j = 0; j < 4; ++j)
        Cout[(size_t)(gm + j) * ldc + gn] = f2bf(fmaxf(acc[i][j2][j] + bsv, 0.f));
    }
  }
}

// QKV: Q (pre-scaled), K, Vt (transposed [B][H][HS][T]) from one GEMM.
__global__ __launch_bounds__(512, 2) void gemm256_qkv(
    const ushort* __restrict__ A, const ushort* __restrict__ Bt,
    const float* __restrict__ bias, ushort* __restrict__ q,
    ushort* __restrict__ k, ushort* __restrict__ vt) {
  __shared__ __align__(16) ushort As[2 * 256 * 64];
  __shared__ __align__(16) ushort Bs[2 * 256 * 64];
  f32x4 acc[8][4] = {};
  int bx, by;
  xcd_swz(bx, by);
  int m0 = by * 256, n0 = bx * 256;
  gemm256_main(A, Bt, m0, n0, As, Bs, acc);
  int lane = threadIdx.x & 63, wid = threadIdx.x >> 6;
  int wr = wid >> 2, wc = wid & 3, fr = lane & 15, fq = lane >> 4;
  const float qscale = 1.4426950408889634f / 32.0f;  // log2e * C^-0.5
#pragma unroll
  for (int i = 0; i < 8; ++i) {
    int gm = m0 + wr * 128 + (i >> 2) * 64 + (i & 3) * 16 + fq * 4;
#pragma unroll
    for (int j2 = 0; j2 < 4; ++j2) {
      int gn = n0 + wc * 64 + (j2 >> 1) * 32 + (j2 & 1) * 16 + fr;
      float bsv = bias[gn];
      if (gn < 1024) {
#pragma unroll
        for (int j = 0; j < 4; ++j)
          q[(size_t)(gm + j) * 1024 + gn] = f2bf((acc[i][j2][j] + bsv) * qscale);
      } else if (gn < 2048) {
        int col = gn - 1024;
#pragma unroll
        for (int j = 0; j < 4; ++j)
          k[(size_t)(gm + j) * 1024 + col] = f2bf(acc[i][j2][j] + bsv);
      } else {
        int dd = gn - 2048, h = dd >> 6, d = dd & 63;
        int bbr = gm >> 11, t = gm & 2047;
        ushort4 pw = {f2bf(acc[i][j2][0] + bsv), f2bf(acc[i][j2][1] + bsv),
                      f2bf(acc[i][j2][2] + bsv), f2bf(acc[i][j2][3] + bsv)};
        *(ushort4*)&vt[(((size_t)(bbr * 16 + h)) * 64 + d) * 2048 + t] = pw;
      }
    }
  }
}

// -------- 128x128 bf16 GEMM (BK=64, 8 waves) — for proj / FFN2 ----------
__device__ __forceinline__ void gemm_main(const ushort* __restrict__ A, int lda,
                                          const ushort* __restrict__ Bt, int ldb,
                                          int K, int m0, int n0,
                                          ushort* __restrict__ As,
                                          ushort* __restrict__ Bs,
                                          f32x4 (&acc)[4][2]) {
  int tid = threadIdx.x, wid = tid >> 6, lane = tid & 63;
  int wr = wid >> 2, wc = wid & 3, fr = lane & 15, fq = lane >> 4;
  const ushort* Ag = A + (size_t)m0 * lda;
  const ushort* Bg = Bt + (size_t)n0 * ldb;
  for (int k0 = 0; k0 < K; k0 += 64) {
#pragma unroll
    for (int c = 0; c < 2; ++c) {
      int slot = c * 512 + tid;
      int row = slot >> 3, s = slot & 7;
      int sw = (s << 3) ^ ((row & 7) << 3);
      gload16(Ag + (size_t)row * lda + k0 + sw, As + (size_t)(c * 512 + wid * 64) * 8);
      gload16(Bg + (size_t)row * ldb + k0 + sw, Bs + (size_t)(c * 512 + wid * 64) * 8);
    }
    __syncthreads();
    bf16x8 av[4][2], bv[2][2];
#pragma unroll
    for (int m = 0; m < 4; ++m) {
      int row = wr * 64 + m * 16 + fr;
#pragma unroll
      for (int ks = 0; ks < 2; ++ks)
        av[m][ks] = *(const bf16x8*)&As[row * 64 + (((ks * 4 + fq) ^ (row & 7)) << 3)];
    }
#pragma unroll
    for (int n = 0; n < 2; ++n) {
      int row = wc * 32 + n * 16 + fr;
#pragma unroll
      for (int ks = 0; ks < 2; ++ks)
        bv[n][ks] = *(const bf16x8*)&Bs[row * 64 + (((ks * 4 + fq) ^ (row & 7)) << 3)];
    }
#pragma unroll
    for (int m = 0; m < 4; ++m)
#pragma unroll
      for (int n = 0; n < 2; ++n)
#pragma unroll
        for (int ks = 0; ks < 2; ++ks)
          acc[m][n] = __builtin_amdgcn_mfma_f32_16x16x32_bf16(
              av[m][ks], bv[n][ks], acc[m][n], 0, 0, 0);
    __syncthreads();
  }
}

template <bool RELU, bool HASRES, bool OUTBF16>
__global__ __launch_bounds__(512) void gemm_bf16(
    const ushort* __restrict__ A, int lda, const ushort* __restrict__ Bt,
    int ldb, const float* __restrict__ bias, const float* __restrict__ res,
    void* __restrict__ Cout, int ldc, int K) {
  __shared__ __align__(16) ushort As[128 * 64];
  __shared__ __align__(16) ushort Bs[128 * 64];
  f32x4 acc[4][2] = {};
  int bx, by;
  xcd_swz(bx, by);
  int m0 = by * 128, n0 = bx * 128;
  gemm_main(A, lda, Bt, ldb, K, m0, n0, As, Bs, acc);
  int lane = threadIdx.x & 63, wid = threadIdx.x >> 6;
  int wr = wid >> 2, wc = wid & 3, fr = lane & 15, fq = lane >> 4;
#pragma unroll
  for (int m = 0; m < 4; ++m) {
    int gm = m0 + wr * 64 + m * 16 + fq * 4;
#pragma unroll
    for (int n = 0; n < 2; ++n) {
      int gn = n0 + wc * 32 + n * 16 + fr;
      float bsv = bias[gn];
#pragma unroll
      for (int j = 0; j < 4; ++j) {
        int row = gm + j;
        float v = acc[m][n][j] + bsv;
        if constexpr (HASRES) v += res[(size_t)row * ldc + gn];
        if constexpr (RELU) v = fmaxf(v, 0.f);
        if constexpr (OUTBF16)
          ((ushort*)Cout)[(size_t)row * ldc + gn] = f2bf(v);
        else
          ((float*)Cout)[(size_t)row * ldc + gn] = v;
      }
    }
  }
}

// ---------------- MFMA flash attention (round-7, unchanged) ----------------
constexpr int QB = 128, KVB = 64;
__global__ __launch_bounds__(512) void attn_kernel(const ushort* __restrict__ Qb,
                                                   const ushort* __restrict__ Kb,
                                                   const ushort* __restrict__ Vt,
                                                   ushort* __restrict__ att) {
  __shared__ __align__(16) ushort Klds[2][64 * 64];
  __shared__ __align__(16) ushort Vlds[2][64 * 64];
  __shared__ __align__(16) ushort Plds[8][16 * 64];
  int tid = threadIdx.x, wid = tid >> 6, lane = tid & 63;
  int fr = lane & 15, fq = lane >> 4;
  int bh = blockIdx.y, bb = bh >> 4, hh = bh & 15;
  const ushort* qkbase = Qb + ((size_t)bb * Tt) * Cc + hh * HSz;
  const ushort* Kbase = Kb + ((size_t)bb * Tt) * Cc + hh * HSz;
  const ushort* Vbase = Vt + ((size_t)(bb * Hh + hh)) * HSz * Tt;
  int srow = tid >> 3;
  int ssw = ((tid & 7) << 3) ^ ((srow & 7) << 3);

#pragma unroll 1
  for (int pass = 0; pass < 2; ++pass) {
    int qt = pass ? (Tt / QB - 1 - (int)blockIdx.x) : (int)blockIdx.x;
    int q0 = qt * QB;
    int q0w = q0 + wid * 16;

    bf16x8 Qreg[2];
#pragma unroll
    for (int d2 = 0; d2 < 2; ++d2)
      Qreg[d2] = *(const bf16x8*)(qkbase + (size_t)(q0w + fr) * Cc + d2 * 32 + fq * 8);
    f32x4 Oa[4] = {};
    float mrow = -1e30f, lrow = 0.f;
    int nt = q0 / KVB + 2;

    __syncthreads();
    gload16(Kbase + (size_t)srow * Cc + ssw, (char*)Klds[0] + wid * 1024);
    gload16(Vbase + (size_t)srow * Tt + ssw, (char*)Vlds[0] + wid * 1024);

#pragma unroll 1
    for (int kt = 0; kt < nt; ++kt) {
      int t0 = kt * KVB;
      int c = kt & 1;
      __syncthreads();
      if (kt + 1 < nt) {
        int t0n = t0 + KVB;
        gload16(Kbase + (size_t)(t0n + srow) * Cc + ssw,
                (char*)Klds[c ^ 1] + wid * 1024);
        gload16(Vbase + (size_t)srow * Tt + t0n + ssw,
                (char*)Vlds[c ^ 1] + wid * 1024);
      }
      if (q0w + 15 < t0) continue;

      const char* Kc = (const char*)Klds[c];
      const char* Vc = (const char*)Vlds[c];
      bf16x8 kf[4][2];
#pragma unroll
      for (int ks = 0; ks < 4; ++ks)
#pragma unroll
        for (int d2 = 0; d2 < 2; ++d2) {
          int row = ks * 16 + fr;
          int off = (d2 * 64 + fq * 16) ^ ((row & 7) << 4);
          kf[ks][d2] = *(const bf16x8*)(Kc + row * 128 + off);
        }
      f32x4 accs[4] = {};
      __builtin_amdgcn_s_setprio(1);
#pragma unroll
      for (int ks = 0; ks < 4; ++ks) {
        accs[ks] = __builtin_amdgcn_mfma_f32_16x16x32_bf16(
            kf[ks][0], Qreg[0], accs[ks], 0, 0, 0);
        accs[ks] = __builtin_amdgcn_mfma_f32_16x16x32_bf16(
            kf[ks][1], Qreg[1], accs[ks], 0, 0, 0);
      }
      __builtin_amdgcn_s_setprio(0);

      float sv[4][4];
      float vmax = -1e30f;
      if (t0 + 63 <= q0w) {
#pragma unroll
        for (int ks = 0; ks < 4; ++ks)
#pragma unroll
          for (int j = 0; j < 4; ++j) {
            sv[ks][j] = accs[ks][j];
            vmax = fmaxf(vmax, sv[ks][j]);
          }
      } else {
        int qg = q0w + fr;
#pragma unroll
        for (int ks = 0; ks < 4; ++ks)
#pragma unroll
          for (int j = 0; j < 4; ++j) {
            int kg = t0 + ks * 16 + fq * 4 + j;
            float s = accs[ks][j];
            s = (kg <= qg) ? s : -1e30f;
            sv[ks][j] = s;
            vmax = fmaxf(vmax, s);
          }
      }
      float mnew = mrow;
      if (!__all(vmax <= mrow + 11.0f)) {
        float rmax = fmaxf(vmax, __shfl_xor(vmax, 16));
        rmax = fmaxf(rmax, __shfl_xor(rmax, 32));
        mnew = fmaxf(mrow, rmax);
        float sf = exp2f(mrow - mnew);
        mrow = mnew;
        lrow *= sf;
#pragma unroll
        for (int j = 0; j < 4; ++j) {
          float sfo = __shfl(sf, fq * 4 + j);
#pragma unroll
          for (int ds = 0; ds < 4; ++ds) Oa[ds][j] *= sfo;
        }
      }
      char* pbase = (char*)Plds[wid] + fr * 128;
#pragma unroll
      for (int ks = 0; ks < 4; ++ks) {
        float p0 = exp2f(sv[ks][0] - mnew);
        float p1 = exp2f(sv[ks][1] - mnew);
        float p2 = exp2f(sv[ks][2] - mnew);
        float p3 = exp2f(sv[ks][3] - mnew);
        lrow += (p0 + p1) + (p2 + p3);
        uint2 pw = {cvtpk_bf16(p0, p1), cvtpk_bf16(p2, p3)};
        int off = (ks * 32 + fq * 8) ^ ((fr & 7) << 4);
        *(uint2*)(pbase + off) = pw;
      }

      bf16x8 vf[4][2];
#pragma unroll
      for (int ds = 0; ds < 4; ++ds)
#pragma unroll
        for (int k2 = 0; k2 < 2; ++k2) {
          int row = ds * 16 + fr;
          int off = (k2 * 64 + fq * 16) ^ ((row & 7) << 4);
          vf[ds][k2] = *(const bf16x8*)(Vc + row * 128 + off);
        }
      bf16x8 pf[2];
#pragma unroll
      for (int k2 = 0; k2 < 2; ++k2) {
        int off = (k2 * 64 + fq * 16) ^ ((fr & 7) << 4);
        pf[k2] = *(const bf16x8*)((const char*)Plds[wid] + fr * 128 + off);
      }
      __builtin_amdgcn_s_setprio(1);
#pragma unroll
      for (int ds = 0; ds < 4; ++ds) {
        Oa[ds] = __builtin_amdgcn_mfma_f32_16x16x32_bf16(
            pf[0], vf[ds][0], Oa[ds], 0, 0, 0);
        Oa[ds] = __builtin_amdgcn_mfma_f32_16x16x32_bf16(
            pf[1], vf[ds][1], Oa[ds], 0, 0, 0);
      }
      __builtin_amdgcn_s_setprio(0);
    }

    {
      lrow += __shfl_xor(lrow, 16);
      lrow += __shfl_xor(lrow, 32);
      float linv = 1.f / lrow;
#pragma unroll
      for (int j = 0; j < 4; ++j) {
        float lo = __shfl(linv, fq * 4 + j);
        int qg = q0w + fq * 4 + j;
        ushort* orow = att + (size_t)(bb * Tt + qg) * Cc + hh * HSz;
#pragma unroll
        for (int ds = 0; ds < 4; ++ds)
          orow[ds * 16 + fr] = f2bf(Oa[ds][j] * lo);
      }
    }
  }
}

extern "C" void kernel_launch(void* const* d_in, const int* in_sizes, int n_in,
                              void* d_out, int out_size, void* d_ws,
                              size_t ws_size, hipStream_t stream) {
  const float* x = (const float*)d_in[0];
  const float* wq = (const float*)d_in[1];
  const float* bq = (const float*)d_in[2];
  const float* wk = (const float*)d_in[3];
  const float* bk = (const float*)d_in[4];
  const float* wv = (const float*)d_in[5];
  const float* bv = (const float*)d_in[6];
  const float* wp = (const float*)d_in[7];
  const float* bp = (const float*)d_in[8];
  const float* w1 = (const float*)d_in[9];
  const float* b1 = (const float*)d_in[10];
  const float* w2 = (const float*)d_in[11];
  const float* b2 = (const float*)d_in[12];
  const float* g1 = (const float*)d_in[13];
  const float* be1 = (const float*)d_in[14];
  const float* g2 = (const float*)d_in[15];
  const float* be2 = (const float*)d_in[16];
  float* out = (float*)d_out;

  ushort* Qb = (ushort*)d_ws;                 // [8192][1024]
  ushort* Kb = Qb + (size_t)8388608;          // [8192][1024]
  ushort* Vt = Kb + (size_t)8388608;          // [4][16][64][2048]
  ushort* att = Vt + (size_t)8388608;         // [8192][1024]
  ushort* ffh = Qb;                           // [8192][4096] overlay
  ushort* h1b = att + (size_t)8388608;        // LN1/LN2 out
  float* x2 = (float*)(h1b + (size_t)8388608);
  ushort* wqkvT = (ushort*)(x2 + (size_t)8388608);  // [3072][1024]
  ushort* wpT = wqkvT + (size_t)3145728;            // [1024][1024]
  ushort* w1T = wpT + (size_t)1048576;              // [4096][1024]
  ushort* w2T = w1T + (size_t)4194304;              // [1024][4096]
  float* bqkv = (float*)(w2T + (size_t)4194304);    // [3072]

  tcast_qkv<<<dim3(32, 2, 48), 256, 0, stream>>>(wq, wk, wv, wqkvT);
  tcast_kernel<<<dim3(32, 32), 256, 0, stream>>>(wp, wpT, 1024, 1024);
  tcast_kernel<<<dim3(32, 128), 256, 0, stream>>>(w1, w1T, 4096, 1024);
  tcast_kernel<<<dim3(128, 32), 256, 0, stream>>>(w2, w2T, 1024, 4096);
  bias_concat<<<dim3(12), 256, 0, stream>>>(bq, bk, bv, bqkv);

  // 1) h1b = LN(x)
  ln_kernel<<<dim3(Mrows), 256, 0, stream>>>(x, g1, be1, h1b);
  // 2) Q,K,Vt = h1b @ WqkvT^T + bqkv  (256^2 4-phase kernel)
  gemm256_qkv<<<dim3(12, 32), 512, 0, stream>>>(h1b, wqkvT, bqkv, Qb, Kb, Vt);
  // 3) att = causal_softmax(Q K^T) V
  attn_kernel<<<dim3(Tt / QB / 2, Bb * Hh), 512, 0, stream>>>(Qb, Kb, Vt, att);
  // 4) x2 = x + att @ wp + bp
  gemm_bf16<false, true, false><<<dim3(8, 64), 512, 0, stream>>>(
      att, 1024, wpT, 1024, bp, x, x2, 1024, 1024);
  // 5) h2b = LN(x2)
  ln_kernel<<<dim3(Mrows), 256, 0, stream>>>(x2, g2, be2, h1b);
  // 6) ffh = relu(h2b @ w1 + b1)  (256^2 4-phase kernel)
  gemm256_relu<<<dim3(16, 32), 512, 0, stream>>>(h1b, w1T, b1, ffh, 4096);
  // 7) out = x2 + ffh @ w2 + b2
  gemm_bf16<false, true, false><<<dim3(8, 64), 512, 0, stream>>>(
      ffh, 4096, w2T, 4096, b2, x2, out, 1024, 4096);
}